// Round 2
// baseline (13361.243 us; speedup 1.0000x reference)
//
#include <hip/hip_runtime.h>
#include <hip/hip_bf16.h>
#include <math.h>

#define ACT_NONE 0
#define ACT_RELU 1
#define ACT_GELU 2

struct GK { float k[41]; };

// ---------------- pixel-shuffle conv: lrms (B,4,64,64) -> lrms_up (B,4,256,256) ----
__global__ __launch_bounds__(256) void conv_ps_k(const float* __restrict__ lrms,
                                                 const float* __restrict__ w,
                                                 float* __restrict__ up){
    int tid = threadIdx.x, bx = blockIdx.x;
    int y = bx & 255, c = (bx >> 8) & 3, b = bx >> 10;
    int x = tid;
    int h = y >> 2, r1 = y & 3, ww = x >> 2, r2 = x & 3;
    int oc = c*16 + r1*4 + r2;
    float acc = 0.f;
    for (int ic = 0; ic < 4; ++ic) {
        const float* base = lrms + ((b*4 + ic) << 12);
        const float* wb = w + (oc*4 + ic)*9;
        #pragma unroll
        for (int ky = 0; ky < 3; ++ky) {
            int hh = h + ky - 1; if (hh < 0 || hh > 63) continue;
            #pragma unroll
            for (int kx = 0; kx < 3; ++kx) {
                int cc = ww + kx - 1; if (cc < 0 || cc > 63) continue;
                acc += base[(hh<<6) + cc] * wb[ky*3 + kx];
            }
        }
    }
    up[(((long)(b*4 + c)) << 16) + (y<<8) + x] = acc;
}

// ---------------- gaussian blur (reflect pad), vertical pass --------------------
__global__ __launch_bounds__(256) void gauss_v_k(const float* __restrict__ src, int bstride,
                                                 float* __restrict__ out, GK gk, int ks){
    int tid = threadIdx.x, bx = blockIdx.x;
    int y = bx & 255, b = bx >> 8, p = ks >> 1;
    const float* s = src + (long)b * bstride;
    float acc = 0.f;
    for (int t = 0; t < ks; ++t) {
        int yy = y - p + t;
        yy = yy < 0 ? -yy : (yy > 255 ? 510 - yy : yy);
        acc += gk.k[t] * s[(yy<<8) + tid];
    }
    out[((long)bx << 8) + tid] = acc;
}
// horizontal pass + highpass: feat5[ch] = orig - blur_h(blur_v)
__global__ __launch_bounds__(256) void gauss_h_k(const float* __restrict__ blur,
                                                 const float* __restrict__ orig, int bstride,
                                                 float* __restrict__ feat5, int ch, GK gk, int ks){
    int tid = threadIdx.x, bx = blockIdx.x;
    int y = bx & 255, b = bx >> 8, p = ks >> 1, x = tid;
    const float* row = blur + ((long)b << 16) + (y<<8);
    float acc = 0.f;
    for (int t = 0; t < ks; ++t) {
        int xx = x - p + t;
        xx = xx < 0 ? -xx : (xx > 255 ? 510 - xx : xx);
        acc += gk.k[t] * row[xx];
    }
    float o = orig[(long)b*bstride + (y<<8) + x];
    feat5[(((long)(b*5 + ch)) << 16) + (y<<8) + x] = o - acc;
}

// ---------------- generic 3x3 SAME conv over 256x256, fp32 ----------------------
__global__ __launch_bounds__(256) void conv3x3_k(const float* __restrict__ in, int inC, int inc0, int Cin,
                                                 const float* __restrict__ w,
                                                 float* __restrict__ out, int outC, int outc0, int Cout,
                                                 int act, int accum){
    int tid = threadIdx.x, bx = blockIdx.x;
    int y = bx & 255;
    int oc = (bx >> 8) % Cout;
    int b  = bx / (Cout << 8);
    __shared__ float wl[144];
    if (tid < Cin*9) wl[tid] = w[(oc*Cin)*9 + tid];
    __syncthreads();
    int x = tid;
    float acc = 0.f;
    for (int ic = 0; ic < Cin; ++ic) {
        const float* base = in + (((long)(b*inC + inc0 + ic)) << 16);
        #pragma unroll
        for (int ky = 0; ky < 3; ++ky) {
            int yy = y + ky - 1; if (yy < 0 || yy > 255) continue;
            const float* rowp = base + (yy<<8);
            #pragma unroll
            for (int kx = 0; kx < 3; ++kx) {
                int xx = x + kx - 1; if (xx < 0 || xx > 255) continue;
                acc += wl[ic*9 + ky*3 + kx] * rowp[xx];
            }
        }
    }
    if (act == ACT_RELU) acc = fmaxf(acc, 0.f);
    else if (act == ACT_GELU) {
        float u = 0.7978845608028654f * (acc + 0.044715f*acc*acc*acc);
        acc = 0.5f * acc * (1.f + tanhf(u));
    }
    long oidx = (((long)(b*outC + outc0 + oc)) << 16) + (y<<8) + x;
    if (accum) out[oidx] += acc; else out[oidx] = acc;
}

// ---------------- 1x1 conv over 256x256 ---------------------------------------
__global__ __launch_bounds__(256) void conv1x1_k(const float* __restrict__ in, int inC, int inc0, int Cin,
                                                 const float* __restrict__ w,
                                                 float* __restrict__ out, int outC, int outc0, int Cout,
                                                 int act){
    int tid = threadIdx.x, bx = blockIdx.x;
    int pt = bx & 255;
    int oc = (bx >> 8) % Cout;
    int b  = bx / (Cout << 8);
    __shared__ float wl[48];
    if (tid < Cin) wl[tid] = w[oc*Cin + tid];
    __syncthreads();
    int p = (pt << 8) + tid;
    float acc = 0.f;
    for (int ic = 0; ic < Cin; ++ic)
        acc += wl[ic] * in[(((long)(b*inC + inc0 + ic)) << 16) + p];
    if (act == ACT_RELU) acc = fmaxf(acc, 0.f);
    out[(((long)(b*outC + outc0 + oc)) << 16) + p] = acc;
}

// ---------------- spatial mean per (b,c) over dense (4,16,65536) buffer ----------
__global__ __launch_bounds__(256) void mean_sp_k(const float* __restrict__ x, float* __restrict__ means){
    int tid = threadIdx.x, bc = blockIdx.x;
    const float* p = x + ((long)bc << 16);
    float s = 0.f;
    for (int i = tid; i < 65536; i += 256) s += p[i];
    __shared__ float sm[256];
    sm[tid] = s; __syncthreads();
    for (int st = 128; st > 0; st >>= 1) { if (tid < st) sm[tid] += sm[tid+st]; __syncthreads(); }
    if (tid == 0) means[bc] = sm[0] * (1.f/65536.f);
}

// ---------------- channel attention (tiny) -------------------------------------
__global__ void ca_k(const float* __restrict__ means, const float* __restrict__ w1,
                     const float* __restrict__ w2, float* __restrict__ ca){
    int t = threadIdx.x;
    if (t < 64) {
        int b = t >> 4, oc = t & 15;
        float hid[4];
        #pragma unroll
        for (int c2 = 0; c2 < 4; ++c2) {
            float a = 0.f;
            for (int c = 0; c < 16; ++c) a += w1[c2*16 + c] * means[b*16 + c];
            hid[c2] = fmaxf(a, 0.f);
        }
        float v = 0.f;
        #pragma unroll
        for (int c2 = 0; c2 < 4; ++c2) v += w2[oc*4 + c2] * hid[c2];
        ca[t] = 1.f / (1.f + expf(-v));
    }
}

// ---------------- y += bdy * ca[plane] -----------------------------------------
__global__ __launch_bounds__(256) void add_mul_ca_k(float* __restrict__ y, const float* __restrict__ bdy,
                                                    const float* __restrict__ ca, int n){
    int i = blockIdx.x*256 + threadIdx.x;
    if (i < n) y[i] += bdy[i] * ca[i >> 16];
}

// ---------------- FFT kernels (brute DFT, 256-pt, ortho = 1/16 per axis) --------
__global__ __launch_bounds__(256) void rfft_w_k(const float* __restrict__ in, int inC, int inc0,
                                                float* __restrict__ ore, float* __restrict__ oim){
    int tid = threadIdx.x, bx = blockIdx.x;
    int y = bx & 255, c = (bx >> 8) & 7, b = bx >> 11;
    __shared__ float row[256], ct[256], st[256];
    float ang = 6.283185307179586f * (float)tid / 256.f;
    ct[tid] = cosf(ang); st[tid] = sinf(ang);
    row[tid] = in[(((long)(b*inC + inc0 + c)) << 16) + (y<<8) + tid];
    __syncthreads();
    if (tid < 129) {
        float re = 0.f, im = 0.f;
        for (int m = 0; m < 256; ++m) {
            int id = (tid * m) & 255;
            float v = row[m];
            re += v * ct[id]; im -= v * st[id];
        }
        long o = ((long)((b*8 + c)*256 + y)) * 129 + tid;
        ore[o] = re * 0.0625f; oim[o] = im * 0.0625f;
    }
}
// c2c fft along H (sgn=+1 forward e^{-i}, sgn=-1 inverse e^{+i})
__global__ __launch_bounds__(256) void fft_h_k(const float* __restrict__ ire, const float* __restrict__ iim,
                                               float* __restrict__ ore, float* __restrict__ oim, float sgn){
    int tid = threadIdx.x, bx = blockIdx.x;
    int k = bx % 129; int t2 = bx / 129; int c = t2 & 7; int b = t2 >> 3;
    __shared__ float cr[256], ci[256], ct[256], st[256];
    float ang = 6.283185307179586f * (float)tid / 256.f;
    ct[tid] = cosf(ang); st[tid] = sinf(ang);
    long base = ((long)(b*8 + c)) * 256 * 129 + k;
    cr[tid] = ire[base + (long)tid*129];
    ci[tid] = iim[base + (long)tid*129];
    __syncthreads();
    float re = 0.f, im = 0.f;
    int u = tid;
    for (int yv = 0; yv < 256; ++yv) {
        int id = (u * yv) & 255;
        float cc = ct[id], ss = st[id];
        float r = cr[yv], i = ci[yv];
        re += r*cc + sgn*(i*ss);
        im += i*cc - sgn*(r*ss);
    }
    ore[base + (long)u*129] = re * 0.0625f;
    oim[base + (long)u*129] = im * 0.0625f;
}
// c2r irfft along W, accumulate (Hermitian formula: ignores imag of bins 0,128)
__global__ __launch_bounds__(256) void irfft_w_acc_k(const float* __restrict__ ire, const float* __restrict__ iim,
                                                     float* __restrict__ out, int outC, int outc0){
    int tid = threadIdx.x, bx = blockIdx.x;
    int y = bx & 255, c = (bx >> 8) & 7, b = bx >> 11;
    __shared__ float vr[129], vi[129], ct[256], st[256];
    float ang = 6.283185307179586f * (float)tid / 256.f;
    ct[tid] = cosf(ang); st[tid] = sinf(ang);
    if (tid < 129) {
        long base = ((long)((b*8 + c)*256 + y)) * 129;
        vr[tid] = ire[base + tid]; vi[tid] = iim[base + tid];
    }
    __syncthreads();
    int m = tid;
    float acc = vr[0] + ((m & 1) ? -vr[128] : vr[128]);
    for (int k = 1; k < 128; ++k) {
        int id = (k * m) & 255;
        acc += 2.f * (vr[k]*ct[id] - vi[k]*st[id]);
    }
    out[(((long)(b*outC + outc0 + c)) << 16) + (y<<8) + m] += acc * 0.0625f;
}
// 1x1 spectral conv + relu on (B, 2x8, 256x129)
__global__ __launch_bounds__(256) void spec_k(const float* __restrict__ re, const float* __restrict__ im,
                                              const float* __restrict__ w,
                                              float* __restrict__ ore, float* __restrict__ oim){
    int tid = threadIdx.x, bx = blockIdx.x;
    int pt = bx % 129; int oc = (bx / 129) & 15; int b = bx / (129*16);
    __shared__ float wl[256];
    wl[tid] = w[tid];
    __syncthreads();
    int p = (pt << 8) + tid;           // < 33024 always
    long pb = ((long)b) * 8 * 33024;
    float acc = 0.f;
    for (int ic = 0; ic < 8; ++ic)
        acc += re[pb + (long)ic*33024 + p] * wl[oc*16 + ic]
             + im[pb + (long)ic*33024 + p] * wl[oc*16 + 8 + ic];
    acc = fmaxf(acc, 0.f);
    if (oc < 8) ore[pb + (long)oc*33024 + p] = acc;
    else        oim[pb + (long)(oc-8)*33024 + p] = acc;
}

// ---------------- LIIF MLP: center corner (weight 1.0 interior / 0.25 on edges) --
#define MLP_P 8
__global__ __launch_bounds__(256) void mlp_center_k(const float* __restrict__ feat,
        const float* __restrict__ w_in, const float* __restrict__ b_in,
        const float* __restrict__ w_h,  const float* __restrict__ b_h,
        const float* __restrict__ w_out,const float* __restrict__ b_out,
        float* __restrict__ fo){
    __shared__ __align__(16) float inp[MLP_P][148];
    __shared__ __align__(16) float h0[MLP_P][256];
    __shared__ __align__(16) float h1[MLP_P][256];
    int tid = threadIdx.x, bx = blockIdx.x;
    int b = bx >> 13;          // 8192 tiles per batch
    int tile = bx & 8191;
    int p0 = tile * MLP_P;
    for (int idx = tid; idx < MLP_P*148; idx += 256) {
        int pp = idx / 148, j = idx % 148;
        int p = p0 + pp; int s0 = p >> 8, s1 = p & 255;
        float v;
        if (j < 144) {
            int iy = j / 48, ix = (j >> 4) % 3, c = j & 15;
            int yy = s0 + iy - 1, xx = s1 + ix - 1;
            v = (yy >= 0 && yy < 256 && xx >= 0 && xx < 256)
                ? feat[(((long)(b*16 + c)) << 16) + (yy<<8) + xx] : 0.f;
        } else if (j < 146) v = 0.f;
        else v = 2.f;
        inp[pp][j] = v;
    }
    __syncthreads();
    float acc[MLP_P];
    #pragma unroll
    for (int pp = 0; pp < MLP_P; ++pp) acc[pp] = 0.f;
    for (int j = 0; j < 148; j += 4) {
        float wv0 = w_in[(j+0)*256 + tid];
        float wv1 = w_in[(j+1)*256 + tid];
        float wv2 = w_in[(j+2)*256 + tid];
        float wv3 = w_in[(j+3)*256 + tid];
        #pragma unroll
        for (int pp = 0; pp < MLP_P; ++pp) {
            float4 v = *(const float4*)&inp[pp][j];
            acc[pp] = fmaf(wv0, v.x, fmaf(wv1, v.y, fmaf(wv2, v.z, fmaf(wv3, v.w, acc[pp]))));
        }
    }
    float bb = b_in[tid];
    #pragma unroll
    for (int pp = 0; pp < MLP_P; ++pp) h0[pp][tid] = fmaxf(acc[pp] + bb, 0.f);
    __syncthreads();
    for (int L = 0; L < 3; ++L) {
        const float* W = w_h + L*65536;
        float (*hin)[256]  = (L & 1) ? h1 : h0;
        float (*hout)[256] = (L & 1) ? h0 : h1;
        #pragma unroll
        for (int pp = 0; pp < MLP_P; ++pp) acc[pp] = 0.f;
        for (int j = 0; j < 256; j += 4) {
            float wv0 = W[(j+0)*256 + tid];
            float wv1 = W[(j+1)*256 + tid];
            float wv2 = W[(j+2)*256 + tid];
            float wv3 = W[(j+3)*256 + tid];
            #pragma unroll
            for (int pp = 0; pp < MLP_P; ++pp) {
                float4 v = *(const float4*)&hin[pp][j];
                acc[pp] = fmaf(wv0, v.x, fmaf(wv1, v.y, fmaf(wv2, v.z, fmaf(wv3, v.w, acc[pp]))));
            }
        }
        float bh = b_h[L*256 + tid];
        #pragma unroll
        for (int pp = 0; pp < MLP_P; ++pp) hout[pp][tid] = fmaxf(acc[pp] + bh, 0.f);
        __syncthreads();
    }
    // result in h1 (L=0 ->h1, L=1 ->h0, L=2 ->h1)
    if (tid < 128) {
        int pp = tid >> 4, oc = tid & 15;
        float a = b_out[oc];
        for (int j = 0; j < 256; ++j) a += h1[pp][j] * w_out[j*16 + oc];
        int p = p0 + pp; int s0 = p >> 8, s1 = p & 255;
        float w0 = (s0 == 255 || s1 == 255) ? 0.25f : 1.0f;
        fo[(((long)(b*16 + oc)) << 16) + p] = w0 * a;
    }
}

// ---------------- LIIF MLP: remaining 3 corners for edge pixels only -------------
__global__ __launch_bounds__(256) void mlp_edge_k(const float* __restrict__ feat,
        const float* __restrict__ w_in, const float* __restrict__ b_in,
        const float* __restrict__ w_h,  const float* __restrict__ b_h,
        const float* __restrict__ w_out,const float* __restrict__ b_out,
        float* __restrict__ fo){
    int tid = threadIdx.x, bx = blockIdx.x;
    int b = bx / 511, e = bx % 511;
    int s0 = (e < 256) ? 255 : (e - 256);
    int s1 = (e < 256) ? e : 255;
    __shared__ float inp[148], h0[256], h1[256];
    const int vxs[3] = {-1, 1, 1};
    const int vys[3] = { 1,-1, 1};
    float outacc = 0.f;
    for (int cn = 0; cn < 3; ++cn) {
        int i0 = vxs[cn] > 0 ? min(s0+1, 255) : s0;
        int i1 = vys[cn] > 0 ? min(s1+1, 255) : s1;
        float rel0 = 2.f * (float)(s0 - i0);
        float rel1 = 2.f * (float)(s1 - i1);
        if (tid < 148) {
            int j = tid; float v;
            if (j < 144) {
                int iy = j / 48, ix = (j >> 4) % 3, c = j & 15;
                int yy = i0 + iy - 1, xx = i1 + ix - 1;
                v = (yy >= 0 && yy < 256 && xx >= 0 && xx < 256)
                    ? feat[(((long)(b*16 + c)) << 16) + (yy<<8) + xx] : 0.f;
            } else if (j == 144) v = rel0;
            else if (j == 145) v = rel1;
            else v = 2.f;
            inp[j] = v;
        }
        __syncthreads();
        float a = 0.f;
        for (int j = 0; j < 148; ++j) a += w_in[j*256 + tid] * inp[j];
        h0[tid] = fmaxf(a + b_in[tid], 0.f);
        __syncthreads();
        for (int L = 0; L < 3; ++L) {
            const float* W = w_h + L*65536;
            float* hin  = (L & 1) ? h1 : h0;
            float* hout = (L & 1) ? h0 : h1;
            float s = 0.f;
            for (int j = 0; j < 256; ++j) s += W[j*256 + tid] * hin[j];
            hout[tid] = fmaxf(s + b_h[L*256 + tid], 0.f);
            __syncthreads();
        }
        if (tid < 16) {
            float o = b_out[tid];
            for (int j = 0; j < 256; ++j) o += h1[j] * w_out[j*16 + tid];
            outacc += 0.25f * o;
        }
        __syncthreads();
    }
    if (tid < 16) {
        int p = (s0 << 8) + s1;
        fo[(((long)(b*16 + tid)) << 16) + p] += outacc;
    }
}

// ---------------- final conv (16->4, 3x3) + lrms_up ------------------------------
__global__ __launch_bounds__(256) void final_k(const float* __restrict__ fo, const float* __restrict__ w,
                                               const float* __restrict__ lrms_up, float* __restrict__ out){
    int tid = threadIdx.x, bx = blockIdx.x;
    int y = bx & 255, oc = (bx >> 8) & 3, b = bx >> 10;
    __shared__ float wl[144];
    if (tid < 144) wl[tid] = w[oc*144 + tid];
    __syncthreads();
    int x = tid;
    float acc = 0.f;
    for (int ic = 0; ic < 16; ++ic) {
        const float* base = fo + (((long)(b*16 + ic)) << 16);
        #pragma unroll
        for (int ky = 0; ky < 3; ++ky) {
            int yy = y + ky - 1; if (yy < 0 || yy > 255) continue;
            const float* rowp = base + (yy<<8);
            #pragma unroll
            for (int kx = 0; kx < 3; ++kx) {
                int xx = x + kx - 1; if (xx < 0 || xx > 255) continue;
                acc += wl[ic*9 + ky*3 + kx] * rowp[xx];
            }
        }
    }
    long oidx = (((long)(b*4 + oc)) << 16) + (y<<8) + x;
    out[oidx] = acc + lrms_up[oidx];
}

// ================================================================================
static void make_gk(GK& g, int ks, double sigma){
    double tmp[41]; double s = 0.0; double c = (ks - 1) / 2.0;
    for (int i = 0; i < ks; ++i) { double d = i - c; tmp[i] = exp(-(d*d)/(2.0*sigma*sigma)); s += tmp[i]; }
    for (int i = 0; i < ks; ++i) g.k[i] = (float)(tmp[i]/s);
    for (int i = ks; i < 41; ++i) g.k[i] = 0.f;
}

extern "C" void kernel_launch(void* const* d_in, const int* in_sizes, int n_in,
                              void* d_out, int out_size, void* d_ws, size_t ws_size,
                              hipStream_t stream) {
    const float* lrms     = (const float*)d_in[0];
    const float* pan      = (const float*)d_in[1];
    const float* w_convps = (const float*)d_in[2];
    const float* hor_w1   = (const float*)d_in[3];
    const float* hor_w2   = (const float*)d_in[4];
    const float* ffc_l2l  = (const float*)d_in[5];
    const float* ffc_l2g  = (const float*)d_in[6];
    const float* ffc_g2l  = (const float*)d_in[7];
    const float* ffc_spec = (const float*)d_in[8];
    const float* ref_in   = (const float*)d_in[9];
    const float* ref_b1   = (const float*)d_in[10];
    const float* ref_b2   = (const float*)d_in[11];
    const float* ref_ca1  = (const float*)d_in[12];
    const float* ref_ca2  = (const float*)d_in[13];
    const float* ref_out  = (const float*)d_in[14];
    const float* w_fuse   = (const float*)d_in[15];
    const float* w_liif   = (const float*)d_in[16];
    const float* w_hp     = (const float*)d_in[17];
    const float* mw_in    = (const float*)d_in[18];
    const float* mb_in    = (const float*)d_in[19];
    const float* mw_h     = (const float*)d_in[20];
    const float* mb_h     = (const float*)d_in[21];
    const float* mw_out   = (const float*)d_in[22];
    const float* mb_out   = (const float*)d_in[23];
    float* out = (float*)d_out;

    const int B = 4;
    const long PIX = 65536;
    float* ws = (float*)d_ws;
    size_t off = 0;
    auto alloc = [&](size_t n){ float* p = ws + off; off += n; return p; };
    float* lrms_up  = alloc((size_t)B*4*PIX);
    float* f012     = alloc((size_t)B*48*PIX);
    float* fusedCat = alloc((size_t)B*48*PIX);
    float* feat_all = alloc((size_t)B*16*PIX);
    float* fo       = alloc((size_t)B*16*PIX);
    float* feat5    = alloc((size_t)B*5*PIX);
    float* tA       = alloc((size_t)B*16*PIX);
    float* tB       = alloc((size_t)B*16*PIX);
    float* tC       = alloc((size_t)B*16*PIX);
    float* blur1    = alloc((size_t)B*PIX);
    size_t fftsz = (size_t)B*8*256*129;
    float* re0 = alloc(fftsz); float* im0 = alloc(fftsz);
    float* re1 = alloc(fftsz); float* im1 = alloc(fftsz);
    float* means = alloc(64); float* ca = alloc(64);
    if (off * sizeof(float) > ws_size) return;   // workspace insufficient: fail visibly

    auto conv3 = [&](const float* in, int inC, int inc0, int Cin, const float* w,
                     float* o, int outC, int outc0, int Cout, int act, int accum){
        conv3x3_k<<<dim3(B*Cout*256), dim3(256), 0, stream>>>(in, inC, inc0, Cin, w, o, outC, outc0, Cout, act, accum);
    };
    auto conv1 = [&](const float* in, int inC, int inc0, int Cin, const float* w,
                     float* o, int outC, int outc0, int Cout, int act){
        conv1x1_k<<<dim3(B*Cout*256), dim3(256), 0, stream>>>(in, inC, inc0, Cin, w, o, outC, outc0, Cout, act);
    };
    // refine: x (dense 16ch), t1,t2 temps; writes out slice of f012
    auto do_refine = [&](float* x, float* t1, float* t2, int ri, int outc0){
        conv3(x, 16, 0, 16, ref_in + (size_t)ri*2304, t1, 16, 0, 16, ACT_NONE, 0);  // y
        conv3(t1, 16, 0, 16, ref_b1 + (size_t)ri*2304, t2, 16, 0, 16, ACT_RELU, 0);
        conv3(t2, 16, 0, 16, ref_b2 + (size_t)ri*2304, x, 16, 0, 16, ACT_NONE, 0);  // bdy -> x
        mean_sp_k<<<dim3(64), dim3(256), 0, stream>>>(x, means);
        ca_k<<<dim3(1), dim3(64), 0, stream>>>(means, ref_ca1 + (size_t)ri*64, ref_ca2 + (size_t)ri*64, ca);
        add_mul_ca_k<<<dim3(16384), dim3(256), 0, stream>>>(t1, x, ca, B*16*65536); // y += bdy*ca
        conv3(t1, 16, 0, 16, ref_out + (size_t)ri*2304, f012, 48, outc0, 16, ACT_NONE, 0);
    };
    // ffc: input is f012 channels [base, base+16); output dense 16ch -> tA
    auto do_ffc = [&](int base, int wi){
        conv3(f012, 48, base,   8, ffc_l2g + (size_t)wi*576, tA, 16, 0, 8, ACT_NONE, 0); // l2g -> ch0..7
        conv3(f012, 48, base,   8, ffc_l2l + (size_t)wi*576, tA, 16, 8, 8, ACT_NONE, 0); // l2l -> ch8..15
        conv3(f012, 48, base+8, 8, ffc_g2l + (size_t)wi*576, tA, 16, 8, 8, ACT_NONE, 1); // + g2l
        rfft_w_k<<<dim3(B*8*256), dim3(256), 0, stream>>>(f012, 48, base+8, re0, im0);
        fft_h_k <<<dim3(B*8*129), dim3(256), 0, stream>>>(re0, im0, re1, im1, 1.f);      // forward
        spec_k  <<<dim3(B*16*129), dim3(256), 0, stream>>>(re1, im1, ffc_spec + (size_t)wi*256, re0, im0);
        fft_h_k <<<dim3(B*8*129), dim3(256), 0, stream>>>(re0, im0, re1, im1, -1.f);     // inverse along H
        irfft_w_acc_k<<<dim3(B*8*256), dim3(256), 0, stream>>>(re1, im1, tA, 16, 0);     // + g2g -> ch0..7
    };

    // ---- lrms_up ----
    conv_ps_k<<<dim3(B*4*256), dim3(256), 0, stream>>>(lrms, w_convps, lrms_up);
    // ---- zero feat5 (channels 2..4 stay zero) ----
    hipMemsetAsync(feat5, 0, (size_t)B*5*PIX*sizeof(float), stream);

    const int kss[3] = {5, 27, 41};
    const double sgs[3] = {1.5, 2.0, 2.8};
    for (int br = 0; br < 3; ++br) {
        GK gk; make_gk(gk, kss[br], sgs[br]);
        int ks = kss[br];
        gauss_v_k<<<dim3(B*256), dim3(256), 0, stream>>>(pan, 65536, blur1, gk, ks);
        gauss_h_k<<<dim3(B*256), dim3(256), 0, stream>>>(blur1, pan, 65536, feat5, 0, gk, ks);
        gauss_v_k<<<dim3(B*256), dim3(256), 0, stream>>>(lrms_up, 4*65536, blur1, gk, ks);
        gauss_h_k<<<dim3(B*256), dim3(256), 0, stream>>>(blur1, lrms_up, 4*65536, feat5, 1, gk, ks);
        // hornet
        conv3(feat5, 5, 0, 5, hor_w1 + (size_t)br*720, tA, 16, 0, 16, ACT_GELU, 0);
        conv3(tA, 16, 0, 16, hor_w2 + (size_t)br*2304, tB, 16, 0, 16, ACT_NONE, 0);
        // refine 0: x=tB -> f0 (f012 ch0..15)
        do_refine(tB, tC, tA, 3*br + 0, 0);
        // ffc 0 -> tA
        do_ffc(0, 2*br + 0);
        // refine 1: x=tA -> f1 (ch16..31)
        do_refine(tA, tC, tB, 3*br + 1, 16);
        // ffc 1 -> tA
        do_ffc(16, 2*br + 1);
        // refine 2 -> f2 (ch32..47)
        do_refine(tA, tC, tB, 3*br + 2, 32);
        // fuse 1x1 (48->16) into fusedCat slice
        conv1(f012, 48, 0, 48, w_fuse + (size_t)br*768, fusedCat, 48, br*16, 16, ACT_NONE);
    }
    // feat_all
    conv1(fusedCat, 48, 0, 48, w_liif, feat_all, 16, 0, 16, ACT_NONE);
    // LIIF MLP
    mlp_center_k<<<dim3(B*8192), dim3(256), 0, stream>>>(feat_all, mw_in, mb_in, mw_h, mb_h, mw_out, mb_out, fo);
    mlp_edge_k  <<<dim3(B*511),  dim3(256), 0, stream>>>(feat_all, mw_in, mb_in, mw_h, mb_h, mw_out, mb_out, fo);
    // final conv + lrms_up
    final_k<<<dim3(B*4*256), dim3(256), 0, stream>>>(fo, w_hp, lrms_up, out);
}

// Round 3
// 6097.079 us; speedup vs baseline: 2.1914x; 2.1914x over previous
//
#include <hip/hip_runtime.h>
#include <hip/hip_bf16.h>
#include <math.h>

#define ACT_NONE 0
#define ACT_RELU 1
#define ACT_GELU 2

typedef __attribute__((ext_vector_type(8))) short short8;
typedef __attribute__((ext_vector_type(4))) float float4v;

struct GK { float k[41]; };

__device__ __forceinline__ short f2bf(float f){
    __hip_bfloat16 h = __float2bfloat16(f);
    return *reinterpret_cast<short*>(&h);
}

// ---------------- pixel-shuffle conv: lrms (B,4,64,64) -> lrms_up (B,4,256,256) ----
__global__ __launch_bounds__(256) void conv_ps_k(const float* __restrict__ lrms,
                                                 const float* __restrict__ w,
                                                 float* __restrict__ up){
    int tid = threadIdx.x, bx = blockIdx.x;
    int y = bx & 255, c = (bx >> 8) & 3, b = bx >> 10;
    int x = tid;
    int h = y >> 2, r1 = y & 3, ww = x >> 2, r2 = x & 3;
    int oc = c*16 + r1*4 + r2;
    float acc = 0.f;
    for (int ic = 0; ic < 4; ++ic) {
        const float* base = lrms + ((b*4 + ic) << 12);
        const float* wb = w + (oc*4 + ic)*9;
        #pragma unroll
        for (int ky = 0; ky < 3; ++ky) {
            int hh = h + ky - 1; if (hh < 0 || hh > 63) continue;
            #pragma unroll
            for (int kx = 0; kx < 3; ++kx) {
                int cc = ww + kx - 1; if (cc < 0 || cc > 63) continue;
                acc += base[(hh<<6) + cc] * wb[ky*3 + kx];
            }
        }
    }
    up[(((long)(b*4 + c)) << 16) + (y<<8) + x] = acc;
}

// ---------------- gaussian blur (reflect pad), vertical pass --------------------
__global__ __launch_bounds__(256) void gauss_v_k(const float* __restrict__ src, int bstride,
                                                 float* __restrict__ out, GK gk, int ks){
    int tid = threadIdx.x, bx = blockIdx.x;
    int y = bx & 255, b = bx >> 8, p = ks >> 1;
    const float* s = src + (long)b * bstride;
    float acc = 0.f;
    for (int t = 0; t < ks; ++t) {
        int yy = y - p + t;
        yy = yy < 0 ? -yy : (yy > 255 ? 510 - yy : yy);
        acc += gk.k[t] * s[(yy<<8) + tid];
    }
    out[((long)bx << 8) + tid] = acc;
}
// horizontal pass + highpass
__global__ __launch_bounds__(256) void gauss_h_k(const float* __restrict__ blur,
                                                 const float* __restrict__ orig, int bstride,
                                                 float* __restrict__ feat5, int ch, GK gk, int ks){
    int tid = threadIdx.x, bx = blockIdx.x;
    int y = bx & 255, b = bx >> 8, p = ks >> 1, x = tid;
    const float* row = blur + ((long)b << 16) + (y<<8);
    float acc = 0.f;
    for (int t = 0; t < ks; ++t) {
        int xx = x - p + t;
        xx = xx < 0 ? -xx : (xx > 255 ? 510 - xx : xx);
        acc += gk.k[t] * row[xx];
    }
    float o = orig[(long)b*bstride + (y<<8) + x];
    feat5[(((long)(b*5 + ch)) << 16) + (y<<8) + x] = o - acc;
}

// ---------------- 3x3 SAME conv, 8 output channels per block --------------------
// Weights read via wave-uniform global addresses -> scalar loads (SGPR operand).
__global__ __launch_bounds__(256) void conv3x3g_k(const float* __restrict__ in, int inC, int inc0, int Cin,
                                                  const float* __restrict__ w,
                                                  float* __restrict__ out, int outC, int outc0, int Cout,
                                                  int act, int accum){
    int tid = threadIdx.x, bx = blockIdx.x;
    int G = Cout >> 3;
    int y = bx & 255;
    int g = (bx >> 8) % G;
    int b = bx / (G << 8);
    const float* wg = w + (size_t)(g*8) * Cin * 9;   // 8 contiguous oc blocks
    int x = tid;
    float acc[8];
    #pragma unroll
    for (int og = 0; og < 8; ++og) acc[og] = 0.f;
    for (int ic = 0; ic < Cin; ++ic) {
        const float* base = in + (((long)(b*inC + inc0 + ic)) << 16);
        #pragma unroll
        for (int ky = 0; ky < 3; ++ky) {
            int yy = y + ky - 1; if (yy < 0 || yy > 255) continue;
            const float* rowp = base + (yy<<8);
            float v0 = (x > 0)   ? rowp[x-1] : 0.f;
            float v1 = rowp[x];
            float v2 = (x < 255) ? rowp[x+1] : 0.f;
            const float* wr = wg + ic*9 + ky*3;
            #pragma unroll
            for (int og = 0; og < 8; ++og) {
                const float* wo = wr + og*Cin*9;
                acc[og] = fmaf(wo[0], v0, fmaf(wo[1], v1, fmaf(wo[2], v2, acc[og])));
            }
        }
    }
    #pragma unroll
    for (int og = 0; og < 8; ++og) {
        float a = acc[og];
        if (act == ACT_RELU) a = fmaxf(a, 0.f);
        else if (act == ACT_GELU) {
            float u = 0.7978845608028654f * (a + 0.044715f*a*a*a);
            a = 0.5f * a * (1.f + tanhf(u));
        }
        long oidx = (((long)(b*outC + outc0 + g*8 + og)) << 16) + (y<<8) + x;
        if (accum) out[oidx] += a; else out[oidx] = a;
    }
}

// ---------------- 1x1 conv over 256x256 ---------------------------------------
__global__ __launch_bounds__(256) void conv1x1_k(const float* __restrict__ in, int inC, int inc0, int Cin,
                                                 const float* __restrict__ w,
                                                 float* __restrict__ out, int outC, int outc0, int Cout,
                                                 int act){
    int tid = threadIdx.x, bx = blockIdx.x;
    int pt = bx & 255;
    int oc = (bx >> 8) % Cout;
    int b  = bx / (Cout << 8);
    __shared__ float wl[48];
    if (tid < Cin) wl[tid] = w[oc*Cin + tid];
    __syncthreads();
    int p = (pt << 8) + tid;
    float acc = 0.f;
    for (int ic = 0; ic < Cin; ++ic)
        acc += wl[ic] * in[(((long)(b*inC + inc0 + ic)) << 16) + p];
    if (act == ACT_RELU) acc = fmaxf(acc, 0.f);
    out[(((long)(b*outC + outc0 + oc)) << 16) + p] = acc;
}

// ---------------- spatial mean per (b,c) ----------------------------------------
__global__ __launch_bounds__(256) void mean_sp_k(const float* __restrict__ x, float* __restrict__ means){
    int tid = threadIdx.x, bc = blockIdx.x;
    const float* p = x + ((long)bc << 16);
    float s = 0.f;
    for (int i = tid; i < 65536; i += 256) s += p[i];
    __shared__ float sm[256];
    sm[tid] = s; __syncthreads();
    for (int st = 128; st > 0; st >>= 1) { if (tid < st) sm[tid] += sm[tid+st]; __syncthreads(); }
    if (tid == 0) means[bc] = sm[0] * (1.f/65536.f);
}

// ---------------- channel attention (tiny) -------------------------------------
__global__ void ca_k(const float* __restrict__ means, const float* __restrict__ w1,
                     const float* __restrict__ w2, float* __restrict__ ca){
    int t = threadIdx.x;
    if (t < 64) {
        int b = t >> 4, oc = t & 15;
        float hid[4];
        #pragma unroll
        for (int c2 = 0; c2 < 4; ++c2) {
            float a = 0.f;
            for (int c = 0; c < 16; ++c) a += w1[c2*16 + c] * means[b*16 + c];
            hid[c2] = fmaxf(a, 0.f);
        }
        float v = 0.f;
        #pragma unroll
        for (int c2 = 0; c2 < 4; ++c2) v += w2[oc*4 + c2] * hid[c2];
        ca[t] = 1.f / (1.f + expf(-v));
    }
}

// ---------------- y += bdy * ca[plane] -----------------------------------------
__global__ __launch_bounds__(256) void add_mul_ca_k(float* __restrict__ y, const float* __restrict__ bdy,
                                                    const float* __restrict__ ca, int n){
    int i = blockIdx.x*256 + threadIdx.x;
    if (i < n) y[i] += bdy[i] * ca[i >> 16];
}

// ---------------- FFT kernels (register-rotation DFT, ortho = 1/16 per axis) ----
// rfft along W: t_m = e^{-i*2*pi*u*m/256}; acc += v_m * t_m
__global__ __launch_bounds__(256) void rfft_w_k(const float* __restrict__ in, int inC, int inc0,
                                                float* __restrict__ ore, float* __restrict__ oim){
    int tid = threadIdx.x, bx = blockIdx.x;
    int y = bx & 255, c = (bx >> 8) & 7, b = bx >> 11;
    __shared__ __align__(16) float row[256];
    row[tid] = in[(((long)(b*inC + inc0 + c)) << 16) + (y<<8) + tid];
    __syncthreads();
    int u = tid;
    float th = -6.283185307179586f * (float)u / 256.f;
    float c1 = cosf(th), s1 = sinf(th);
    float c2 = c1*c1 - s1*s1, s2 = 2.f*c1*s1;
    float c3 = c2*c1 - s2*s1, s3 = c2*s1 + s2*c1;
    float c4 = c2*c2 - s2*s2, s4 = 2.f*c2*s2;
    float tr0=1.f, ti0=0.f, tr1=c1, ti1=s1, tr2=c2, ti2=s2, tr3=c3, ti3=s3;
    float re0=0,im0=0,re1=0,im1=0,re2=0,im2=0,re3=0,im3=0;
    for (int g = 0; g < 256; g += 4) {
        float4 v = *(const float4*)&row[g];
        re0 += v.x*tr0; im0 += v.x*ti0;
        re1 += v.y*tr1; im1 += v.y*ti1;
        re2 += v.z*tr2; im2 += v.z*ti2;
        re3 += v.w*tr3; im3 += v.w*ti3;
        float t;
        t = tr0*c4 - ti0*s4; ti0 = tr0*s4 + ti0*c4; tr0 = t;
        t = tr1*c4 - ti1*s4; ti1 = tr1*s4 + ti1*c4; tr1 = t;
        t = tr2*c4 - ti2*s4; ti2 = tr2*s4 + ti2*c4; tr2 = t;
        t = tr3*c4 - ti3*s4; ti3 = tr3*s4 + ti3*c4; tr3 = t;
    }
    if (u < 129) {
        long o = ((long)((b*8 + c)*256 + y)) * 129 + u;
        ore[o] = (re0+re1+re2+re3) * 0.0625f;
        oim[o] = (im0+im1+im2+im3) * 0.0625f;
    }
}
// c2c fft along H: t_y = e^{-i*sgn*2*pi*u*y/256}; acc += (r + i*im)*t
__global__ __launch_bounds__(256) void fft_h_k(const float* __restrict__ ire, const float* __restrict__ iim,
                                               float* __restrict__ ore, float* __restrict__ oim, float sgn){
    int tid = threadIdx.x, bx = blockIdx.x;
    int k = bx % 129; int t2 = bx / 129; int c = t2 & 7; int b = t2 >> 3;
    __shared__ __align__(16) float cr[256], ci[256];
    long base = ((long)(b*8 + c)) * 256 * 129 + k;
    cr[tid] = ire[base + (long)tid*129];
    ci[tid] = iim[base + (long)tid*129];
    __syncthreads();
    int u = tid;
    float th = -sgn * 6.283185307179586f * (float)u / 256.f;
    float c1 = cosf(th), s1 = sinf(th);
    float c2 = c1*c1 - s1*s1, s2 = 2.f*c1*s1;
    float c3 = c2*c1 - s2*s1, s3 = c2*s1 + s2*c1;
    float c4 = c2*c2 - s2*s2, s4 = 2.f*c2*s2;
    float tr0=1.f, ti0=0.f, tr1=c1, ti1=s1, tr2=c2, ti2=s2, tr3=c3, ti3=s3;
    float re0=0,im0=0,re1=0,im1=0,re2=0,im2=0,re3=0,im3=0;
    for (int g = 0; g < 256; g += 4) {
        float4 r4 = *(const float4*)&cr[g];
        float4 i4 = *(const float4*)&ci[g];
        re0 += r4.x*tr0 - i4.x*ti0;  im0 += i4.x*tr0 + r4.x*ti0;
        re1 += r4.y*tr1 - i4.y*ti1;  im1 += i4.y*tr1 + r4.y*ti1;
        re2 += r4.z*tr2 - i4.z*ti2;  im2 += i4.z*tr2 + r4.z*ti2;
        re3 += r4.w*tr3 - i4.w*ti3;  im3 += i4.w*tr3 + r4.w*ti3;
        float t;
        t = tr0*c4 - ti0*s4; ti0 = tr0*s4 + ti0*c4; tr0 = t;
        t = tr1*c4 - ti1*s4; ti1 = tr1*s4 + ti1*c4; tr1 = t;
        t = tr2*c4 - ti2*s4; ti2 = tr2*s4 + ti2*c4; tr2 = t;
        t = tr3*c4 - ti3*s4; ti3 = tr3*s4 + ti3*c4; tr3 = t;
    }
    ore[base + (long)u*129] = (re0+re1+re2+re3) * 0.0625f;
    oim[base + (long)u*129] = (im0+im1+im2+im3) * 0.0625f;
}
// c2r irfft along W: acc = sum_{k=0..127} 2*(vr*cos - vi*sin) - vr[0] + (-1)^m*vr[128]
__global__ __launch_bounds__(256) void irfft_w_acc_k(const float* __restrict__ ire, const float* __restrict__ iim,
                                                     float* __restrict__ out, int outC, int outc0){
    int tid = threadIdx.x, bx = blockIdx.x;
    int y = bx & 255, c = (bx >> 8) & 7, b = bx >> 11;
    __shared__ __align__(16) float vr[132], vi[132];
    if (tid < 129) {
        long base = ((long)((b*8 + c)*256 + y)) * 129;
        vr[tid] = ire[base + tid]; vi[tid] = iim[base + tid];
    }
    __syncthreads();
    int m = tid;
    float th = 6.283185307179586f * (float)m / 256.f;
    float c1 = cosf(th), s1 = sinf(th);
    float c2 = c1*c1 - s1*s1, s2 = 2.f*c1*s1;
    float c3 = c2*c1 - s2*s1, s3 = c2*s1 + s2*c1;
    float c4 = c2*c2 - s2*s2, s4 = 2.f*c2*s2;
    float tr0=1.f, ti0=0.f, tr1=c1, ti1=s1, tr2=c2, ti2=s2, tr3=c3, ti3=s3;
    float a0=0,a1=0,a2=0,a3=0;
    for (int g = 0; g < 128; g += 4) {
        float4 r4 = *(const float4*)&vr[g];
        float4 i4 = *(const float4*)&vi[g];
        a0 += r4.x*tr0 - i4.x*ti0;
        a1 += r4.y*tr1 - i4.y*ti1;
        a2 += r4.z*tr2 - i4.z*ti2;
        a3 += r4.w*tr3 - i4.w*ti3;
        float t;
        t = tr0*c4 - ti0*s4; ti0 = tr0*s4 + ti0*c4; tr0 = t;
        t = tr1*c4 - ti1*s4; ti1 = tr1*s4 + ti1*c4; tr1 = t;
        t = tr2*c4 - ti2*s4; ti2 = tr2*s4 + ti2*c4; tr2 = t;
        t = tr3*c4 - ti3*s4; ti3 = tr3*s4 + ti3*c4; tr3 = t;
    }
    float acc = 2.f*(a0+a1+a2+a3) - vr[0] + ((m & 1) ? -vr[128] : vr[128]);
    out[(((long)(b*outC + outc0 + c)) << 16) + (y<<8) + m] += acc * 0.0625f;
}
// 1x1 spectral conv + relu on (B, 2x8, 256x129)
__global__ __launch_bounds__(256) void spec_k(const float* __restrict__ re, const float* __restrict__ im,
                                              const float* __restrict__ w,
                                              float* __restrict__ ore, float* __restrict__ oim){
    int tid = threadIdx.x, bx = blockIdx.x;
    int pt = bx % 129; int oc = (bx / 129) & 15; int b = bx / (129*16);
    __shared__ float wl[256];
    wl[tid] = w[tid];
    __syncthreads();
    int p = (pt << 8) + tid;
    long pb = ((long)b) * 8 * 33024;
    float acc = 0.f;
    for (int ic = 0; ic < 8; ++ic)
        acc += re[pb + (long)ic*33024 + p] * wl[oc*16 + ic]
             + im[pb + (long)ic*33024 + p] * wl[oc*16 + 8 + ic];
    acc = fmaxf(acc, 0.f);
    if (oc < 8) ore[pb + (long)oc*33024 + p] = acc;
    else        oim[pb + (long)(oc-8)*33024 + p] = acc;
}

// ---------------- weight repack for MFMA MLP (fragment-contiguous bf16) ----------
// layout: [kt][nt][lane(64)][j(8)]; lane l: q=l>>4, n_l=l&15; k=kt*32+q*8+j; n=nt*16+n_l
__global__ __launch_bounds__(256) void repack_k(const float* __restrict__ mw_in,
                                                const float* __restrict__ mw_h,
                                                const float* __restrict__ mw_out,
                                                short* __restrict__ wp){
    int idx = blockIdx.x*256 + threadIdx.x;
    const int S0 = 40960;             // 5*16*64*8
    const int SH = 65536;             // 8*16*64*8 per hidden layer
    const int TOT = S0 + 3*SH + 4096;
    if (idx >= TOT) return;
    float val;
    if (idx < S0) {
        int j = idx & 7, l = (idx>>3) & 63, nt = (idx>>9) & 15, kt = idx >> 13;
        int k = kt*32 + (l>>4)*8 + j;
        int n = nt*16 + (l&15);
        val = (k < 148) ? mw_in[k*256 + n] : 0.f;
    } else if (idx < S0 + 3*SH) {
        int i2 = idx - S0;
        int L = i2 >> 16, r = i2 & 65535;
        int j = r & 7, l = (r>>3) & 63, nt = (r>>9) & 15, kt = r >> 13;
        int k = kt*32 + (l>>4)*8 + j;
        int n = nt*16 + (l&15);
        val = mw_h[L*65536 + k*256 + n];
    } else {
        int i3 = idx - S0 - 3*SH;
        int j = i3 & 7, l = (i3>>3) & 63, kt = i3 >> 9;
        int k = kt*32 + (l>>4)*8 + j;
        int oc = l & 15;
        val = mw_out[k*16 + oc];
    }
    wp[idx] = f2bf(val);
}

// ---------------- LIIF MLP via MFMA (center corner) ------------------------------
// block: 256 thr = 4 waves; 128 pixels/block (wave w owns rows [w*32, w*32+32))
// act in dynamic LDS: [128][264] bf16 (stride 264 shorts = 528B, 16B aligned)
__global__ __launch_bounds__(256) void mlp_mfma_k(const float* __restrict__ feat,
        const short* __restrict__ wp,          // packed weights (repack_k layout)
        const float* __restrict__ b_in, const float* __restrict__ b_h,
        const float* __restrict__ b_out,
        float* __restrict__ fo){
    extern __shared__ short act_s[];           // 128*264 shorts = 67584 B
    int tid = threadIdx.x, bx = blockIdx.x;
    long P0 = (long)bx * 128;
    // ---- fill inputs: 148 features (+pad to 160 with zeros; 146,147 = 2.0) ----
    for (int idx = tid; idx < 128*160; idx += 256) {
        int pp = idx / 160, j = idx - pp*160;
        long P = P0 + pp;
        int bb = (int)(P >> 16), pim = (int)(P & 65535);
        int s0 = pim >> 8, s1 = pim & 255;
        float v = 0.f;
        if (j < 144) {
            int iy = j/48, ix = (j>>4)%3, c2 = j&15;
            int yy = s0 + iy - 1, xx = s1 + ix - 1;
            v = (yy >= 0 && yy < 256 && xx >= 0 && xx < 256)
                ? feat[(((long)(bb*16 + c2)) << 16) + (yy<<8) + xx] : 0.f;
        } else if (j == 146 || j == 147) v = 2.f;
        act_s[pp*264 + j] = f2bf(v);
    }
    __syncthreads();   // only barrier; afterwards each wave touches only its rows

    int l = tid & 63, w = tid >> 6;
    int m_l = l & 15, q = l >> 4;
    int row0 = w * 32;
    const short* wph  = wp + 40960;
    const short* wpo  = wp + 40960 + 3*65536;

    float4v acc[2][16];
    // ======== layer 0: K=160 (5 kt), N=256 (16 nt) ========
    #pragma unroll
    for (int mt = 0; mt < 2; ++mt)
        #pragma unroll
        for (int nt = 0; nt < 16; ++nt) acc[mt][nt] = (float4v){0.f,0.f,0.f,0.f};
    for (int kt = 0; kt < 5; ++kt) {
        short8 a0 = *(const short8*)&act_s[(row0 + m_l)*264 + kt*32 + q*8];
        short8 a1 = *(const short8*)&act_s[(row0 + 16 + m_l)*264 + kt*32 + q*8];
        const short* bp = wp + ((size_t)(kt*16)*64 + l)*8;
        #pragma unroll
        for (int nt = 0; nt < 16; ++nt) {
            short8 bf = *(const short8*)(bp + (size_t)nt*64*8);
            acc[0][nt] = __builtin_amdgcn_mfma_f32_16x16x32_bf16(a0, bf, acc[0][nt], 0, 0, 0);
            acc[1][nt] = __builtin_amdgcn_mfma_f32_16x16x32_bf16(a1, bf, acc[1][nt], 0, 0, 0);
        }
    }
    #pragma unroll
    for (int nt = 0; nt < 16; ++nt) {
        float bias = b_in[nt*16 + m_l];
        #pragma unroll
        for (int mt = 0; mt < 2; ++mt)
            #pragma unroll
            for (int r = 0; r < 4; ++r) {
                float vv = fmaxf(acc[mt][nt][r] + bias, 0.f);
                act_s[(row0 + mt*16 + q*4 + r)*264 + nt*16 + m_l] = f2bf(vv);
            }
    }
    // ======== hidden layers 1..3: K=256 (8 kt), N=256 ========
    for (int L = 0; L < 3; ++L) {
        #pragma unroll
        for (int mt = 0; mt < 2; ++mt)
            #pragma unroll
            for (int nt = 0; nt < 16; ++nt) acc[mt][nt] = (float4v){0.f,0.f,0.f,0.f};
        const short* wl = wph + (size_t)L * 65536;
        for (int kt = 0; kt < 8; ++kt) {
            short8 a0 = *(const short8*)&act_s[(row0 + m_l)*264 + kt*32 + q*8];
            short8 a1 = *(const short8*)&act_s[(row0 + 16 + m_l)*264 + kt*32 + q*8];
            const short* bp = wl + ((size_t)(kt*16)*64 + l)*8;
            #pragma unroll
            for (int nt = 0; nt < 16; ++nt) {
                short8 bf = *(const short8*)(bp + (size_t)nt*64*8);
                acc[0][nt] = __builtin_amdgcn_mfma_f32_16x16x32_bf16(a0, bf, acc[0][nt], 0, 0, 0);
                acc[1][nt] = __builtin_amdgcn_mfma_f32_16x16x32_bf16(a1, bf, acc[1][nt], 0, 0, 0);
            }
        }
        #pragma unroll
        for (int nt = 0; nt < 16; ++nt) {
            float bias = b_h[L*256 + nt*16 + m_l];
            #pragma unroll
            for (int mt = 0; mt < 2; ++mt)
                #pragma unroll
                for (int r = 0; r < 4; ++r) {
                    float vv = fmaxf(acc[mt][nt][r] + bias, 0.f);
                    act_s[(row0 + mt*16 + q*4 + r)*264 + nt*16 + m_l] = f2bf(vv);
                }
        }
    }
    // ======== output layer: K=256 (8 kt), N=16 (1 nt) ========
    float4v o0 = (float4v){0.f,0.f,0.f,0.f}, o1 = (float4v){0.f,0.f,0.f,0.f};
    for (int kt = 0; kt < 8; ++kt) {
        short8 a0 = *(const short8*)&act_s[(row0 + m_l)*264 + kt*32 + q*8];
        short8 a1 = *(const short8*)&act_s[(row0 + 16 + m_l)*264 + kt*32 + q*8];
        short8 bf = *(const short8*)(wpo + ((size_t)kt*64 + l)*8);
        o0 = __builtin_amdgcn_mfma_f32_16x16x32_bf16(a0, bf, o0, 0, 0, 0);
        o1 = __builtin_amdgcn_mfma_f32_16x16x32_bf16(a1, bf, o1, 0, 0, 0);
    }
    float bias = b_out[m_l];
    #pragma unroll
    for (int mt = 0; mt < 2; ++mt) {
        float4v* op = mt ? &o1 : &o0;
        #pragma unroll
        for (int r = 0; r < 4; ++r) {
            long P = P0 + row0 + mt*16 + q*4 + r;
            int bb = (int)(P >> 16), pim = (int)(P & 65535);
            int s0 = pim >> 8, s1 = pim & 255;
            float w0 = (s0 == 255 || s1 == 255) ? 0.25f : 1.0f;
            fo[(((long)(bb*16 + m_l)) << 16) + pim] = w0 * ((*op)[r] + bias);
        }
    }
}

// ---------------- LIIF MLP: remaining 3 corners for edge pixels only (fp32) ------
__global__ __launch_bounds__(256) void mlp_edge_k(const float* __restrict__ feat,
        const float* __restrict__ w_in, const float* __restrict__ b_in,
        const float* __restrict__ w_h,  const float* __restrict__ b_h,
        const float* __restrict__ w_out,const float* __restrict__ b_out,
        float* __restrict__ fo){
    int tid = threadIdx.x, bx = blockIdx.x;
    int b = bx / 511, e = bx % 511;
    int s0 = (e < 256) ? 255 : (e - 256);
    int s1 = (e < 256) ? e : 255;
    __shared__ float inp[148], h0[256], h1[256];
    const int vxs[3] = {-1, 1, 1};
    const int vys[3] = { 1,-1, 1};
    float outacc = 0.f;
    for (int cn = 0; cn < 3; ++cn) {
        int i0 = vxs[cn] > 0 ? min(s0+1, 255) : s0;
        int i1 = vys[cn] > 0 ? min(s1+1, 255) : s1;
        float rel0 = 2.f * (float)(s0 - i0);
        float rel1 = 2.f * (float)(s1 - i1);
        if (tid < 148) {
            int j = tid; float v;
            if (j < 144) {
                int iy = j / 48, ix = (j >> 4) % 3, c = j & 15;
                int yy = i0 + iy - 1, xx = i1 + ix - 1;
                v = (yy >= 0 && yy < 256 && xx >= 0 && xx < 256)
                    ? feat[(((long)(b*16 + c)) << 16) + (yy<<8) + xx] : 0.f;
            } else if (j == 144) v = rel0;
            else if (j == 145) v = rel1;
            else v = 2.f;
            inp[j] = v;
        }
        __syncthreads();
        float a = 0.f;
        for (int j = 0; j < 148; ++j) a += w_in[j*256 + tid] * inp[j];
        h0[tid] = fmaxf(a + b_in[tid], 0.f);
        __syncthreads();
        for (int L = 0; L < 3; ++L) {
            const float* W = w_h + L*65536;
            float* hin  = (L & 1) ? h1 : h0;
            float* hout = (L & 1) ? h0 : h1;
            float s = 0.f;
            for (int j = 0; j < 256; ++j) s += W[j*256 + tid] * hin[j];
            hout[tid] = fmaxf(s + b_h[L*256 + tid], 0.f);
            __syncthreads();
        }
        if (tid < 16) {
            float o = b_out[tid];
            for (int j = 0; j < 256; ++j) o += h1[j] * w_out[j*16 + tid];
            outacc += 0.25f * o;
        }
        __syncthreads();
    }
    if (tid < 16) {
        int p = (s0 << 8) + s1;
        fo[(((long)(b*16 + tid)) << 16) + p] += outacc;
    }
}

// ---------------- final conv (16->4, 3x3) + lrms_up ------------------------------
__global__ __launch_bounds__(256) void final_k(const float* __restrict__ fo, const float* __restrict__ w,
                                               const float* __restrict__ lrms_up, float* __restrict__ out){
    int tid = threadIdx.x, bx = blockIdx.x;
    int y = bx & 255, oc = (bx >> 8) & 3, b = bx >> 10;
    int x = tid;
    const float* wg = w + (size_t)oc * 144;
    float acc = 0.f;
    for (int ic = 0; ic < 16; ++ic) {
        const float* base = fo + (((long)(b*16 + ic)) << 16);
        #pragma unroll
        for (int ky = 0; ky < 3; ++ky) {
            int yy = y + ky - 1; if (yy < 0 || yy > 255) continue;
            const float* rowp = base + (yy<<8);
            float v0 = (x > 0)   ? rowp[x-1] : 0.f;
            float v1 = rowp[x];
            float v2 = (x < 255) ? rowp[x+1] : 0.f;
            const float* wr = wg + ic*9 + ky*3;
            acc = fmaf(wr[0], v0, fmaf(wr[1], v1, fmaf(wr[2], v2, acc)));
        }
    }
    long oidx = (((long)(b*4 + oc)) << 16) + (y<<8) + x;
    out[oidx] = acc + lrms_up[oidx];
}

// ================================================================================
static void make_gk(GK& g, int ks, double sigma){
    double tmp[41]; double s = 0.0; double c = (ks - 1) / 2.0;
    for (int i = 0; i < ks; ++i) { double d = i - c; tmp[i] = exp(-(d*d)/(2.0*sigma*sigma)); s += tmp[i]; }
    for (int i = 0; i < ks; ++i) g.k[i] = (float)(tmp[i]/s);
    for (int i = ks; i < 41; ++i) g.k[i] = 0.f;
}

extern "C" void kernel_launch(void* const* d_in, const int* in_sizes, int n_in,
                              void* d_out, int out_size, void* d_ws, size_t ws_size,
                              hipStream_t stream) {
    const float* lrms     = (const float*)d_in[0];
    const float* pan      = (const float*)d_in[1];
    const float* w_convps = (const float*)d_in[2];
    const float* hor_w1   = (const float*)d_in[3];
    const float* hor_w2   = (const float*)d_in[4];
    const float* ffc_l2l  = (const float*)d_in[5];
    const float* ffc_l2g  = (const float*)d_in[6];
    const float* ffc_g2l  = (const float*)d_in[7];
    const float* ffc_spec = (const float*)d_in[8];
    const float* ref_in   = (const float*)d_in[9];
    const float* ref_b1   = (const float*)d_in[10];
    const float* ref_b2   = (const float*)d_in[11];
    const float* ref_ca1  = (const float*)d_in[12];
    const float* ref_ca2  = (const float*)d_in[13];
    const float* ref_out  = (const float*)d_in[14];
    const float* w_fuse   = (const float*)d_in[15];
    const float* w_liif   = (const float*)d_in[16];
    const float* w_hp     = (const float*)d_in[17];
    const float* mw_in    = (const float*)d_in[18];
    const float* mb_in    = (const float*)d_in[19];
    const float* mw_h     = (const float*)d_in[20];
    const float* mb_h     = (const float*)d_in[21];
    const float* mw_out   = (const float*)d_in[22];
    const float* mb_out   = (const float*)d_in[23];
    float* out = (float*)d_out;

    const int B = 4;
    const long PIX = 65536;
    float* ws = (float*)d_ws;
    size_t off = 0;
    auto alloc = [&](size_t n){ float* p = ws + off; off += n; return p; };
    float* lrms_up  = alloc((size_t)B*4*PIX);
    float* f012     = alloc((size_t)B*48*PIX);
    float* fusedCat = alloc((size_t)B*48*PIX);
    float* feat_all = alloc((size_t)B*16*PIX);
    float* fo       = alloc((size_t)B*16*PIX);
    float* feat5    = alloc((size_t)B*5*PIX);
    float* tA       = alloc((size_t)B*16*PIX);
    float* tB       = alloc((size_t)B*16*PIX);
    float* tC       = alloc((size_t)B*16*PIX);
    float* blur1    = alloc((size_t)B*PIX);
    size_t fftsz = (size_t)B*8*256*129;
    float* re0 = alloc(fftsz); float* im0 = alloc(fftsz);
    float* re1 = alloc(fftsz); float* im1 = alloc(fftsz);
    float* means = alloc(64); float* ca = alloc(64);
    short* wpack = (short*)alloc(120832);   // 241664 bf16 shorts
    if (off * sizeof(float) > ws_size) return;

    auto conv3 = [&](const float* in, int inC, int inc0, int Cin, const float* w,
                     float* o, int outC, int outc0, int Cout, int act, int accum){
        conv3x3g_k<<<dim3(B*(Cout>>3)*256), dim3(256), 0, stream>>>(in, inC, inc0, Cin, w, o, outC, outc0, Cout, act, accum);
    };
    auto conv1 = [&](const float* in, int inC, int inc0, int Cin, const float* w,
                     float* o, int outC, int outc0, int Cout, int act){
        conv1x1_k<<<dim3(B*Cout*256), dim3(256), 0, stream>>>(in, inC, inc0, Cin, w, o, outC, outc0, Cout, act);
    };
    auto do_refine = [&](float* x, float* t1, float* t2, int ri, int outc0){
        conv3(x, 16, 0, 16, ref_in + (size_t)ri*2304, t1, 16, 0, 16, ACT_NONE, 0);  // y
        conv3(t1, 16, 0, 16, ref_b1 + (size_t)ri*2304, t2, 16, 0, 16, ACT_RELU, 0);
        conv3(t2, 16, 0, 16, ref_b2 + (size_t)ri*2304, x, 16, 0, 16, ACT_NONE, 0);  // bdy
        mean_sp_k<<<dim3(64), dim3(256), 0, stream>>>(x, means);
        ca_k<<<dim3(1), dim3(64), 0, stream>>>(means, ref_ca1 + (size_t)ri*64, ref_ca2 + (size_t)ri*64, ca);
        add_mul_ca_k<<<dim3(16384), dim3(256), 0, stream>>>(t1, x, ca, B*16*65536);
        conv3(t1, 16, 0, 16, ref_out + (size_t)ri*2304, f012, 48, outc0, 16, ACT_NONE, 0);
    };
    auto do_ffc = [&](int base, int wi){
        conv3(f012, 48, base,   8, ffc_l2g + (size_t)wi*576, tA, 16, 0, 8, ACT_NONE, 0);
        conv3(f012, 48, base,   8, ffc_l2l + (size_t)wi*576, tA, 16, 8, 8, ACT_NONE, 0);
        conv3(f012, 48, base+8, 8, ffc_g2l + (size_t)wi*576, tA, 16, 8, 8, ACT_NONE, 1);
        rfft_w_k<<<dim3(B*8*256), dim3(256), 0, stream>>>(f012, 48, base+8, re0, im0);
        fft_h_k <<<dim3(B*8*129), dim3(256), 0, stream>>>(re0, im0, re1, im1, 1.f);
        spec_k  <<<dim3(B*16*129), dim3(256), 0, stream>>>(re1, im1, ffc_spec + (size_t)wi*256, re0, im0);
        fft_h_k <<<dim3(B*8*129), dim3(256), 0, stream>>>(re0, im0, re1, im1, -1.f);
        irfft_w_acc_k<<<dim3(B*8*256), dim3(256), 0, stream>>>(re1, im1, tA, 16, 0);
    };

    // weight repack for MFMA MLP (independent of everything until mlp)
    repack_k<<<dim3(944), dim3(256), 0, stream>>>(mw_in, mw_h, mw_out, wpack);

    conv_ps_k<<<dim3(B*4*256), dim3(256), 0, stream>>>(lrms, w_convps, lrms_up);
    hipMemsetAsync(feat5, 0, (size_t)B*5*PIX*sizeof(float), stream);

    const int kss[3] = {5, 27, 41};
    const double sgs[3] = {1.5, 2.0, 2.8};
    for (int br = 0; br < 3; ++br) {
        GK gk; make_gk(gk, kss[br], sgs[br]);
        int ks = kss[br];
        gauss_v_k<<<dim3(B*256), dim3(256), 0, stream>>>(pan, 65536, blur1, gk, ks);
        gauss_h_k<<<dim3(B*256), dim3(256), 0, stream>>>(blur1, pan, 65536, feat5, 0, gk, ks);
        gauss_v_k<<<dim3(B*256), dim3(256), 0, stream>>>(lrms_up, 4*65536, blur1, gk, ks);
        gauss_h_k<<<dim3(B*256), dim3(256), 0, stream>>>(blur1, lrms_up, 4*65536, feat5, 1, gk, ks);
        conv3(feat5, 5, 0, 5, hor_w1 + (size_t)br*720, tA, 16, 0, 16, ACT_GELU, 0);
        conv3(tA, 16, 0, 16, hor_w2 + (size_t)br*2304, tB, 16, 0, 16, ACT_NONE, 0);
        do_refine(tB, tC, tA, 3*br + 0, 0);
        do_ffc(0, 2*br + 0);
        do_refine(tA, tC, tB, 3*br + 1, 16);
        do_ffc(16, 2*br + 1);
        do_refine(tA, tC, tB, 3*br + 2, 32);
        conv1(f012, 48, 0, 48, w_fuse + (size_t)br*768, fusedCat, 48, br*16, 16, ACT_NONE);
    }
    conv1(fusedCat, 48, 0, 48, w_liif, feat_all, 16, 0, 16, ACT_NONE);
    // LIIF MLP: MFMA center + fp32 edges
    mlp_mfma_k<<<dim3(2048), dim3(256), 128*264*2, stream>>>(feat_all, wpack, mb_in, mb_h, mb_out, fo);
    mlp_edge_k<<<dim3(B*511), dim3(256), 0, stream>>>(feat_all, mw_in, mb_in, mw_h, mb_h, mw_out, mb_out, fo);
    final_k<<<dim3(B*4*256), dim3(256), 0, stream>>>(fo, w_hp, lrms_up, out);
}

// Round 4
// 3019.476 us; speedup vs baseline: 4.4250x; 2.0193x over previous
//
#include <hip/hip_runtime.h>
#include <hip/hip_bf16.h>
#include <math.h>

typedef __hip_bfloat16 bf16;
typedef __attribute__((ext_vector_type(8))) short short8;
typedef __attribute__((ext_vector_type(4))) float float4v;

#define ACT_NONE 0
#define ACT_RELU 1
#define ACT_GELU 2

__device__ __forceinline__ float b2f(bf16 v){ return __bfloat162float(v); }
__device__ __forceinline__ bf16  f2b(float f){ return __float2bfloat16(f); }
__device__ __forceinline__ short f2bs(float f){ bf16 h = __float2bfloat16(f); return *reinterpret_cast<short*>(&h); }
__device__ __forceinline__ void rotc(float& tr, float& ti, float cr, float ci){
    float t = tr*cr - ti*ci; ti = tr*ci + ti*cr; tr = t;
}

struct GK3 { float k[3][41]; int ks[3]; };

// ---------------- pixel-shuffle conv: lrms (B,4,64,64) -> lrms_up fp32 (B,4,256,256)
__global__ __launch_bounds__(256) void conv_ps_k(const float* __restrict__ lrms,
                                                 const float* __restrict__ w,
                                                 float* __restrict__ up){
    int tid = threadIdx.x, bx = blockIdx.x;
    int y = bx & 255, c = (bx >> 8) & 3, b = bx >> 10;
    int x = tid;
    int h = y >> 2, r1 = y & 3, ww = x >> 2, r2 = x & 3;
    int oc = c*16 + r1*4 + r2;
    float acc = 0.f;
    for (int ic = 0; ic < 4; ++ic) {
        const float* base = lrms + ((b*4 + ic) << 12);
        const float* wb = w + (oc*4 + ic)*9;
        #pragma unroll
        for (int ky = 0; ky < 3; ++ky) {
            int hh = h + ky - 1; if (hh < 0 || hh > 63) continue;
            #pragma unroll
            for (int kx = 0; kx < 3; ++kx) {
                int cc = ww + kx - 1; if (cc < 0 || cc > 63) continue;
                acc += base[(hh<<6) + cc] * wb[ky*3 + kx];
            }
        }
    }
    up[(((size_t)(b*4 + c)) << 16) + (y<<8) + x] = acc;
}

// ---------------- fused gaussian highpass (v+h, reflect), lockstep 3br x 2src ----
// feat2[br][b][src] = orig - blur ; bf16 out
__global__ __launch_bounds__(256) void gauss_hp_k(const float* __restrict__ pan,
                                                  const float* __restrict__ lrms_up,
                                                  bf16* __restrict__ feat2, GK3 g){
    int tid = threadIdx.x, bx = blockIdx.x;
    int y = bx & 255, b = (bx >> 8) & 3, src = (bx >> 10) & 1, br = bx >> 11;
    int ks = g.ks[br], p = ks >> 1;
    const float* gk = g.k[br];
    const float* s = src ? (lrms_up + (size_t)b*4*65536) : (pan + (size_t)b*65536);
    __shared__ float vext[296];
    for (int i = tid; i < 296; i += 256) {
        int xe = i - 20; int xr = xe < 0 ? -xe : (xe > 255 ? 510 - xe : xe);
        float acc = 0.f;
        for (int t = 0; t < ks; ++t) {
            int yy = y - p + t; yy = yy < 0 ? -yy : (yy > 255 ? 510 - yy : yy);
            acc += gk[t] * s[(yy<<8) + xr];
        }
        vext[i] = acc;
    }
    __syncthreads();
    int x = tid;
    float acc = 0.f;
    for (int t = 0; t < ks; ++t) acc += gk[t] * vext[x - p + t + 20];
    float o = s[(y<<8) + x];
    feat2[(((size_t)((br*4 + b)*2 + src)) << 16) + (y<<8) + x] = f2b(o - acc);
}

// ---------------- 3x3 conv, bf16 in/out, 16 oc per block, lockstep branches ------
// grid 3072: row=bx&255, b=(bx>>8)&3, br=bx>>10.  weights fp32, wave-uniform.
__global__ __launch_bounds__(256) void convA_k(const bf16* __restrict__ in, int inCper, int Cin,
                                               const float* __restrict__ wbase, int wbrstride, int wocstride,
                                               bf16* __restrict__ out, int act, float* means){
    int tid = threadIdx.x, bx = blockIdx.x;
    int y = bx & 255, b = (bx >> 8) & 3, br = bx >> 10;
    const float* w = wbase + (size_t)br * wbrstride;
    int x = tid;
    float acc[16];
    #pragma unroll
    for (int oc = 0; oc < 16; ++oc) acc[oc] = 0.f;
    for (int ic = 0; ic < Cin; ++ic) {
        const bf16* base = in + ((size_t)((br*4 + b)*inCper + ic) << 16);
        const float* wic = w + ic*9;
        #pragma unroll
        for (int ky = 0; ky < 3; ++ky) {
            int yy = y + ky - 1; if (yy < 0 || yy > 255) continue;
            const bf16* rowp = base + (yy<<8);
            float v0 = (x > 0)   ? b2f(rowp[x-1]) : 0.f;
            float v1 = b2f(rowp[x]);
            float v2 = (x < 255) ? b2f(rowp[x+1]) : 0.f;
            const float* wr = wic + ky*3;
            #pragma unroll
            for (int oc = 0; oc < 16; ++oc) {
                const float* wo = wr + oc*wocstride;
                acc[oc] = fmaf(wo[0], v0, fmaf(wo[1], v1, fmaf(wo[2], v2, acc[oc])));
            }
        }
    }
    if (means) {   // block-partial spatial sums of pre-act output (bdy)
        __shared__ float sm[4][16];
        int wv = tid >> 6, lane = tid & 63;
        #pragma unroll
        for (int oc = 0; oc < 16; ++oc) {
            float v = acc[oc];
            for (int off = 32; off; off >>= 1) v += __shfl_down(v, off, 64);
            if (lane == 0) sm[wv][oc] = v;
        }
        __syncthreads();
        if (tid < 16) atomicAdd(&means[br*64 + b*16 + tid],
                                sm[0][tid] + sm[1][tid] + sm[2][tid] + sm[3][tid]);
    }
    #pragma unroll
    for (int oc = 0; oc < 16; ++oc) {
        float a = acc[oc];
        if (act == ACT_RELU) a = fmaxf(a, 0.f);
        else if (act == ACT_GELU) {
            float u = 0.7978845608028654f * (a + 0.044715f*a*a*a);
            a = 0.5f * a * (1.f + tanhf(u));
        }
        out[((size_t)((br*4 + b)*16 + oc) << 16) + (y<<8) + x] = f2b(a);
    }
}

// ---------------- refine output conv: in = Y + BDY*ca (on the fly), + fuse 1x1 ---
__global__ __launch_bounds__(256) void convOut_k(const bf16* __restrict__ Y, const bf16* __restrict__ BDY,
                                                 const float* __restrict__ cav, const float* __restrict__ wout,
                                                 const float* __restrict__ wfuse, int step,
                                                 bf16* __restrict__ F, bf16* __restrict__ fusedCat){
    int tid = threadIdx.x, bx = blockIdx.x;
    int y = bx & 255, b = (bx >> 8) & 3, br = bx >> 10;
    const float* w = wout + (size_t)br * 6912;
    float cc[16];
    #pragma unroll
    for (int ic = 0; ic < 16; ++ic) cc[ic] = cav[br*64 + b*16 + ic];
    int x = tid;
    float acc[16];
    #pragma unroll
    for (int oc = 0; oc < 16; ++oc) acc[oc] = 0.f;
    for (int ic = 0; ic < 16; ++ic) {
        size_t plane = (size_t)((br*4 + b)*16 + ic) << 16;
        const bf16* yb = Y + plane; const bf16* db = BDY + plane;
        float c0 = cc[ic];
        const float* wic = w + ic*9;
        #pragma unroll
        for (int ky = 0; ky < 3; ++ky) {
            int yy = y + ky - 1; if (yy < 0 || yy > 255) continue;
            const bf16* yr = yb + (yy<<8); const bf16* dr = db + (yy<<8);
            float v0 = (x > 0)   ? fmaf(b2f(dr[x-1]), c0, b2f(yr[x-1])) : 0.f;
            float v1 = fmaf(b2f(dr[x]), c0, b2f(yr[x]));
            float v2 = (x < 255) ? fmaf(b2f(dr[x+1]), c0, b2f(yr[x+1])) : 0.f;
            const float* wr = wic + ky*3;
            #pragma unroll
            for (int oc = 0; oc < 16; ++oc) {
                const float* wo = wr + oc*144;
                acc[oc] = fmaf(wo[0], v0, fmaf(wo[1], v1, fmaf(wo[2], v2, acc[oc])));
            }
        }
    }
    #pragma unroll
    for (int oc = 0; oc < 16; ++oc)
        F[((size_t)((br*4 + b)*16 + oc) << 16) + (y<<8) + x] = f2b(acc[oc]);
    const float* wf = wfuse + br*768 + step*16;
    #pragma unroll
    for (int oc2 = 0; oc2 < 16; ++oc2) {
        float s = 0.f;
        #pragma unroll
        for (int oc = 0; oc < 16; ++oc) s += wf[oc2*48 + oc] * acc[oc];
        size_t fidx = ((size_t)(b*48 + br*16 + oc2) << 16) + (y<<8) + x;
        if (step == 0) fusedCat[fidx] = f2b(s);
        else           fusedCat[fidx] = f2b(b2f(fusedCat[fidx]) + s);
    }
}

// ---------------- channel attention, lockstep; also rezeros means ---------------
__global__ void ca_k(float* __restrict__ means, const float* __restrict__ ca1,
                     const float* __restrict__ ca2, int step, float* __restrict__ cav){
    int t = threadIdx.x;  // 192
    int br = t >> 6, rem = t & 63, b = rem >> 4, oc = rem & 15;
    int ri = 3*br + step;
    const float* w1 = ca1 + ri*64; const float* w2 = ca2 + ri*64;
    float hid[4];
    #pragma unroll
    for (int c2 = 0; c2 < 4; ++c2) {
        float a = 0.f;
        for (int c = 0; c < 16; ++c) a += w1[c2*16 + c] * (means[br*64 + b*16 + c] * (1.f/65536.f));
        hid[c2] = fmaxf(a, 0.f);
    }
    float v = 0.f;
    #pragma unroll
    for (int c2 = 0; c2 < 4; ++c2) v += w2[oc*4 + c2] * hid[c2];
    cav[t] = 1.f / (1.f + expf(-v));
    __syncthreads();
    means[t] = 0.f;
}

// ---------------- radix-16 DFT kernels (256-pt, ortho 1/16 per axis), bf16 IO ---
__global__ __launch_bounds__(256) void rfft_w_k(const bf16* __restrict__ F,
                                                bf16* __restrict__ ore, bf16* __restrict__ oim){
    int tid = threadIdx.x, bx = blockIdx.x;
    int y = bx & 255, c = (bx >> 8) & 7, b = (bx >> 11) & 3, br = bx >> 13;
    __shared__ float row[256], Ar[256], Ai[256];
    row[tid] = b2f(F[((size_t)((br*4 + b)*16 + 8 + c) << 16) + (y<<8) + tid]);
    __syncthreads();
    int n1 = tid >> 4, k1 = tid & 15;
    float a1 = -6.283185307179586f * (float)k1 / 16.f;
    float c1, s1; __sincosf(a1, &s1, &c1);
    float twr = 1.f, twi = 0.f, ar = 0.f, ai = 0.f;
    #pragma unroll
    for (int n2 = 0; n2 < 16; ++n2) {
        float xr = row[n1 + (n2<<4)];
        ar = fmaf(xr, twr, ar); ai = fmaf(xr, twi, ai);
        rotc(twr, twi, c1, s1);
    }
    Ar[tid] = ar; Ai[tid] = ai;
    __syncthreads();
    int k = tid, kk1 = k & 15;
    float a2 = -6.283185307179586f * (float)k / 256.f;
    float c2v, s2v; __sincosf(a2, &s2v, &c2v);
    float t2r = 1.f, t2i = 0.f, re = 0.f, im = 0.f;
    #pragma unroll
    for (int m = 0; m < 16; ++m) {
        float r = Ar[(m<<4) + kk1], i = Ai[(m<<4) + kk1];
        re += r*t2r - i*t2i; im += i*t2r + r*t2i;
        rotc(t2r, t2i, c2v, s2v);
    }
    if (k < 129) {
        size_t o = ((size_t)(((br*4 + b)*8 + c)*256 + y))*129 + k;
        ore[o] = f2b(re * 0.0625f); oim[o] = f2b(im * 0.0625f);
    }
}

__global__ __launch_bounds__(256) void fft_h_k(bf16* __restrict__ re, bf16* __restrict__ im, float sgn){
    int tid = threadIdx.x, bx = blockIdx.x;
    int k = bx % 129; int r2 = bx / 129; int c = r2 & 7, b = (r2 >> 3) & 3, br = r2 >> 5;
    __shared__ float cr[256], ci[256], Ar[256], Ai[256];
    size_t base = ((size_t)(((br*4 + b)*8 + c)*256))*129 + k;
    cr[tid] = b2f(re[base + (size_t)tid*129]);
    ci[tid] = b2f(im[base + (size_t)tid*129]);
    __syncthreads();
    int n1 = tid >> 4, k1 = tid & 15;
    float a1 = -sgn * 6.283185307179586f * (float)k1 / 16.f;
    float c1, s1; __sincosf(a1, &s1, &c1);
    float twr = 1.f, twi = 0.f, ar = 0.f, ai = 0.f;
    #pragma unroll
    for (int n2 = 0; n2 < 16; ++n2) {
        float r = cr[n1 + (n2<<4)], i = ci[n1 + (n2<<4)];
        ar += r*twr - i*twi; ai += i*twr + r*twi;
        rotc(twr, twi, c1, s1);
    }
    Ar[tid] = ar; Ai[tid] = ai;
    __syncthreads();
    int u = tid, uk1 = u & 15;
    float a2 = -sgn * 6.283185307179586f * (float)u / 256.f;
    float c2v, s2v; __sincosf(a2, &s2v, &c2v);
    float t2r = 1.f, t2i = 0.f, racc = 0.f, iacc = 0.f;
    #pragma unroll
    for (int m = 0; m < 16; ++m) {
        float r = Ar[(m<<4) + uk1], i = Ai[(m<<4) + uk1];
        racc += r*t2r - i*t2i; iacc += i*t2r + r*t2i;
        rotc(t2r, t2i, c2v, s2v);
    }
    re[base + (size_t)u*129] = f2b(racc * 0.0625f);
    im[base + (size_t)u*129] = f2b(iacc * 0.0625f);
}

// c2r irfft along W (Hermitian ext, imag of bins 0/128 ignored), += into A ch0..7
__global__ __launch_bounds__(256) void irfft_w_k(const bf16* __restrict__ re1, const bf16* __restrict__ im1,
                                                 bf16* __restrict__ A){
    int tid = threadIdx.x, bx = blockIdx.x;
    int y = bx & 255, c = (bx >> 8) & 7, b = (bx >> 11) & 3, br = bx >> 13;
    __shared__ float cr[256], ci[256], Ar[256], Ai[256];
    size_t base = ((size_t)(((br*4 + b)*8 + c)*256 + y))*129;
    if (tid < 129) {
        cr[tid] = b2f(re1[base + tid]);
        ci[tid] = (tid == 0 || tid == 128) ? 0.f : b2f(im1[base + tid]);
    }
    __syncthreads();
    if (tid >= 129) { cr[tid] = cr[256 - tid]; ci[tid] = -ci[256 - tid]; }
    __syncthreads();
    int n1 = tid >> 4, k1 = tid & 15;
    float a1 = 6.283185307179586f * (float)k1 / 16.f;   // inverse: e^{+i}
    float c1, s1; __sincosf(a1, &s1, &c1);
    float twr = 1.f, twi = 0.f, ar = 0.f, ai = 0.f;
    #pragma unroll
    for (int n2 = 0; n2 < 16; ++n2) {
        float r = cr[n1 + (n2<<4)], i = ci[n1 + (n2<<4)];
        ar += r*twr - i*twi; ai += i*twr + r*twi;
        rotc(twr, twi, c1, s1);
    }
    Ar[tid] = ar; Ai[tid] = ai;
    __syncthreads();
    int m = tid, mk1 = m & 15;
    float a2 = 6.283185307179586f * (float)m / 256.f;
    float c2v, s2v; __sincosf(a2, &s2v, &c2v);
    float t2r = 1.f, t2i = 0.f, racc = 0.f;
    #pragma unroll
    for (int q = 0; q < 16; ++q) {
        float r = Ar[(q<<4) + mk1], i = Ai[(q<<4) + mk1];
        racc += r*t2r - i*t2i;
        rotc(t2r, t2i, c2v, s2v);
    }
    size_t o = ((size_t)((br*4 + b)*16 + c) << 16) + (y<<8) + m;
    A[o] = f2b(b2f(A[o]) + racc * 0.0625f);
}

// ---------------- 1x1 spectral conv + relu, bf16 IO, lockstep --------------------
__global__ __launch_bounds__(256) void spec_k(const bf16* __restrict__ re0, const bf16* __restrict__ im0,
                                              const float* __restrict__ wspec, int step,
                                              bf16* __restrict__ re1, bf16* __restrict__ im1){
    int tid = threadIdx.x, bx = blockIdx.x;
    int pt = bx % 129; int r2 = bx / 129; int oc = r2 & 15, b = (r2 >> 4) & 3, br = r2 >> 6;
    const float* wl = wspec + (2*br + step)*256;
    int p = pt*256 + tid;
    size_t pb = (size_t)((br*4 + b)*8) * 33024;
    float acc = 0.f;
    #pragma unroll
    for (int ic = 0; ic < 8; ++ic)
        acc += b2f(re0[pb + (size_t)ic*33024 + p]) * wl[oc*16 + ic]
             + b2f(im0[pb + (size_t)ic*33024 + p]) * wl[oc*16 + 8 + ic];
    acc = fmaxf(acc, 0.f);
    if (oc < 8) re1[pb + (size_t)oc*33024 + p] = f2b(acc);
    else        im1[pb + (size_t)(oc-8)*33024 + p] = f2b(acc);
}

// ---------------- pack combined ffc conv weights (6 x 16 x 16 x 9) ---------------
__global__ __launch_bounds__(256) void pack_ffcw_k(const float* __restrict__ l2l, const float* __restrict__ l2g,
                                                   const float* __restrict__ g2l, float* __restrict__ wout){
    int idx = blockIdx.x*256 + threadIdx.x;
    if (idx >= 6*2304) return;
    int t = idx % 9; int ic = (idx/9) % 16; int oc = (idx/144) % 16; int wi = idx/2304;
    float v;
    if (oc < 8) v = (ic < 8) ? l2g[((wi*8 + oc)*8 + ic)*9 + t] : 0.f;
    else {
        int o = oc - 8;
        v = (ic < 8) ? l2l[((wi*8 + o)*8 + ic)*9 + t] : g2l[((wi*8 + o)*8 + (ic-8))*9 + t];
    }
    wout[idx] = v;
}

// ---------------- fuse 1x1 (48->16), bf16 in/out ---------------------------------
__global__ __launch_bounds__(256) void fuse1x1_k(const bf16* __restrict__ fc, const float* __restrict__ wl,
                                                 bf16* __restrict__ feat_all){
    int tid = threadIdx.x, bx = blockIdx.x;
    int pt = bx & 255, b = bx >> 8;
    int p = (pt << 8) + tid;
    float acc[16];
    #pragma unroll
    for (int oc = 0; oc < 16; ++oc) acc[oc] = 0.f;
    for (int ic = 0; ic < 48; ++ic) {
        float v = b2f(fc[((size_t)(b*48 + ic) << 16) + p]);
        #pragma unroll
        for (int oc = 0; oc < 16; ++oc) acc[oc] = fmaf(wl[oc*48 + ic], v, acc[oc]);
    }
    #pragma unroll
    for (int oc = 0; oc < 16; ++oc)
        feat_all[((size_t)(b*16 + oc) << 16) + p] = f2b(acc[oc]);
}

// ---------------- MLP weight repack (fragment-contiguous bf16) -------------------
__global__ __launch_bounds__(256) void repack_k(const float* __restrict__ mw_in,
                                                const float* __restrict__ mw_h,
                                                const float* __restrict__ mw_out,
                                                short* __restrict__ wp){
    int idx = blockIdx.x*256 + threadIdx.x;
    const int S0 = 40960;
    const int SH = 65536;
    const int TOT = S0 + 3*SH + 4096;
    if (idx >= TOT) return;
    float val;
    if (idx < S0) {
        int j = idx & 7, l = (idx>>3) & 63, nt = (idx>>9) & 15, kt = idx >> 13;
        int k = kt*32 + (l>>4)*8 + j;
        int n = nt*16 + (l&15);
        val = (k < 148) ? mw_in[k*256 + n] : 0.f;
    } else if (idx < S0 + 3*SH) {
        int i2 = idx - S0;
        int L = i2 >> 16, r = i2 & 65535;
        int j = r & 7, l = (r>>3) & 63, nt = (r>>9) & 15, kt = r >> 13;
        int k = kt*32 + (l>>4)*8 + j;
        int n = nt*16 + (l&15);
        val = mw_h[L*65536 + k*256 + n];
    } else {
        int i3 = idx - S0 - 3*SH;
        int j = i3 & 7, l = (i3>>3) & 63, kt = i3 >> 9;
        int k = kt*32 + (l>>4)*8 + j;
        int oc = l & 15;
        val = mw_out[k*16 + oc];
    }
    wp[idx] = f2bs(val);
}

// ---------------- LIIF MLP via MFMA (center corner), feat bf16 -------------------
__global__ __launch_bounds__(256) void mlp_mfma_k(const short* __restrict__ feat,
        const short* __restrict__ wp,
        const float* __restrict__ b_in, const float* __restrict__ b_h,
        const float* __restrict__ b_out,
        float* __restrict__ fo){
    extern __shared__ short act_s[];           // 128*264 shorts
    int tid = threadIdx.x, bx = blockIdx.x;
    long P0 = (long)bx * 128;
    for (int idx = tid; idx < 128*160; idx += 256) {
        int pp = idx / 160, j = idx - pp*160;
        long P = P0 + pp;
        int bb = (int)(P >> 16), pim = (int)(P & 65535);
        int s0 = pim >> 8, s1 = pim & 255;
        short v = 0;
        if (j < 144) {
            int iy = j/48, ix = (j>>4)%3, c2 = j&15;
            int yy = s0 + iy - 1, xx = s1 + ix - 1;
            if (yy >= 0 && yy < 256 && xx >= 0 && xx < 256)
                v = feat[(((long)(bb*16 + c2)) << 16) + (yy<<8) + xx];
        } else if (j == 146 || j == 147) v = 0x4000; // 2.0 bf16
        act_s[pp*264 + j] = v;
    }
    __syncthreads();

    int l = tid & 63, w = tid >> 6;
    int m_l = l & 15, q = l >> 4;
    int row0 = w * 32;
    const short* wph  = wp + 40960;
    const short* wpo  = wp + 40960 + 3*65536;

    float4v acc[2][16];
    #pragma unroll
    for (int mt = 0; mt < 2; ++mt)
        #pragma unroll
        for (int nt = 0; nt < 16; ++nt) acc[mt][nt] = (float4v){0.f,0.f,0.f,0.f};
    for (int kt = 0; kt < 5; ++kt) {
        short8 a0 = *(const short8*)&act_s[(row0 + m_l)*264 + kt*32 + q*8];
        short8 a1 = *(const short8*)&act_s[(row0 + 16 + m_l)*264 + kt*32 + q*8];
        const short* bp = wp + ((size_t)(kt*16)*64 + l)*8;
        #pragma unroll
        for (int nt = 0; nt < 16; ++nt) {
            short8 bf = *(const short8*)(bp + (size_t)nt*64*8);
            acc[0][nt] = __builtin_amdgcn_mfma_f32_16x16x32_bf16(a0, bf, acc[0][nt], 0, 0, 0);
            acc[1][nt] = __builtin_amdgcn_mfma_f32_16x16x32_bf16(a1, bf, acc[1][nt], 0, 0, 0);
        }
    }
    #pragma unroll
    for (int nt = 0; nt < 16; ++nt) {
        float bias = b_in[nt*16 + m_l];
        #pragma unroll
        for (int mt = 0; mt < 2; ++mt)
            #pragma unroll
            for (int r = 0; r < 4; ++r) {
                float vv = fmaxf(acc[mt][nt][r] + bias, 0.f);
                act_s[(row0 + mt*16 + q*4 + r)*264 + nt*16 + m_l] = f2bs(vv);
            }
    }
    for (int L = 0; L < 3; ++L) {
        #pragma unroll
        for (int mt = 0; mt < 2; ++mt)
            #pragma unroll
            for (int nt = 0; nt < 16; ++nt) acc[mt][nt] = (float4v){0.f,0.f,0.f,0.f};
        const short* wl = wph + (size_t)L * 65536;
        for (int kt = 0; kt < 8; ++kt) {
            short8 a0 = *(const short8*)&act_s[(row0 + m_l)*264 + kt*32 + q*8];
            short8 a1 = *(const short8*)&act_s[(row0 + 16 + m_l)*264 + kt*32 + q*8];
            const short* bp = wl + ((size_t)(kt*16)*64 + l)*8;
            #pragma unroll
            for (int nt = 0; nt < 16; ++nt) {
                short8 bf = *(const short8*)(bp + (size_t)nt*64*8);
                acc[0][nt] = __builtin_amdgcn_mfma_f32_16x16x32_bf16(a0, bf, acc[0][nt], 0, 0, 0);
                acc[1][nt] = __builtin_amdgcn_mfma_f32_16x16x32_bf16(a1, bf, acc[1][nt], 0, 0, 0);
            }
        }
        #pragma unroll
        for (int nt = 0; nt < 16; ++nt) {
            float bias = b_h[L*256 + nt*16 + m_l];
            #pragma unroll
            for (int mt = 0; mt < 2; ++mt)
                #pragma unroll
                for (int r = 0; r < 4; ++r) {
                    float vv = fmaxf(acc[mt][nt][r] + bias, 0.f);
                    act_s[(row0 + mt*16 + q*4 + r)*264 + nt*16 + m_l] = f2bs(vv);
                }
        }
    }
    float4v o0 = (float4v){0.f,0.f,0.f,0.f}, o1 = (float4v){0.f,0.f,0.f,0.f};
    for (int kt = 0; kt < 8; ++kt) {
        short8 a0 = *(const short8*)&act_s[(row0 + m_l)*264 + kt*32 + q*8];
        short8 a1 = *(const short8*)&act_s[(row0 + 16 + m_l)*264 + kt*32 + q*8];
        short8 bf = *(const short8*)(wpo + ((size_t)kt*64 + l)*8);
        o0 = __builtin_amdgcn_mfma_f32_16x16x32_bf16(a0, bf, o0, 0, 0, 0);
        o1 = __builtin_amdgcn_mfma_f32_16x16x32_bf16(a1, bf, o1, 0, 0, 0);
    }
    float bias = b_out[m_l];
    #pragma unroll
    for (int mt = 0; mt < 2; ++mt) {
        float4v* op = mt ? &o1 : &o0;
        #pragma unroll
        for (int r = 0; r < 4; ++r) {
            long P = P0 + row0 + mt*16 + q*4 + r;
            int bb = (int)(P >> 16), pim = (int)(P & 65535);
            int s0 = pim >> 8, s1 = pim & 255;
            float w0 = (s0 == 255 || s1 == 255) ? 0.25f : 1.0f;
            fo[(((long)(bb*16 + m_l)) << 16) + pim] = w0 * ((*op)[r] + bias);
        }
    }
}

// ---------------- LIIF MLP: 3 remaining corners for edge pixels (fp32) -----------
__global__ __launch_bounds__(256) void mlp_edge_k(const bf16* __restrict__ feat,
        const float* __restrict__ w_in, const float* __restrict__ b_in,
        const float* __restrict__ w_h,  const float* __restrict__ b_h,
        const float* __restrict__ w_out,const float* __restrict__ b_out,
        float* __restrict__ fo){
    int tid = threadIdx.x, bx = blockIdx.x;
    int b = bx / 511, e = bx % 511;
    int s0 = (e < 256) ? 255 : (e - 256);
    int s1 = (e < 256) ? e : 255;
    __shared__ float inp[148], h0[256], h1[256];
    const int vxs[3] = {-1, 1, 1};
    const int vys[3] = { 1,-1, 1};
    float outacc = 0.f;
    for (int cn = 0; cn < 3; ++cn) {
        int i0 = vxs[cn] > 0 ? min(s0+1, 255) : s0;
        int i1 = vys[cn] > 0 ? min(s1+1, 255) : s1;
        float rel0 = 2.f * (float)(s0 - i0);
        float rel1 = 2.f * (float)(s1 - i1);
        if (tid < 148) {
            int j = tid; float v;
            if (j < 144) {
                int iy = j / 48, ix = (j >> 4) % 3, c = j & 15;
                int yy = i0 + iy - 1, xx = i1 + ix - 1;
                v = (yy >= 0 && yy < 256 && xx >= 0 && xx < 256)
                    ? b2f(feat[(((long)(b*16 + c)) << 16) + (yy<<8) + xx]) : 0.f;
            } else if (j == 144) v = rel0;
            else if (j == 145) v = rel1;
            else v = 2.f;
            inp[j] = v;
        }
        __syncthreads();
        float a = 0.f;
        for (int j = 0; j < 148; ++j) a += w_in[j*256 + tid] * inp[j];
        h0[tid] = fmaxf(a + b_in[tid], 0.f);
        __syncthreads();
        for (int L = 0; L < 3; ++L) {
            const float* W = w_h + L*65536;
            float* hin  = (L & 1) ? h1 : h0;
            float* hout = (L & 1) ? h0 : h1;
            float s = 0.f;
            for (int j = 0; j < 256; ++j) s += W[j*256 + tid] * hin[j];
            hout[tid] = fmaxf(s + b_h[L*256 + tid], 0.f);
            __syncthreads();
        }
        if (tid < 16) {
            float o = b_out[tid];
            for (int j = 0; j < 256; ++j) o += h1[j] * w_out[j*16 + tid];
            outacc += 0.25f * o;
        }
        __syncthreads();
    }
    if (tid < 16) {
        int p = (s0 << 8) + s1;
        fo[(((long)(b*16 + tid)) << 16) + p] += outacc;
    }
}

// ---------------- final conv (16->4) + lrms_up, fp32 out -------------------------
__global__ __launch_bounds__(256) void final_k(const float* __restrict__ fo, const float* __restrict__ w,
                                               const float* __restrict__ lrms_up, float* __restrict__ out){
    int tid = threadIdx.x, bx = blockIdx.x;
    int y = bx & 255, oc = (bx >> 8) & 3, b = bx >> 10;
    int x = tid;
    const float* wg = w + (size_t)oc * 144;
    float acc = 0.f;
    for (int ic = 0; ic < 16; ++ic) {
        const float* base = fo + (((size_t)(b*16 + ic)) << 16);
        #pragma unroll
        for (int ky = 0; ky < 3; ++ky) {
            int yy = y + ky - 1; if (yy < 0 || yy > 255) continue;
            const float* rowp = base + (yy<<8);
            float v0 = (x > 0)   ? rowp[x-1] : 0.f;
            float v1 = rowp[x];
            float v2 = (x < 255) ? rowp[x+1] : 0.f;
            const float* wr = wg + ic*9 + ky*3;
            acc = fmaf(wr[0], v0, fmaf(wr[1], v1, fmaf(wr[2], v2, acc)));
        }
    }
    size_t oidx = (((size_t)(b*4 + oc)) << 16) + (y<<8) + x;
    out[oidx] = acc + lrms_up[oidx];
}

// ================================================================================
extern "C" void kernel_launch(void* const* d_in, const int* in_sizes, int n_in,
                              void* d_out, int out_size, void* d_ws, size_t ws_size,
                              hipStream_t stream) {
    const float* lrms     = (const float*)d_in[0];
    const float* pan      = (const float*)d_in[1];
    const float* w_convps = (const float*)d_in[2];
    const float* hor_w1   = (const float*)d_in[3];
    const float* hor_w2   = (const float*)d_in[4];
    const float* ffc_l2l  = (const float*)d_in[5];
    const float* ffc_l2g  = (const float*)d_in[6];
    const float* ffc_g2l  = (const float*)d_in[7];
    const float* ffc_spec = (const float*)d_in[8];
    const float* ref_in   = (const float*)d_in[9];
    const float* ref_b1   = (const float*)d_in[10];
    const float* ref_b2   = (const float*)d_in[11];
    const float* ref_ca1  = (const float*)d_in[12];
    const float* ref_ca2  = (const float*)d_in[13];
    const float* ref_out  = (const float*)d_in[14];
    const float* w_fuse   = (const float*)d_in[15];
    const float* w_liif   = (const float*)d_in[16];
    const float* w_hp     = (const float*)d_in[17];
    const float* mw_in    = (const float*)d_in[18];
    const float* mb_in    = (const float*)d_in[19];
    const float* mw_h     = (const float*)d_in[20];
    const float* mb_h     = (const float*)d_in[21];
    const float* mw_out   = (const float*)d_in[22];
    const float* mb_out   = (const float*)d_in[23];
    float* out = (float*)d_out;

    const size_t PLANE = 65536;
    char* base = (char*)d_ws;
    size_t off = 0;
    auto alloc = [&](size_t bytes){ void* p = base + off; off += (bytes + 255) & ~(size_t)255; return p; };
    float* lrms_up  = (float*)alloc(16*PLANE*4);
    bf16*  feat2    = (bf16*) alloc(24*PLANE*2);
    bf16*  bA       = (bf16*) alloc(192*PLANE*2);
    bf16*  bB       = (bf16*) alloc(192*PLANE*2);
    bf16*  bC       = (bf16*) alloc(192*PLANE*2);
    bf16*  bF       = (bf16*) alloc(192*PLANE*2);
    bf16*  fusedCat = (bf16*) alloc(192*PLANE*2);
    bf16*  feat_all = (bf16*) alloc(64*PLANE*2);
    float* fo       = (float*)alloc(64*PLANE*4);
    const size_t FFTB = (size_t)3*4*8*256*129;   // elems per fft buffer (3 branches)
    bf16* re0 = (bf16*)alloc(FFTB*2); bf16* im0 = (bf16*)alloc(FFTB*2);
    bf16* re1 = (bf16*)alloc(FFTB*2); bf16* im1 = (bf16*)alloc(FFTB*2);
    short* wpack = (short*)alloc(241664*2);
    float* ffcw  = (float*)alloc(13824*4);
    float* means = (float*)alloc(192*4);
    float* cav   = (float*)alloc(192*4);
    if (off > ws_size) return;   // workspace insufficient -> fail visibly

    hipMemsetAsync(means, 0, 192*4, stream);
    repack_k<<<dim3(944), dim3(256), 0, stream>>>(mw_in, mw_h, mw_out, wpack);
    pack_ffcw_k<<<dim3(54), dim3(256), 0, stream>>>(ffc_l2l, ffc_l2g, ffc_g2l, ffcw);
    conv_ps_k<<<dim3(4096), dim3(256), 0, stream>>>(lrms, w_convps, lrms_up);

    GK3 g3;
    {
        const int kss[3] = {5, 27, 41};
        const double sgs[3] = {1.5, 2.0, 2.8};
        for (int br = 0; br < 3; ++br) {
            g3.ks[br] = kss[br];
            double tmp[41]; double s = 0.0; double c = (kss[br]-1)/2.0;
            for (int i = 0; i < kss[br]; ++i) { double d = i - c; tmp[i] = exp(-(d*d)/(2.0*sgs[br]*sgs[br])); s += tmp[i]; }
            for (int i = 0; i < 41; ++i) g3.k[br][i] = (i < kss[br]) ? (float)(tmp[i]/s) : 0.f;
        }
    }
    gauss_hp_k<<<dim3(6144), dim3(256), 0, stream>>>(pan, lrms_up, feat2, g3);

    // hornet (only feat channels 0,1 are nonzero)
    convA_k<<<dim3(3072), dim3(256), 0, stream>>>(feat2, 2, 2,  hor_w1, 720, 45,  bA, ACT_GELU, nullptr);
    convA_k<<<dim3(3072), dim3(256), 0, stream>>>(bA,   16, 16, hor_w2, 2304, 144, bB, ACT_NONE, nullptr);

    for (int step = 0; step < 3; ++step) {
        bf16* Xin = (step == 0) ? bB : bA;
        bf16* Yb  = (step == 0) ? bA : bB;
        bf16* Db  = (step == 0) ? bB : bA;
        convA_k<<<dim3(3072), dim3(256), 0, stream>>>(Xin, 16, 16, ref_in + step*2304, 6912, 144, Yb, ACT_NONE, nullptr);
        convA_k<<<dim3(3072), dim3(256), 0, stream>>>(Yb,  16, 16, ref_b1 + step*2304, 6912, 144, bC, ACT_RELU, nullptr);
        convA_k<<<dim3(3072), dim3(256), 0, stream>>>(bC,  16, 16, ref_b2 + step*2304, 6912, 144, Db, ACT_NONE, means);
        ca_k<<<dim3(1), dim3(192), 0, stream>>>(means, ref_ca1, ref_ca2, step, cav);
        convOut_k<<<dim3(3072), dim3(256), 0, stream>>>(Yb, Db, cav, ref_out + step*2304, w_fuse, step, bF, fusedCat);
        if (step < 2) {
            convA_k<<<dim3(3072), dim3(256), 0, stream>>>(bF, 16, 16, ffcw + step*2304, 4608, 144, bA, ACT_NONE, nullptr);
            rfft_w_k<<<dim3(24576), dim3(256), 0, stream>>>(bF, re0, im0);
            fft_h_k <<<dim3(12384), dim3(256), 0, stream>>>(re0, im0, 1.f);
            spec_k  <<<dim3(24768), dim3(256), 0, stream>>>(re0, im0, ffc_spec, step, re1, im1);
            fft_h_k <<<dim3(12384), dim3(256), 0, stream>>>(re1, im1, -1.f);
            irfft_w_k<<<dim3(24576), dim3(256), 0, stream>>>(re1, im1, bA);
        }
    }

    fuse1x1_k<<<dim3(1024), dim3(256), 0, stream>>>(fusedCat, w_liif, feat_all);
    mlp_mfma_k<<<dim3(2048), dim3(256), 128*264*2, stream>>>((const short*)feat_all, wpack, mb_in, mb_h, mb_out, fo);
    mlp_edge_k<<<dim3(2044), dim3(256), 0, stream>>>(feat_all, mw_in, mb_in, mw_h, mb_h, mw_out, mb_out, fo);
    final_k<<<dim3(4096), dim3(256), 0, stream>>>(fo, w_hp, lrms_up, out);
}

// Round 5
// 1935.405 us; speedup vs baseline: 6.9036x; 1.5601x over previous
//
#include <hip/hip_runtime.h>
#include <hip/hip_bf16.h>
#include <math.h>

typedef __hip_bfloat16 bf16;
typedef __attribute__((ext_vector_type(8))) short short8;
typedef __attribute__((ext_vector_type(4))) short short4v;
typedef __attribute__((ext_vector_type(4))) float float4v;

#define ACT_NONE 0
#define ACT_RELU 1
#define ACT_GELU 2

__device__ __forceinline__ float b2f(bf16 v){ return __bfloat162float(v); }
__device__ __forceinline__ bf16  f2b(float f){ return __float2bfloat16(f); }
__device__ __forceinline__ short f2bs(float f){ bf16 h = __float2bfloat16(f); return *reinterpret_cast<short*>(&h); }
__device__ __forceinline__ void rotc(float& tr, float& ti, float cr, float ci){
    float t = tr*cr - ti*ci; ti = tr*ci + ti*cr; tr = t;
}

struct GK3 { float k[3][41]; int ks[3]; };

// ---------------- pixel-shuffle conv ------------------------------------------
__global__ __launch_bounds__(256) void conv_ps_k(const float* __restrict__ lrms,
                                                 const float* __restrict__ w,
                                                 float* __restrict__ up){
    int tid = threadIdx.x, bx = blockIdx.x;
    int y = bx & 255, c = (bx >> 8) & 3, b = bx >> 10;
    int x = tid;
    int h = y >> 2, r1 = y & 3, ww = x >> 2, r2 = x & 3;
    int oc = c*16 + r1*4 + r2;
    float acc = 0.f;
    for (int ic = 0; ic < 4; ++ic) {
        const float* base = lrms + ((b*4 + ic) << 12);
        const float* wb = w + (oc*4 + ic)*9;
        #pragma unroll
        for (int ky = 0; ky < 3; ++ky) {
            int hh = h + ky - 1; if (hh < 0 || hh > 63) continue;
            #pragma unroll
            for (int kx = 0; kx < 3; ++kx) {
                int cc = ww + kx - 1; if (cc < 0 || cc > 63) continue;
                acc += base[(hh<<6) + cc] * wb[ky*3 + kx];
            }
        }
    }
    up[(((size_t)(b*4 + c)) << 16) + (y<<8) + x] = acc;
}

// ---------------- fused gaussian highpass -------------------------------------
__global__ __launch_bounds__(256) void gauss_hp_k(const float* __restrict__ pan,
                                                  const float* __restrict__ lrms_up,
                                                  bf16* __restrict__ feat2, GK3 g){
    int tid = threadIdx.x, bx = blockIdx.x;
    int y = bx & 255, b = (bx >> 8) & 3, src = (bx >> 10) & 1, br = bx >> 11;
    int ks = g.ks[br], p = ks >> 1;
    const float* gk = g.k[br];
    const float* s = src ? (lrms_up + (size_t)b*4*65536) : (pan + (size_t)b*65536);
    __shared__ float vext[296];
    for (int i = tid; i < 296; i += 256) {
        int xe = i - 20; int xr = xe < 0 ? -xe : (xe > 255 ? 510 - xe : xe);
        float acc = 0.f;
        for (int t = 0; t < ks; ++t) {
            int yy = y - p + t; yy = yy < 0 ? -yy : (yy > 255 ? 510 - yy : yy);
            acc += gk[t] * s[(yy<<8) + xr];
        }
        vext[i] = acc;
    }
    __syncthreads();
    int x = tid;
    float acc = 0.f;
    for (int t = 0; t < ks; ++t) acc += gk[t] * vext[x - p + t + 20];
    float o = s[(y<<8) + x];
    feat2[(((size_t)((br*4 + b)*2 + src)) << 16) + (y<<8) + x] = f2b(o - acc);
}

// ---------------- scalar 3x3 conv (only for hornet conv1, Cin=2) ----------------
__global__ __launch_bounds__(256) void convA_k(const bf16* __restrict__ in, int inCper, int Cin,
                                               const float* __restrict__ wbase, int wbrstride, int wocstride,
                                               bf16* __restrict__ out, int act){
    int tid = threadIdx.x, bx = blockIdx.x;
    int y = bx & 255, b = (bx >> 8) & 3, br = bx >> 10;
    const float* w = wbase + (size_t)br * wbrstride;
    int x = tid;
    float acc[16];
    #pragma unroll
    for (int oc = 0; oc < 16; ++oc) acc[oc] = 0.f;
    for (int ic = 0; ic < Cin; ++ic) {
        const bf16* base = in + ((size_t)((br*4 + b)*inCper + ic) << 16);
        const float* wic = w + ic*9;
        #pragma unroll
        for (int ky = 0; ky < 3; ++ky) {
            int yy = y + ky - 1; if (yy < 0 || yy > 255) continue;
            const bf16* rowp = base + (yy<<8);
            float v0 = (x > 0)   ? b2f(rowp[x-1]) : 0.f;
            float v1 = b2f(rowp[x]);
            float v2 = (x < 255) ? b2f(rowp[x+1]) : 0.f;
            const float* wr = wic + ky*3;
            #pragma unroll
            for (int oc = 0; oc < 16; ++oc) {
                const float* wo = wr + oc*wocstride;
                acc[oc] = fmaf(wo[0], v0, fmaf(wo[1], v1, fmaf(wo[2], v2, acc[oc])));
            }
        }
    }
    #pragma unroll
    for (int oc = 0; oc < 16; ++oc) {
        float a = acc[oc];
        if (act == ACT_RELU) a = fmaxf(a, 0.f);
        else if (act == ACT_GELU) {
            float u = 0.7978845608028654f * (a + 0.044715f*a*a*a);
            a = 0.5f * a * (1.f + tanhf(u));
        }
        out[((size_t)((br*4 + b)*16 + oc) << 16) + (y<<8) + x] = f2b(a);
    }
}

// ---------------- pack conv weights for MFMA: 45 sets x [kt5][lane64][j8] --------
// k = tap*16 + ic (tap=ky*3+kx), n = oc; B[k][n]: lane l -> n=l&15, k=kt*32+(l>>4)*8+j
__global__ __launch_bounds__(256) void pack_convw_k(const float* __restrict__ hor_w2,
        const float* __restrict__ ref_in, const float* __restrict__ ref_b1,
        const float* __restrict__ ref_b2, const float* __restrict__ ffcw,
        short* __restrict__ wp){
    int idx = blockIdx.x*256 + threadIdx.x;
    if (idx >= 45*2560) return;
    int set = idx / 2560, r = idx % 2560;
    int j = r & 7, l = (r>>3) & 63, kt = r >> 9;
    int k = kt*32 + ((l>>4)&3)*8 + j;
    int n = l & 15;
    int g = set / 3, br = set % 3;
    float v = 0.f;
    if (k < 144) {
        int tap = k >> 4, ic = k & 15;
        int widx = (n*16 + ic)*9 + tap;
        const float* src;
        if (g == 0)       src = hor_w2 + br*2304;
        else if (g <= 3)  src = ref_in + (3*br + (g-1))*2304;
        else if (g <= 6)  src = ref_b1 + (3*br + (g-4))*2304;
        else if (g <= 9)  src = ref_b2 + (3*br + (g-7))*2304;
        else              src = ffcw   + (2*br + (g-10))*2304;
        v = src[widx];
    }
    wp[idx] = f2bs(v);
}

// ---------------- MFMA 3x3 conv, Cin=16 -> 16 oc, lockstep branches -------------
// LDS stage: sIn[(r*258 + xi)*20 + ic]; K=144 (9 taps x 16 ic) padded to 160.
__global__ __launch_bounds__(256) void convM_k(const bf16* __restrict__ in,
        const short* __restrict__ wgroup,     // + br*2560 inside
        bf16* __restrict__ out, int act, float* __restrict__ means){
    __shared__ short sIn[3*258*20];
    __shared__ float sm[4][16];
    int tid = threadIdx.x, bx = blockIdx.x;
    int y = bx & 255, b = (bx >> 8) & 3, br = bx >> 10;
    size_t pbase = (size_t)((br*4 + b)*16) << 16;
    if (tid < 96) {
        int r = tid >> 5, xi = ((tid >> 4) & 1) ? 257 : 0, ic = tid & 15;
        sIn[(r*258 + xi)*20 + ic] = 0;
    }
    for (int r = 0; r < 3; ++r) {
        int yy = y + r - 1;
        bool rv = (yy >= 0 && yy <= 255);
        #pragma unroll
        for (int ic = 0; ic < 16; ++ic) {
            short v = 0;
            if (rv) v = *(const short*)&in[pbase + ((size_t)ic << 16) + (yy<<8) + tid];
            sIn[(r*258 + tid + 1)*20 + ic] = v;
        }
    }
    __syncthreads();
    int l = tid & 63, w = tid >> 6;
    int m_l = l & 15, q = l >> 4;
    int px0 = w*64;
    const short* wp = wgroup + br*2560;
    short8 bfr[5];
    #pragma unroll
    for (int kt = 0; kt < 5; ++kt)
        bfr[kt] = *(const short8*)(wp + (kt*64 + l)*8);
    float4v acc[4];
    #pragma unroll
    for (int mt = 0; mt < 4; ++mt) acc[mt] = (float4v){0.f,0.f,0.f,0.f};
    #pragma unroll
    for (int kt = 0; kt < 5; ++kt) {
        int k0 = kt*32 + q*8;
        bool pad = (k0 >= 144);
        int tap = k0 >> 4, icb = k0 & 15;
        int ky = tap / 3, kx = tap - ky*3;
        if (pad) { ky = 0; kx = 0; }    // safe dummy (frag zeroed below)
        #pragma unroll
        for (int mt = 0; mt < 4; ++mt) {
            int px = px0 + mt*16 + m_l;
            const short* ap = &sIn[(ky*258 + px + kx)*20 + icb];
            short4v alo = *(const short4v*)ap;
            short4v ahi = *(const short4v*)(ap + 4);
            short8 a;
            #pragma unroll
            for (int t = 0; t < 4; ++t) { a[t] = pad ? (short)0 : alo[t]; a[t+4] = pad ? (short)0 : ahi[t]; }
            acc[mt] = __builtin_amdgcn_mfma_f32_16x16x32_bf16(a, bfr[kt], acc[mt], 0, 0, 0);
        }
    }
    if (means) {
        float s = 0.f;
        #pragma unroll
        for (int mt = 0; mt < 4; ++mt)
            #pragma unroll
            for (int r = 0; r < 4; ++r) s += acc[mt][r];
        s += __shfl_xor(s, 16, 64);
        s += __shfl_xor(s, 32, 64);
        if (l < 16) sm[w][l] = s;
        __syncthreads();
        if (tid < 16) atomicAdd(&means[br*64 + b*16 + tid],
                                sm[0][tid] + sm[1][tid] + sm[2][tid] + sm[3][tid]);
    }
    #pragma unroll
    for (int mt = 0; mt < 4; ++mt) {
        #pragma unroll
        for (int r = 0; r < 4; ++r) {
            float a = acc[mt][r];
            if (act == ACT_RELU) a = fmaxf(a, 0.f);
            else if (act == ACT_GELU) {
                float u = 0.7978845608028654f * (a + 0.044715f*a*a*a);
                a = 0.5f * a * (1.f + tanhf(u));
            }
            int px = px0 + mt*16 + q*4 + r;
            out[pbase + ((size_t)m_l << 16) + (y<<8) + px] = f2b(a);
        }
    }
}

// ---------------- refine output conv (scalar; fused Y+ca*BDY, + fuse 1x1) -------
__global__ __launch_bounds__(256) void convOut_k(const bf16* __restrict__ Y, const bf16* __restrict__ BDY,
                                                 const float* __restrict__ cav, const float* __restrict__ wout,
                                                 const float* __restrict__ wfuse, int step,
                                                 bf16* __restrict__ F, bf16* __restrict__ fusedCat){
    int tid = threadIdx.x, bx = blockIdx.x;
    int y = bx & 255, b = (bx >> 8) & 3, br = bx >> 10;
    const float* w = wout + (size_t)br * 6912;
    float cc[16];
    #pragma unroll
    for (int ic = 0; ic < 16; ++ic) cc[ic] = cav[br*64 + b*16 + ic];
    int x = tid;
    float acc[16];
    #pragma unroll
    for (int oc = 0; oc < 16; ++oc) acc[oc] = 0.f;
    for (int ic = 0; ic < 16; ++ic) {
        size_t plane = (size_t)((br*4 + b)*16 + ic) << 16;
        const bf16* yb = Y + plane; const bf16* db = BDY + plane;
        float c0 = cc[ic];
        const float* wic = w + ic*9;
        #pragma unroll
        for (int ky = 0; ky < 3; ++ky) {
            int yy = y + ky - 1; if (yy < 0 || yy > 255) continue;
            const bf16* yr = yb + (yy<<8); const bf16* dr = db + (yy<<8);
            float v0 = (x > 0)   ? fmaf(b2f(dr[x-1]), c0, b2f(yr[x-1])) : 0.f;
            float v1 = fmaf(b2f(dr[x]), c0, b2f(yr[x]));
            float v2 = (x < 255) ? fmaf(b2f(dr[x+1]), c0, b2f(yr[x+1])) : 0.f;
            const float* wr = wic + ky*3;
            #pragma unroll
            for (int oc = 0; oc < 16; ++oc) {
                const float* wo = wr + oc*144;
                acc[oc] = fmaf(wo[0], v0, fmaf(wo[1], v1, fmaf(wo[2], v2, acc[oc])));
            }
        }
    }
    #pragma unroll
    for (int oc = 0; oc < 16; ++oc)
        F[((size_t)((br*4 + b)*16 + oc) << 16) + (y<<8) + x] = f2b(acc[oc]);
    const float* wf = wfuse + br*768 + step*16;
    #pragma unroll
    for (int oc2 = 0; oc2 < 16; ++oc2) {
        float s = 0.f;
        #pragma unroll
        for (int oc = 0; oc < 16; ++oc) s += wf[oc2*48 + oc] * acc[oc];
        size_t fidx = ((size_t)(b*48 + br*16 + oc2) << 16) + (y<<8) + x;
        if (step == 0) fusedCat[fidx] = f2b(s);
        else           fusedCat[fidx] = f2b(b2f(fusedCat[fidx]) + s);
    }
}

// ---------------- channel attention; rezeros means -------------------------------
__global__ void ca_k(float* __restrict__ means, const float* __restrict__ ca1,
                     const float* __restrict__ ca2, int step, float* __restrict__ cav){
    int t = threadIdx.x;  // 192
    int br = t >> 6, rem = t & 63, b = rem >> 4, oc = rem & 15;
    int ri = 3*br + step;
    const float* w1 = ca1 + ri*64; const float* w2 = ca2 + ri*64;
    float hid[4];
    #pragma unroll
    for (int c2 = 0; c2 < 4; ++c2) {
        float a = 0.f;
        for (int c = 0; c < 16; ++c) a += w1[c2*16 + c] * (means[br*64 + b*16 + c] * (1.f/65536.f));
        hid[c2] = fmaxf(a, 0.f);
    }
    float v = 0.f;
    #pragma unroll
    for (int c2 = 0; c2 < 4; ++c2) v += w2[oc*4 + c2] * hid[c2];
    cav[t] = 1.f / (1.f + expf(-v));
    __syncthreads();
    means[t] = 0.f;
}

// ---------------- radix-16 rfft along W (bf16 IO) --------------------------------
__global__ __launch_bounds__(256) void rfft_w_k(const bf16* __restrict__ F,
                                                bf16* __restrict__ ore, bf16* __restrict__ oim){
    int tid = threadIdx.x, bx = blockIdx.x;
    int y = bx & 255, c = (bx >> 8) & 7, b = (bx >> 11) & 3, br = bx >> 13;
    __shared__ float row[256], Ar[256], Ai[256];
    row[tid] = b2f(F[((size_t)((br*4 + b)*16 + 8 + c) << 16) + (y<<8) + tid]);
    __syncthreads();
    int n1 = tid >> 4, k1 = tid & 15;
    float a1 = -6.283185307179586f * (float)k1 / 16.f;
    float c1, s1; __sincosf(a1, &s1, &c1);
    float twr = 1.f, twi = 0.f, ar = 0.f, ai = 0.f;
    #pragma unroll
    for (int n2 = 0; n2 < 16; ++n2) {
        float xr = row[n1 + (n2<<4)];
        ar = fmaf(xr, twr, ar); ai = fmaf(xr, twi, ai);
        rotc(twr, twi, c1, s1);
    }
    Ar[tid] = ar; Ai[tid] = ai;
    __syncthreads();
    int k = tid, kk1 = k & 15;
    float a2 = -6.283185307179586f * (float)k / 256.f;
    float c2v, s2v; __sincosf(a2, &s2v, &c2v);
    float t2r = 1.f, t2i = 0.f, re = 0.f, im = 0.f;
    #pragma unroll
    for (int m = 0; m < 16; ++m) {
        float r = Ar[(m<<4) + kk1], i = Ai[(m<<4) + kk1];
        re += r*t2r - i*t2i; im += i*t2r + r*t2i;
        rotc(t2r, t2i, c2v, s2v);
    }
    if (k < 129) {
        size_t o = ((size_t)(((br*4 + b)*8 + c)*256 + y))*129 + k;
        ore[o] = f2b(re * 0.0625f); oim[o] = f2b(im * 0.0625f);
    }
}

// ---------------- FUSED: fft_h fwd (8ch) -> spec 1x1+relu -> fft_h inv (8ch) -----
__global__ __launch_bounds__(256) void fftspec_h_k(const bf16* __restrict__ re0, const bf16* __restrict__ im0,
                                                   const float* __restrict__ wspec, int step,
                                                   bf16* __restrict__ re1, bf16* __restrict__ im1){
    __shared__ float Fr[8][256], Fi[8][256], Sr[8][256], Si[8][256], Ar[256], Ai[256];
    int tid = threadIdx.x, bx = blockIdx.x;
    int k = bx % 129; int r2 = bx / 129; int b = r2 & 3, br = r2 >> 2;
    size_t cb = ((size_t)((br*4 + b)*8))*33024 + k;
    int n1 = tid >> 4, k1 = tid & 15;
    float a1 = -6.283185307179586f * (float)k1 / 16.f;
    float c1, s1; __sincosf(a1, &s1, &c1);
    float a2 = -6.283185307179586f * (float)tid / 256.f;
    float c2v, s2v; __sincosf(a2, &s2v, &c2v);
    // load all 8 channel columns
    #pragma unroll
    for (int c = 0; c < 8; ++c) {
        size_t base = cb + (size_t)c*33024 + (size_t)tid*129;
        Fr[c][tid] = b2f(re0[base]);
        Fi[c][tid] = b2f(im0[base]);
    }
    __syncthreads();
    // forward per channel: F[c] -> S[c]
    for (int c = 0; c < 8; ++c) {
        float twr = 1.f, twi = 0.f, ar = 0.f, ai = 0.f;
        #pragma unroll
        for (int n2 = 0; n2 < 16; ++n2) {
            float r = Fr[c][n1 + (n2<<4)], i = Fi[c][n1 + (n2<<4)];
            ar += r*twr - i*twi; ai += i*twr + r*twi;
            rotc(twr, twi, c1, s1);
        }
        Ar[tid] = ar; Ai[tid] = ai;
        __syncthreads();
        float t2r = 1.f, t2i = 0.f, rr = 0.f, ii = 0.f;
        #pragma unroll
        for (int m = 0; m < 16; ++m) {
            float r = Ar[(m<<4) + k1], i = Ai[(m<<4) + k1];
            rr += r*t2r - i*t2i; ii += i*t2r + r*t2i;
            rotc(t2r, t2i, c2v, s2v);
        }
        Sr[c][tid] = rr * 0.0625f; Si[c][tid] = ii * 0.0625f;
        __syncthreads();
    }
    // spec 1x1 + relu: S -> F
    {
        const float* wl = wspec + (2*br + step)*256;
        float outv[16];
        #pragma unroll
        for (int oc = 0; oc < 16; ++oc) {
            float acc = 0.f;
            #pragma unroll
            for (int ic = 0; ic < 8; ++ic)
                acc += Sr[ic][tid] * wl[oc*16 + ic] + Si[ic][tid] * wl[oc*16 + 8 + ic];
            outv[oc] = fmaxf(acc, 0.f);
        }
        __syncthreads();
        #pragma unroll
        for (int oc = 0; oc < 8; ++oc) { Fr[oc][tid] = outv[oc]; Fi[oc][tid] = outv[oc+8]; }
        __syncthreads();
    }
    // inverse per channel: F[c] -> global
    for (int c = 0; c < 8; ++c) {
        float twr = 1.f, twi = 0.f, ar = 0.f, ai = 0.f;
        #pragma unroll
        for (int n2 = 0; n2 < 16; ++n2) {
            float r = Fr[c][n1 + (n2<<4)], i = Fi[c][n1 + (n2<<4)];
            ar += r*twr + i*twi;            // conj twiddle
            ai += i*twr - r*twi;
            rotc(twr, twi, c1, s1);
        }
        Ar[tid] = ar; Ai[tid] = ai;
        __syncthreads();
        float t2r = 1.f, t2i = 0.f, rr = 0.f, ii = 0.f;
        #pragma unroll
        for (int m = 0; m < 16; ++m) {
            float r = Ar[(m<<4) + k1], i = Ai[(m<<4) + k1];
            rr += r*t2r + i*t2i;
            ii += i*t2r - r*t2i;
            rotc(t2r, t2i, c2v, s2v);
        }
        size_t base = cb + (size_t)c*33024 + (size_t)tid*129;
        re1[base] = f2b(rr * 0.0625f);
        im1[base] = f2b(ii * 0.0625f);
        __syncthreads();
    }
}

// ---------------- c2r irfft along W, += into A ch0..7 ----------------------------
__global__ __launch_bounds__(256) void irfft_w_k(const bf16* __restrict__ re1, const bf16* __restrict__ im1,
                                                 bf16* __restrict__ A){
    int tid = threadIdx.x, bx = blockIdx.x;
    int y = bx & 255, c = (bx >> 8) & 7, b = (bx >> 11) & 3, br = bx >> 13;
    __shared__ float cr[256], ci[256], Ar[256], Ai[256];
    size_t base = ((size_t)(((br*4 + b)*8 + c)*256 + y))*129;
    if (tid < 129) {
        cr[tid] = b2f(re1[base + tid]);
        ci[tid] = (tid == 0 || tid == 128) ? 0.f : b2f(im1[base + tid]);
    }
    __syncthreads();
    if (tid >= 129) { cr[tid] = cr[256 - tid]; ci[tid] = -ci[256 - tid]; }
    __syncthreads();
    int n1 = tid >> 4, k1 = tid & 15;
    float a1 = 6.283185307179586f * (float)k1 / 16.f;
    float c1, s1; __sincosf(a1, &s1, &c1);
    float twr = 1.f, twi = 0.f, ar = 0.f, ai = 0.f;
    #pragma unroll
    for (int n2 = 0; n2 < 16; ++n2) {
        float r = cr[n1 + (n2<<4)], i = ci[n1 + (n2<<4)];
        ar += r*twr - i*twi; ai += i*twr + r*twi;
        rotc(twr, twi, c1, s1);
    }
    Ar[tid] = ar; Ai[tid] = ai;
    __syncthreads();
    int m = tid, mk1 = m & 15;
    float a2 = 6.283185307179586f * (float)m / 256.f;
    float c2v, s2v; __sincosf(a2, &s2v, &c2v);
    float t2r = 1.f, t2i = 0.f, racc = 0.f;
    #pragma unroll
    for (int q = 0; q < 16; ++q) {
        float r = Ar[(q<<4) + mk1], i = Ai[(q<<4) + mk1];
        racc += r*t2r - i*t2i;
        rotc(t2r, t2i, c2v, s2v);
    }
    size_t o = ((size_t)((br*4 + b)*16 + c) << 16) + (y<<8) + m;
    A[o] = f2b(b2f(A[o]) + racc * 0.0625f);
}

// ---------------- pack combined ffc conv weights ---------------------------------
__global__ __launch_bounds__(256) void pack_ffcw_k(const float* __restrict__ l2l, const float* __restrict__ l2g,
                                                   const float* __restrict__ g2l, float* __restrict__ wout){
    int idx = blockIdx.x*256 + threadIdx.x;
    if (idx >= 6*2304) return;
    int t = idx % 9; int ic = (idx/9) % 16; int oc = (idx/144) % 16; int wi = idx/2304;
    float v;
    if (oc < 8) v = (ic < 8) ? l2g[((wi*8 + oc)*8 + ic)*9 + t] : 0.f;
    else {
        int o = oc - 8;
        v = (ic < 8) ? l2l[((wi*8 + o)*8 + ic)*9 + t] : g2l[((wi*8 + o)*8 + (ic-8))*9 + t];
    }
    wout[idx] = v;
}

// ---------------- fuse 1x1 (48->16) ---------------------------------------------
__global__ __launch_bounds__(256) void fuse1x1_k(const bf16* __restrict__ fc, const float* __restrict__ wl,
                                                 bf16* __restrict__ feat_all){
    int tid = threadIdx.x, bx = blockIdx.x;
    int pt = bx & 255, b = bx >> 8;
    int p = (pt << 8) + tid;
    float acc[16];
    #pragma unroll
    for (int oc = 0; oc < 16; ++oc) acc[oc] = 0.f;
    for (int ic = 0; ic < 48; ++ic) {
        float v = b2f(fc[((size_t)(b*48 + ic) << 16) + p]);
        #pragma unroll
        for (int oc = 0; oc < 16; ++oc) acc[oc] = fmaf(wl[oc*48 + ic], v, acc[oc]);
    }
    #pragma unroll
    for (int oc = 0; oc < 16; ++oc)
        feat_all[((size_t)(b*16 + oc) << 16) + p] = f2b(acc[oc]);
}

// ---------------- MLP weight repack ---------------------------------------------
__global__ __launch_bounds__(256) void repack_k(const float* __restrict__ mw_in,
                                                const float* __restrict__ mw_h,
                                                const float* __restrict__ mw_out,
                                                short* __restrict__ wp){
    int idx = blockIdx.x*256 + threadIdx.x;
    const int S0 = 40960;
    const int SH = 65536;
    const int TOT = S0 + 3*SH + 4096;
    if (idx >= TOT) return;
    float val;
    if (idx < S0) {
        int j = idx & 7, l = (idx>>3) & 63, nt = (idx>>9) & 15, kt = idx >> 13;
        int k = kt*32 + (l>>4)*8 + j;
        int n = nt*16 + (l&15);
        val = (k < 148) ? mw_in[k*256 + n] : 0.f;
    } else if (idx < S0 + 3*SH) {
        int i2 = idx - S0;
        int L = i2 >> 16, r = i2 & 65535;
        int j = r & 7, l = (r>>3) & 63, nt = (r>>9) & 15, kt = r >> 13;
        int k = kt*32 + (l>>4)*8 + j;
        int n = nt*16 + (l&15);
        val = mw_h[L*65536 + k*256 + n];
    } else {
        int i3 = idx - S0 - 3*SH;
        int j = i3 & 7, l = (i3>>3) & 63, kt = i3 >> 9;
        int k = kt*32 + (l>>4)*8 + j;
        int oc = l & 15;
        val = mw_out[k*16 + oc];
    }
    wp[idx] = f2bs(val);
}

// ---------------- MFMA MLP body macro-free helper --------------------------------
// (identical math in center & edge kernels)

// ---------------- LIIF MLP via MFMA (center corner) ------------------------------
__global__ __launch_bounds__(256) void mlp_mfma_k(const short* __restrict__ feat,
        const short* __restrict__ wp,
        const float* __restrict__ b_in, const float* __restrict__ b_h,
        const float* __restrict__ b_out,
        float* __restrict__ fo){
    extern __shared__ short act_s[];
    int tid = threadIdx.x, bx = blockIdx.x;
    long P0 = (long)bx * 128;
    for (int idx = tid; idx < 128*160; idx += 256) {
        int pp = idx / 160, j = idx - pp*160;
        long P = P0 + pp;
        int bb = (int)(P >> 16), pim = (int)(P & 65535);
        int s0 = pim >> 8, s1 = pim & 255;
        short v = 0;
        if (j < 144) {
            int iy = j/48, ix = (j>>4)%3, c2 = j&15;
            int yy = s0 + iy - 1, xx = s1 + ix - 1;
            if (yy >= 0 && yy < 256 && xx >= 0 && xx < 256)
                v = feat[(((long)(bb*16 + c2)) << 16) + (yy<<8) + xx];
        } else if (j == 146 || j == 147) v = 0x4000;
        act_s[pp*264 + j] = v;
    }
    __syncthreads();

    int l = tid & 63, w = tid >> 6;
    int m_l = l & 15, q = l >> 4;
    int row0 = w * 32;
    const short* wph  = wp + 40960;
    const short* wpo  = wp + 40960 + 3*65536;

    float4v acc[2][16];
    #pragma unroll
    for (int mt = 0; mt < 2; ++mt)
        #pragma unroll
        for (int nt = 0; nt < 16; ++nt) acc[mt][nt] = (float4v){0.f,0.f,0.f,0.f};
    for (int kt = 0; kt < 5; ++kt) {
        short8 a0 = *(const short8*)&act_s[(row0 + m_l)*264 + kt*32 + q*8];
        short8 a1 = *(const short8*)&act_s[(row0 + 16 + m_l)*264 + kt*32 + q*8];
        const short* bp = wp + ((size_t)(kt*16)*64 + l)*8;
        #pragma unroll
        for (int nt = 0; nt < 16; ++nt) {
            short8 bf = *(const short8*)(bp + (size_t)nt*64*8);
            acc[0][nt] = __builtin_amdgcn_mfma_f32_16x16x32_bf16(a0, bf, acc[0][nt], 0, 0, 0);
            acc[1][nt] = __builtin_amdgcn_mfma_f32_16x16x32_bf16(a1, bf, acc[1][nt], 0, 0, 0);
        }
    }
    #pragma unroll
    for (int nt = 0; nt < 16; ++nt) {
        float bias = b_in[nt*16 + m_l];
        #pragma unroll
        for (int mt = 0; mt < 2; ++mt)
            #pragma unroll
            for (int r = 0; r < 4; ++r) {
                float vv = fmaxf(acc[mt][nt][r] + bias, 0.f);
                act_s[(row0 + mt*16 + q*4 + r)*264 + nt*16 + m_l] = f2bs(vv);
            }
    }
    for (int L = 0; L < 3; ++L) {
        #pragma unroll
        for (int mt = 0; mt < 2; ++mt)
            #pragma unroll
            for (int nt = 0; nt < 16; ++nt) acc[mt][nt] = (float4v){0.f,0.f,0.f,0.f};
        const short* wl = wph + (size_t)L * 65536;
        for (int kt = 0; kt < 8; ++kt) {
            short8 a0 = *(const short8*)&act_s[(row0 + m_l)*264 + kt*32 + q*8];
            short8 a1 = *(const short8*)&act_s[(row0 + 16 + m_l)*264 + kt*32 + q*8];
            const short* bp = wl + ((size_t)(kt*16)*64 + l)*8;
            #pragma unroll
            for (int nt = 0; nt < 16; ++nt) {
                short8 bf = *(const short8*)(bp + (size_t)nt*64*8);
                acc[0][nt] = __builtin_amdgcn_mfma_f32_16x16x32_bf16(a0, bf, acc[0][nt], 0, 0, 0);
                acc[1][nt] = __builtin_amdgcn_mfma_f32_16x16x32_bf16(a1, bf, acc[1][nt], 0, 0, 0);
            }
        }
        #pragma unroll
        for (int nt = 0; nt < 16; ++nt) {
            float bias = b_h[L*256 + nt*16 + m_l];
            #pragma unroll
            for (int mt = 0; mt < 2; ++mt)
                #pragma unroll
                for (int r = 0; r < 4; ++r) {
                    float vv = fmaxf(acc[mt][nt][r] + bias, 0.f);
                    act_s[(row0 + mt*16 + q*4 + r)*264 + nt*16 + m_l] = f2bs(vv);
                }
        }
    }
    float4v o0 = (float4v){0.f,0.f,0.f,0.f}, o1 = (float4v){0.f,0.f,0.f,0.f};
    for (int kt = 0; kt < 8; ++kt) {
        short8 a0 = *(const short8*)&act_s[(row0 + m_l)*264 + kt*32 + q*8];
        short8 a1 = *(const short8*)&act_s[(row0 + 16 + m_l)*264 + kt*32 + q*8];
        short8 bf = *(const short8*)(wpo + ((size_t)kt*64 + l)*8);
        o0 = __builtin_amdgcn_mfma_f32_16x16x32_bf16(a0, bf, o0, 0, 0, 0);
        o1 = __builtin_amdgcn_mfma_f32_16x16x32_bf16(a1, bf, o1, 0, 0, 0);
    }
    float bias = b_out[m_l];
    #pragma unroll
    for (int mt = 0; mt < 2; ++mt) {
        float4v* op = mt ? &o1 : &o0;
        #pragma unroll
        for (int r = 0; r < 4; ++r) {
            long P = P0 + row0 + mt*16 + q*4 + r;
            int bb = (int)(P >> 16), pim = (int)(P & 65535);
            int s0 = pim >> 8, s1 = pim & 255;
            float w0 = (s0 == 255 || s1 == 255) ? 0.25f : 1.0f;
            fo[(((long)(bb*16 + m_l)) << 16) + pim] = w0 * ((*op)[r] + bias);
        }
    }
}

// ---------------- LIIF MLP edge corners via MFMA ---------------------------------
// 6132 (edge pixel, corner) evals padded to 6144; 128 per block -> 48 blocks.
__global__ __launch_bounds__(256) void mlp_edge_mfma_k(const short* __restrict__ feat,
        const short* __restrict__ wp,
        const float* __restrict__ b_in, const float* __restrict__ b_h,
        const float* __restrict__ b_out,
        float* __restrict__ fo){
    extern __shared__ short act_s[];
    int tid = threadIdx.x, bx = blockIdx.x;
    int E0 = bx * 128;
    for (int idx = tid; idx < 128*160; idx += 256) {
        int pp = idx / 160, j = idx - pp*160;
        int e = E0 + pp; if (e >= 6132) e = 0;
        int bb = e / 1533; int rem = e - bb*1533;
        int cn = rem / 511; int eidx = rem - cn*511;
        int s0 = (eidx < 256) ? 255 : eidx - 256;
        int s1 = (eidx < 256) ? eidx : 255;
        int vx = (cn == 0) ? -1 : 1;
        int vy = (cn == 1) ? -1 : 1;
        int i0 = (vx > 0) ? min(s0+1, 255) : s0;
        int i1 = (vy > 0) ? min(s1+1, 255) : s1;
        short v = 0;
        if (j < 144) {
            int iy = j/48, ix = (j>>4)%3, c2 = j&15;
            int yy = i0 + iy - 1, xx = i1 + ix - 1;
            if (yy >= 0 && yy < 256 && xx >= 0 && xx < 256)
                v = feat[(((long)(bb*16 + c2)) << 16) + (yy<<8) + xx];
        } else if (j == 144) v = f2bs(2.f*(float)(s0 - i0));
        else if (j == 145) v = f2bs(2.f*(float)(s1 - i1));
        else if (j >= 146) v = 0x4000;
        act_s[pp*264 + j] = v;
    }
    __syncthreads();

    int l = tid & 63, w = tid >> 6;
    int m_l = l & 15, q = l >> 4;
    int row0 = w * 32;
    const short* wph  = wp + 40960;
    const short* wpo  = wp + 40960 + 3*65536;

    float4v acc[2][16];
    #pragma unroll
    for (int mt = 0; mt < 2; ++mt)
        #pragma unroll
        for (int nt = 0; nt < 16; ++nt) acc[mt][nt] = (float4v){0.f,0.f,0.f,0.f};
    for (int kt = 0; kt < 5; ++kt) {
        short8 a0 = *(const short8*)&act_s[(row0 + m_l)*264 + kt*32 + q*8];
        short8 a1 = *(const short8*)&act_s[(row0 + 16 + m_l)*264 + kt*32 + q*8];
        const short* bp = wp + ((size_t)(kt*16)*64 + l)*8;
        #pragma unroll
        for (int nt = 0; nt < 16; ++nt) {
            short8 bf = *(const short8*)(bp + (size_t)nt*64*8);
            acc[0][nt] = __builtin_amdgcn_mfma_f32_16x16x32_bf16(a0, bf, acc[0][nt], 0, 0, 0);
            acc[1][nt] = __builtin_amdgcn_mfma_f32_16x16x32_bf16(a1, bf, acc[1][nt], 0, 0, 0);
        }
    }
    #pragma unroll
    for (int nt = 0; nt < 16; ++nt) {
        float bias = b_in[nt*16 + m_l];
        #pragma unroll
        for (int mt = 0; mt < 2; ++mt)
            #pragma unroll
            for (int r = 0; r < 4; ++r) {
                float vv = fmaxf(acc[mt][nt][r] + bias, 0.f);
                act_s[(row0 + mt*16 + q*4 + r)*264 + nt*16 + m_l] = f2bs(vv);
            }
    }
    for (int L = 0; L < 3; ++L) {
        #pragma unroll
        for (int mt = 0; mt < 2; ++mt)
            #pragma unroll
            for (int nt = 0; nt < 16; ++nt) acc[mt][nt] = (float4v){0.f,0.f,0.f,0.f};
        const short* wl = wph + (size_t)L * 65536;
        for (int kt = 0; kt < 8; ++kt) {
            short8 a0 = *(const short8*)&act_s[(row0 + m_l)*264 + kt*32 + q*8];
            short8 a1 = *(const short8*)&act_s[(row0 + 16 + m_l)*264 + kt*32 + q*8];
            const short* bp = wl + ((size_t)(kt*16)*64 + l)*8;
            #pragma unroll
            for (int nt = 0; nt < 16; ++nt) {
                short8 bf = *(const short8*)(bp + (size_t)nt*64*8);
                acc[0][nt] = __builtin_amdgcn_mfma_f32_16x16x32_bf16(a0, bf, acc[0][nt], 0, 0, 0);
                acc[1][nt] = __builtin_amdgcn_mfma_f32_16x16x32_bf16(a1, bf, acc[1][nt], 0, 0, 0);
            }
        }
        #pragma unroll
        for (int nt = 0; nt < 16; ++nt) {
            float bias = b_h[L*256 + nt*16 + m_l];
            #pragma unroll
            for (int mt = 0; mt < 2; ++mt)
                #pragma unroll
                for (int r = 0; r < 4; ++r) {
                    float vv = fmaxf(acc[mt][nt][r] + bias, 0.f);
                    act_s[(row0 + mt*16 + q*4 + r)*264 + nt*16 + m_l] = f2bs(vv);
                }
        }
    }
    float4v o0 = (float4v){0.f,0.f,0.f,0.f}, o1 = (float4v){0.f,0.f,0.f,0.f};
    for (int kt = 0; kt < 8; ++kt) {
        short8 a0 = *(const short8*)&act_s[(row0 + m_l)*264 + kt*32 + q*8];
        short8 a1 = *(const short8*)&act_s[(row0 + 16 + m_l)*264 + kt*32 + q*8];
        short8 bf = *(const short8*)(wpo + ((size_t)kt*64 + l)*8);
        o0 = __builtin_amdgcn_mfma_f32_16x16x32_bf16(a0, bf, o0, 0, 0, 0);
        o1 = __builtin_amdgcn_mfma_f32_16x16x32_bf16(a1, bf, o1, 0, 0, 0);
    }
    float bias = b_out[m_l];
    #pragma unroll
    for (int mt = 0; mt < 2; ++mt) {
        float4v* op = mt ? &o1 : &o0;
        #pragma unroll
        for (int r = 0; r < 4; ++r) {
            int e = E0 + row0 + mt*16 + q*4 + r;
            float scale = (e < 6132) ? 0.25f : 0.f;
            if (e >= 6132) e = 0;
            int bb = e / 1533; int rem = e - bb*1533;
            int cn = rem / 511; int eidx = rem - cn*511;
            int s0 = (eidx < 256) ? 255 : eidx - 256;
            int s1 = (eidx < 256) ? eidx : 255;
            atomicAdd(&fo[(((long)(bb*16 + m_l)) << 16) + (s0<<8) + s1],
                      scale * ((*op)[r] + bias));
        }
    }
}

// ---------------- final conv (16->4) + lrms_up -----------------------------------
__global__ __launch_bounds__(256) void final_k(const float* __restrict__ fo, const float* __restrict__ w,
                                               const float* __restrict__ lrms_up, float* __restrict__ out){
    int tid = threadIdx.x, bx = blockIdx.x;
    int y = bx & 255, oc = (bx >> 8) & 3, b = bx >> 10;
    int x = tid;
    const float* wg = w + (size_t)oc * 144;
    float acc = 0.f;
    for (int ic = 0; ic < 16; ++ic) {
        const float* base = fo + (((size_t)(b*16 + ic)) << 16);
        #pragma unroll
        for (int ky = 0; ky < 3; ++ky) {
            int yy = y + ky - 1; if (yy < 0 || yy > 255) continue;
            const float* rowp = base + (yy<<8);
            float v0 = (x > 0)   ? rowp[x-1] : 0.f;
            float v1 = rowp[x];
            float v2 = (x < 255) ? rowp[x+1] : 0.f;
            const float* wr = wg + ic*9 + ky*3;
            acc = fmaf(wr[0], v0, fmaf(wr[1], v1, fmaf(wr[2], v2, acc)));
        }
    }
    size_t oidx = (((size_t)(b*4 + oc)) << 16) + (y<<8) + x;
    out[oidx] = acc + lrms_up[oidx];
}

// ================================================================================
extern "C" void kernel_launch(void* const* d_in, const int* in_sizes, int n_in,
                              void* d_out, int out_size, void* d_ws, size_t ws_size,
                              hipStream_t stream) {
    const float* lrms     = (const float*)d_in[0];
    const float* pan      = (const float*)d_in[1];
    const float* w_convps = (const float*)d_in[2];
    const float* hor_w1   = (const float*)d_in[3];
    const float* hor_w2   = (const float*)d_in[4];
    const float* ffc_l2l  = (const float*)d_in[5];
    const float* ffc_l2g  = (const float*)d_in[6];
    const float* ffc_g2l  = (const float*)d_in[7];
    const float* ffc_spec = (const float*)d_in[8];
    const float* ref_in   = (const float*)d_in[9];
    const float* ref_b1   = (const float*)d_in[10];
    const float* ref_b2   = (const float*)d_in[11];
    const float* ref_ca1  = (const float*)d_in[12];
    const float* ref_ca2  = (const float*)d_in[13];
    const float* ref_out  = (const float*)d_in[14];
    const float* w_fuse   = (const float*)d_in[15];
    const float* w_liif   = (const float*)d_in[16];
    const float* w_hp     = (const float*)d_in[17];
    const float* mw_in    = (const float*)d_in[18];
    const float* mb_in    = (const float*)d_in[19];
    const float* mw_h     = (const float*)d_in[20];
    const float* mb_h     = (const float*)d_in[21];
    const float* mw_out   = (const float*)d_in[22];
    const float* mb_out   = (const float*)d_in[23];
    float* out = (float*)d_out;

    const size_t PLANE = 65536;
    char* base = (char*)d_ws;
    size_t off = 0;
    auto alloc = [&](size_t bytes){ void* p = base + off; off += (bytes + 255) & ~(size_t)255; return p; };
    float* lrms_up  = (float*)alloc(16*PLANE*4);
    bf16*  feat2    = (bf16*) alloc(24*PLANE*2);
    bf16*  bA       = (bf16*) alloc(192*PLANE*2);
    bf16*  bB       = (bf16*) alloc(192*PLANE*2);
    bf16*  bC       = (bf16*) alloc(192*PLANE*2);
    bf16*  bF       = (bf16*) alloc(192*PLANE*2);
    bf16*  fusedCat = (bf16*) alloc(192*PLANE*2);
    bf16*  feat_all = (bf16*) alloc(64*PLANE*2);
    float* fo       = (float*)alloc(64*PLANE*4);
    const size_t FFTB = (size_t)3*4*8*256*129;
    bf16* re0 = (bf16*)alloc(FFTB*2); bf16* im0 = (bf16*)alloc(FFTB*2);
    bf16* re1 = (bf16*)alloc(FFTB*2); bf16* im1 = (bf16*)alloc(FFTB*2);
    short* wpack = (short*)alloc(241664*2);
    float* ffcw  = (float*)alloc(13824*4);
    short* wconv = (short*)alloc(45*2560*2);
    float* means = (float*)alloc(192*4);
    float* cav   = (float*)alloc(192*4);
    if (off > ws_size) return;

    hipMemsetAsync(means, 0, 192*4, stream);
    repack_k<<<dim3(944), dim3(256), 0, stream>>>(mw_in, mw_h, mw_out, wpack);
    pack_ffcw_k<<<dim3(54), dim3(256), 0, stream>>>(ffc_l2l, ffc_l2g, ffc_g2l, ffcw);
    pack_convw_k<<<dim3(450), dim3(256), 0, stream>>>(hor_w2, ref_in, ref_b1, ref_b2, ffcw, wconv);
    conv_ps_k<<<dim3(4096), dim3(256), 0, stream>>>(lrms, w_convps, lrms_up);

    GK3 g3;
    {
        const int kss[3] = {5, 27, 41};
        const double sgs[3] = {1.5, 2.0, 2.8};
        for (int br = 0; br < 3; ++br) {
            g3.ks[br] = kss[br];
            double tmp[41]; double s = 0.0; double c = (kss[br]-1)/2.0;
            for (int i = 0; i < kss[br]; ++i) { double d = i - c; tmp[i] = exp(-(d*d)/(2.0*sgs[br]*sgs[br])); s += tmp[i]; }
            for (int i = 0; i < 41; ++i) g3.k[br][i] = (i < kss[br]) ? (float)(tmp[i]/s) : 0.f;
        }
    }
    gauss_hp_k<<<dim3(6144), dim3(256), 0, stream>>>(pan, lrms_up, feat2, g3);

    // hornet
    convA_k<<<dim3(3072), dim3(256), 0, stream>>>(feat2, 2, 2, hor_w1, 720, 45, bA, ACT_GELU);
    convM_k<<<dim3(3072), dim3(256), 0, stream>>>(bA, wconv + 0*3*2560, bB, ACT_NONE, nullptr);

    for (int step = 0; step < 3; ++step) {
        bf16* Xin = (step == 0) ? bB : bA;
        bf16* Yb  = (step == 0) ? bA : bB;
        bf16* Db  = (step == 0) ? bB : bA;
        convM_k<<<dim3(3072), dim3(256), 0, stream>>>(Xin, wconv + (1+step)*3*2560, Yb, ACT_NONE, nullptr);
        convM_k<<<dim3(3072), dim3(256), 0, stream>>>(Yb,  wconv + (4+step)*3*2560, bC, ACT_RELU, nullptr);
        convM_k<<<dim3(3072), dim3(256), 0, stream>>>(bC,  wconv + (7+step)*3*2560, Db, ACT_NONE, means);
        ca_k<<<dim3(1), dim3(192), 0, stream>>>(means, ref_ca1, ref_ca2, step, cav);
        convOut_k<<<dim3(3072), dim3(256), 0, stream>>>(Yb, Db, cav, ref_out + step*2304, w_fuse, step, bF, fusedCat);
        if (step < 2) {
            convM_k<<<dim3(3072), dim3(256), 0, stream>>>(bF, wconv + (10+step)*3*2560, bA, ACT_NONE, nullptr);
            rfft_w_k<<<dim3(24576), dim3(256), 0, stream>>>(bF, re0, im0);
            fftspec_h_k<<<dim3(1548), dim3(256), 0, stream>>>(re0, im0, ffc_spec, step, re1, im1);
            irfft_w_k<<<dim3(24576), dim3(256), 0, stream>>>(re1, im1, bA);
        }
    }

    fuse1x1_k<<<dim3(1024), dim3(256), 0, stream>>>(fusedCat, w_liif, feat_all);
    mlp_mfma_k<<<dim3(2048), dim3(256), 128*264*2, stream>>>((const short*)feat_all, wpack, mb_in, mb_h, mb_out, fo);
    mlp_edge_mfma_k<<<dim3(48), dim3(256), 128*264*2, stream>>>((const short*)feat_all, wpack, mb_in, mb_h, mb_out, fo);
    final_k<<<dim3(4096), dim3(256), 0, stream>>>(fo, w_hp, lrms_up, out);
}

// Round 6
// 1845.527 us; speedup vs baseline: 7.2398x; 1.0487x over previous
//
#include <hip/hip_runtime.h>
#include <hip/hip_bf16.h>
#include <math.h>

typedef __hip_bfloat16 bf16;
typedef __attribute__((ext_vector_type(8))) short short8;
typedef __attribute__((ext_vector_type(4))) short short4v;
typedef __attribute__((ext_vector_type(4))) float float4v;

#define ACT_NONE 0
#define ACT_RELU 1
#define ACT_GELU 2

__device__ __forceinline__ float b2f(bf16 v){ return __bfloat162float(v); }
__device__ __forceinline__ bf16  f2b(float f){ return __float2bfloat16(f); }
__device__ __forceinline__ short f2bs(float f){ bf16 h = __float2bfloat16(f); return *reinterpret_cast<short*>(&h); }
__device__ __forceinline__ void rotc(float& tr, float& ti, float cr, float ci){
    float t = tr*cr - ti*ci; ti = tr*ci + ti*cr; tr = t;
}

struct GK3 { float k[3][41]; int ks[3]; };

// ---------------- pixel-shuffle conv ------------------------------------------
__global__ __launch_bounds__(256) void conv_ps_k(const float* __restrict__ lrms,
                                                 const float* __restrict__ w,
                                                 float* __restrict__ up){
    int tid = threadIdx.x, bx = blockIdx.x;
    int y = bx & 255, c = (bx >> 8) & 3, b = bx >> 10;
    int x = tid;
    int h = y >> 2, r1 = y & 3, ww = x >> 2, r2 = x & 3;
    int oc = c*16 + r1*4 + r2;
    float acc = 0.f;
    for (int ic = 0; ic < 4; ++ic) {
        const float* base = lrms + ((b*4 + ic) << 12);
        const float* wb = w + (oc*4 + ic)*9;
        #pragma unroll
        for (int ky = 0; ky < 3; ++ky) {
            int hh = h + ky - 1; if (hh < 0 || hh > 63) continue;
            #pragma unroll
            for (int kx = 0; kx < 3; ++kx) {
                int cc = ww + kx - 1; if (cc < 0 || cc > 63) continue;
                acc += base[(hh<<6) + cc] * wb[ky*3 + kx];
            }
        }
    }
    up[(((size_t)(b*4 + c)) << 16) + (y<<8) + x] = acc;
}

// ---------------- fused gaussian highpass -------------------------------------
__global__ __launch_bounds__(256) void gauss_hp_k(const float* __restrict__ pan,
                                                  const float* __restrict__ lrms_up,
                                                  bf16* __restrict__ feat2, GK3 g){
    int tid = threadIdx.x, bx = blockIdx.x;
    int y = bx & 255, b = (bx >> 8) & 3, src = (bx >> 10) & 1, br = bx >> 11;
    int ks = g.ks[br], p = ks >> 1;
    const float* gk = g.k[br];
    const float* s = src ? (lrms_up + (size_t)b*4*65536) : (pan + (size_t)b*65536);
    __shared__ float vext[296];
    for (int i = tid; i < 296; i += 256) {
        int xe = i - 20; int xr = xe < 0 ? -xe : (xe > 255 ? 510 - xe : xe);
        float acc = 0.f;
        for (int t = 0; t < ks; ++t) {
            int yy = y - p + t; yy = yy < 0 ? -yy : (yy > 255 ? 510 - yy : yy);
            acc += gk[t] * s[(yy<<8) + xr];
        }
        vext[i] = acc;
    }
    __syncthreads();
    int x = tid;
    float acc = 0.f;
    for (int t = 0; t < ks; ++t) acc += gk[t] * vext[x - p + t + 20];
    float o = s[(y<<8) + x];
    feat2[(((size_t)((br*4 + b)*2 + src)) << 16) + (y<<8) + x] = f2b(o - acc);
}

// ---------------- scalar 3x3 conv (hornet conv1, Cin=2) -------------------------
__global__ __launch_bounds__(256) void convA_k(const bf16* __restrict__ in, int inCper, int Cin,
                                               const float* __restrict__ wbase, int wbrstride, int wocstride,
                                               bf16* __restrict__ out, int act){
    int tid = threadIdx.x, bx = blockIdx.x;
    int y = bx & 255, b = (bx >> 8) & 3, br = bx >> 10;
    const float* w = wbase + (size_t)br * wbrstride;
    int x = tid;
    float acc[16];
    #pragma unroll
    for (int oc = 0; oc < 16; ++oc) acc[oc] = 0.f;
    for (int ic = 0; ic < Cin; ++ic) {
        const bf16* base = in + ((size_t)((br*4 + b)*inCper + ic) << 16);
        const float* wic = w + ic*9;
        #pragma unroll
        for (int ky = 0; ky < 3; ++ky) {
            int yy = y + ky - 1; if (yy < 0 || yy > 255) continue;
            const bf16* rowp = base + (yy<<8);
            float v0 = (x > 0)   ? b2f(rowp[x-1]) : 0.f;
            float v1 = b2f(rowp[x]);
            float v2 = (x < 255) ? b2f(rowp[x+1]) : 0.f;
            const float* wr = wic + ky*3;
            #pragma unroll
            for (int oc = 0; oc < 16; ++oc) {
                const float* wo = wr + oc*wocstride;
                acc[oc] = fmaf(wo[0], v0, fmaf(wo[1], v1, fmaf(wo[2], v2, acc[oc])));
            }
        }
    }
    #pragma unroll
    for (int oc = 0; oc < 16; ++oc) {
        float a = acc[oc];
        if (act == ACT_RELU) a = fmaxf(a, 0.f);
        else if (act == ACT_GELU) {
            float u = 0.7978845608028654f * (a + 0.044715f*a*a*a);
            a = 0.5f * a * (1.f + tanhf(u));
        }
        out[((size_t)((br*4 + b)*16 + oc) << 16) + (y<<8) + x] = f2b(a);
    }
}

// ---------------- pack conv weights for MFMA: 45 sets x [kt5][lane64][j8] --------
__global__ __launch_bounds__(256) void pack_convw_k(const float* __restrict__ hor_w2,
        const float* __restrict__ ref_in, const float* __restrict__ ref_b1,
        const float* __restrict__ ref_b2, const float* __restrict__ ffcw,
        short* __restrict__ wp){
    int idx = blockIdx.x*256 + threadIdx.x;
    if (idx >= 45*2560) return;
    int set = idx / 2560, r = idx % 2560;
    int j = r & 7, l = (r>>3) & 63, kt = r >> 9;
    int k = kt*32 + ((l>>4)&3)*8 + j;
    int n = l & 15;
    int g = set / 3, br = set % 3;
    float v = 0.f;
    if (k < 144 && g < 12) {
        int tap = k >> 4, ic = k & 15;
        int widx = (n*16 + ic)*9 + tap;
        const float* src;
        if (g == 0)       src = hor_w2 + br*2304;
        else if (g <= 3)  src = ref_in + (3*br + (g-1))*2304;
        else if (g <= 6)  src = ref_b1 + (3*br + (g-4))*2304;
        else if (g <= 9)  src = ref_b2 + (3*br + (g-7))*2304;
        else              src = ffcw   + (2*br + (g-10))*2304;
        v = src[widx];
    }
    wp[idx] = f2bs(v);
}

// ---------------- MFMA 3x3 conv, 4 output rows per block ------------------------
// grid 768: y0=(bx&63)*4, b=(bx>>6)&3, br=bx>>8. Wave w computes row y0+w.
__global__ __launch_bounds__(256) void convM_k(const bf16* __restrict__ in,
        const short* __restrict__ wgroup,
        bf16* __restrict__ out, int act, float* __restrict__ means){
    __shared__ short sIn[6*258*20];
    __shared__ float sm[4][16];
    int tid = threadIdx.x, bx = blockIdx.x;
    int y0 = (bx & 63) << 2, b = (bx >> 6) & 3, br = bx >> 8;
    size_t pbase = (size_t)((br*4 + b)*16) << 16;
    if (tid < 192) {
        int r = tid >> 5, side = (tid >> 4) & 1, ic = tid & 15;
        sIn[(r*258 + (side ? 257 : 0))*20 + ic] = 0;
    }
    {
        int g = tid >> 5, tl = tid & 31, x0 = tl << 3, ic0 = g*2;
        for (int r = 0; r < 6; ++r) {
            int yy = y0 - 1 + r;
            short8 lo = {0,0,0,0,0,0,0,0}, hi = {0,0,0,0,0,0,0,0};
            if (yy >= 0 && yy <= 255) {
                lo = *(const short8*)&in[pbase + ((size_t)ic0<<16) + (yy<<8) + x0];
                hi = *(const short8*)&in[pbase + ((size_t)(ic0+1)<<16) + (yy<<8) + x0];
            }
            #pragma unroll
            for (int t = 0; t < 8; ++t) {
                int v = (int)(unsigned short)lo[t] | ((int)(unsigned short)hi[t] << 16);
                *(int*)&sIn[(r*258 + x0 + t + 1)*20 + ic0] = v;
            }
        }
    }
    __syncthreads();
    int l = tid & 63, w = tid >> 6, m_l = l & 15, q = l >> 4;
    const short* wp = wgroup + br*2560;
    short8 bfr[5];
    #pragma unroll
    for (int kt = 0; kt < 5; ++kt)
        bfr[kt] = *(const short8*)(wp + (kt*64 + l)*8);
    float4v acc[16];
    #pragma unroll
    for (int j = 0; j < 16; ++j) acc[j] = (float4v){0.f,0.f,0.f,0.f};
    #pragma unroll
    for (int kt = 0; kt < 5; ++kt) {
        int k0 = kt*32 + q*8;
        bool pad = (k0 >= 144);
        int tap = pad ? 0 : (k0 >> 4);
        int icb = k0 & 15;
        int ky = tap/3, kx = tap - ky*3;
        int rbase = (w + ky)*258 + kx;
        #pragma unroll
        for (int j = 0; j < 16; ++j) {
            int x = j*16 + m_l;
            const short* ap = &sIn[(rbase + x)*20 + icb];
            short4v alo = *(const short4v*)ap;
            short4v ahi = *(const short4v*)(ap + 4);
            short8 a;
            #pragma unroll
            for (int t = 0; t < 4; ++t) { a[t] = pad ? (short)0 : alo[t]; a[t+4] = pad ? (short)0 : ahi[t]; }
            acc[j] = __builtin_amdgcn_mfma_f32_16x16x32_bf16(a, bfr[kt], acc[j], 0, 0, 0);
        }
    }
    if (means) {
        float s = 0.f;
        #pragma unroll
        for (int j = 0; j < 16; ++j)
            #pragma unroll
            for (int r = 0; r < 4; ++r) s += acc[j][r];
        s += __shfl_xor(s, 16, 64);
        s += __shfl_xor(s, 32, 64);
        if (l < 16) sm[w][l] = s;
        __syncthreads();
        if (tid < 16) atomicAdd(&means[br*64 + b*16 + tid],
                                sm[0][tid] + sm[1][tid] + sm[2][tid] + sm[3][tid]);
    }
    int yrow = y0 + w;
    #pragma unroll
    for (int j = 0; j < 16; ++j) {
        #pragma unroll
        for (int r = 0; r < 4; ++r) {
            float a = acc[j][r];
            if (act == ACT_RELU) a = fmaxf(a, 0.f);
            else if (act == ACT_GELU) {
                float u = 0.7978845608028654f * (a + 0.044715f*a*a*a);
                a = 0.5f * a * (1.f + tanhf(u));
            }
            int x = j*16 + q*4 + r;
            out[pbase + ((size_t)m_l << 16) + (yrow<<8) + x] = f2b(a);
        }
    }
}

// ---------------- refine output conv (scalar; fused Y+ca*BDY, + fuse 1x1) -------
__global__ __launch_bounds__(256) void convOut_k(const bf16* __restrict__ Y, const bf16* __restrict__ BDY,
                                                 const float* __restrict__ cav, const float* __restrict__ wout,
                                                 const float* __restrict__ wfuse, int step,
                                                 bf16* __restrict__ F, bf16* __restrict__ fusedCat){
    int tid = threadIdx.x, bx = blockIdx.x;
    int y = bx & 255, b = (bx >> 8) & 3, br = bx >> 10;
    const float* w = wout + (size_t)br * 6912;
    float cc[16];
    #pragma unroll
    for (int ic = 0; ic < 16; ++ic) cc[ic] = cav[br*64 + b*16 + ic];
    int x = tid;
    float acc[16];
    #pragma unroll
    for (int oc = 0; oc < 16; ++oc) acc[oc] = 0.f;
    for (int ic = 0; ic < 16; ++ic) {
        size_t plane = (size_t)((br*4 + b)*16 + ic) << 16;
        const bf16* yb = Y + plane; const bf16* db = BDY + plane;
        float c0 = cc[ic];
        const float* wic = w + ic*9;
        #pragma unroll
        for (int ky = 0; ky < 3; ++ky) {
            int yy = y + ky - 1; if (yy < 0 || yy > 255) continue;
            const bf16* yr = yb + (yy<<8); const bf16* dr = db + (yy<<8);
            float v0 = (x > 0)   ? fmaf(b2f(dr[x-1]), c0, b2f(yr[x-1])) : 0.f;
            float v1 = fmaf(b2f(dr[x]), c0, b2f(yr[x]));
            float v2 = (x < 255) ? fmaf(b2f(dr[x+1]), c0, b2f(yr[x+1])) : 0.f;
            const float* wr = wic + ky*3;
            #pragma unroll
            for (int oc = 0; oc < 16; ++oc) {
                const float* wo = wr + oc*144;
                acc[oc] = fmaf(wo[0], v0, fmaf(wo[1], v1, fmaf(wo[2], v2, acc[oc])));
            }
        }
    }
    #pragma unroll
    for (int oc = 0; oc < 16; ++oc)
        F[((size_t)((br*4 + b)*16 + oc) << 16) + (y<<8) + x] = f2b(acc[oc]);
    const float* wf = wfuse + br*768 + step*16;
    #pragma unroll
    for (int oc2 = 0; oc2 < 16; ++oc2) {
        float s = 0.f;
        #pragma unroll
        for (int oc = 0; oc < 16; ++oc) s += wf[oc2*48 + oc] * acc[oc];
        size_t fidx = ((size_t)(b*48 + br*16 + oc2) << 16) + (y<<8) + x;
        if (step == 0) fusedCat[fidx] = f2b(s);
        else           fusedCat[fidx] = f2b(b2f(fusedCat[fidx]) + s);
    }
}

// ---------------- channel attention; rezeros means -------------------------------
__global__ void ca_k(float* __restrict__ means, const float* __restrict__ ca1,
                     const float* __restrict__ ca2, int step, float* __restrict__ cav){
    int t = threadIdx.x;  // 192
    int br = t >> 6, rem = t & 63, b = rem >> 4, oc = rem & 15;
    int ri = 3*br + step;
    const float* w1 = ca1 + ri*64; const float* w2 = ca2 + ri*64;
    float hid[4];
    #pragma unroll
    for (int c2 = 0; c2 < 4; ++c2) {
        float a = 0.f;
        for (int c = 0; c < 16; ++c) a += w1[c2*16 + c] * (means[br*64 + b*16 + c] * (1.f/65536.f));
        hid[c2] = fmaxf(a, 0.f);
    }
    float v = 0.f;
    #pragma unroll
    for (int c2 = 0; c2 < 4; ++c2) v += w2[oc*4 + c2] * hid[c2];
    cav[t] = 1.f / (1.f + expf(-v));
    __syncthreads();
    means[t] = 0.f;
}

// ---------------- radix-16 rfft along W (bf16 IO) --------------------------------
__global__ __launch_bounds__(256) void rfft_w_k(const bf16* __restrict__ F,
                                                bf16* __restrict__ ore, bf16* __restrict__ oim){
    int tid = threadIdx.x, bx = blockIdx.x;
    int y = bx & 255, c = (bx >> 8) & 7, b = (bx >> 11) & 3, br = bx >> 13;
    __shared__ float row[256], Ar[256], Ai[256];
    row[tid] = b2f(F[((size_t)((br*4 + b)*16 + 8 + c) << 16) + (y<<8) + tid]);
    __syncthreads();
    int n1 = tid >> 4, k1 = tid & 15;
    float a1 = -6.283185307179586f * (float)k1 / 16.f;
    float c1, s1; __sincosf(a1, &s1, &c1);
    float twr = 1.f, twi = 0.f, ar = 0.f, ai = 0.f;
    #pragma unroll
    for (int n2 = 0; n2 < 16; ++n2) {
        float xr = row[n1 + (n2<<4)];
        ar = fmaf(xr, twr, ar); ai = fmaf(xr, twi, ai);
        rotc(twr, twi, c1, s1);
    }
    Ar[tid] = ar; Ai[tid] = ai;
    __syncthreads();
    int k = tid, kk1 = k & 15;
    float a2 = -6.283185307179586f * (float)k / 256.f;
    float c2v, s2v; __sincosf(a2, &s2v, &c2v);
    float t2r = 1.f, t2i = 0.f, re = 0.f, im = 0.f;
    #pragma unroll
    for (int m = 0; m < 16; ++m) {
        float r = Ar[(m<<4) + kk1], i = Ai[(m<<4) + kk1];
        re += r*t2r - i*t2i; im += i*t2r + r*t2i;
        rotc(t2r, t2i, c2v, s2v);
    }
    if (k < 129) {
        size_t o = ((size_t)(((br*4 + b)*8 + c)*256 + y))*129 + k;
        ore[o] = f2b(re * 0.0625f); oim[o] = f2b(im * 0.0625f);
    }
}

// ---------------- FUSED: fft_h fwd (8ch) -> spec 1x1+relu -> fft_h inv (8ch) -----
__global__ __launch_bounds__(256) void fftspec_h_k(const bf16* __restrict__ re0, const bf16* __restrict__ im0,
                                                   const float* __restrict__ wspec, int step,
                                                   bf16* __restrict__ re1, bf16* __restrict__ im1){
    __shared__ float Fr[8][256], Fi[8][256], Sr[8][256], Si[8][256], Ar[256], Ai[256];
    int tid = threadIdx.x, bx = blockIdx.x;
    int k = bx % 129; int r2 = bx / 129; int b = r2 & 3, br = r2 >> 2;
    size_t cb = ((size_t)((br*4 + b)*8))*33024 + k;
    int n1 = tid >> 4, k1 = tid & 15;
    float a1 = -6.283185307179586f * (float)k1 / 16.f;
    float c1, s1; __sincosf(a1, &s1, &c1);
    float a2 = -6.283185307179586f * (float)tid / 256.f;
    float c2v, s2v; __sincosf(a2, &s2v, &c2v);
    #pragma unroll
    for (int c = 0; c < 8; ++c) {
        size_t base = cb + (size_t)c*33024 + (size_t)tid*129;
        Fr[c][tid] = b2f(re0[base]);
        Fi[c][tid] = b2f(im0[base]);
    }
    __syncthreads();
    for (int c = 0; c < 8; ++c) {
        float twr = 1.f, twi = 0.f, ar = 0.f, ai = 0.f;
        #pragma unroll
        for (int n2 = 0; n2 < 16; ++n2) {
            float r = Fr[c][n1 + (n2<<4)], i = Fi[c][n1 + (n2<<4)];
            ar += r*twr - i*twi; ai += i*twr + r*twi;
            rotc(twr, twi, c1, s1);
        }
        Ar[tid] = ar; Ai[tid] = ai;
        __syncthreads();
        float t2r = 1.f, t2i = 0.f, rr = 0.f, ii = 0.f;
        #pragma unroll
        for (int m = 0; m < 16; ++m) {
            float r = Ar[(m<<4) + k1], i = Ai[(m<<4) + k1];
            rr += r*t2r - i*t2i; ii += i*t2r + r*t2i;
            rotc(t2r, t2i, c2v, s2v);
        }
        Sr[c][tid] = rr * 0.0625f; Si[c][tid] = ii * 0.0625f;
        __syncthreads();
    }
    {
        const float* wl = wspec + (2*br + step)*256;
        float outv[16];
        #pragma unroll
        for (int oc = 0; oc < 16; ++oc) {
            float acc = 0.f;
            #pragma unroll
            for (int ic = 0; ic < 8; ++ic)
                acc += Sr[ic][tid] * wl[oc*16 + ic] + Si[ic][tid] * wl[oc*16 + 8 + ic];
            outv[oc] = fmaxf(acc, 0.f);
        }
        __syncthreads();
        #pragma unroll
        for (int oc = 0; oc < 8; ++oc) { Fr[oc][tid] = outv[oc]; Fi[oc][tid] = outv[oc+8]; }
        __syncthreads();
    }
    for (int c = 0; c < 8; ++c) {
        float twr = 1.f, twi = 0.f, ar = 0.f, ai = 0.f;
        #pragma unroll
        for (int n2 = 0; n2 < 16; ++n2) {
            float r = Fr[c][n1 + (n2<<4)], i = Fi[c][n1 + (n2<<4)];
            ar += r*twr + i*twi;
            ai += i*twr - r*twi;
            rotc(twr, twi, c1, s1);
        }
        Ar[tid] = ar; Ai[tid] = ai;
        __syncthreads();
        float t2r = 1.f, t2i = 0.f, rr = 0.f, ii = 0.f;
        #pragma unroll
        for (int m = 0; m < 16; ++m) {
            float r = Ar[(m<<4) + k1], i = Ai[(m<<4) + k1];
            rr += r*t2r + i*t2i;
            ii += i*t2r - r*t2i;
            rotc(t2r, t2i, c2v, s2v);
        }
        size_t base = cb + (size_t)c*33024 + (size_t)tid*129;
        re1[base] = f2b(rr * 0.0625f);
        im1[base] = f2b(ii * 0.0625f);
        __syncthreads();
    }
}

// ---------------- c2r irfft along W, += into A ch0..7 ----------------------------
__global__ __launch_bounds__(256) void irfft_w_k(const bf16* __restrict__ re1, const bf16* __restrict__ im1,
                                                 bf16* __restrict__ A){
    int tid = threadIdx.x, bx = blockIdx.x;
    int y = bx & 255, c = (bx >> 8) & 7, b = (bx >> 11) & 3, br = bx >> 13;
    __shared__ float cr[256], ci[256], Ar[256], Ai[256];
    size_t base = ((size_t)(((br*4 + b)*8 + c)*256 + y))*129;
    if (tid < 129) {
        cr[tid] = b2f(re1[base + tid]);
        ci[tid] = (tid == 0 || tid == 128) ? 0.f : b2f(im1[base + tid]);
    }
    __syncthreads();
    if (tid >= 129) { cr[tid] = cr[256 - tid]; ci[tid] = -ci[256 - tid]; }
    __syncthreads();
    int n1 = tid >> 4, k1 = tid & 15;
    float a1 = 6.283185307179586f * (float)k1 / 16.f;
    float c1, s1; __sincosf(a1, &s1, &c1);
    float twr = 1.f, twi = 0.f, ar = 0.f, ai = 0.f;
    #pragma unroll
    for (int n2 = 0; n2 < 16; ++n2) {
        float r = cr[n1 + (n2<<4)], i = ci[n1 + (n2<<4)];
        ar += r*twr - i*twi; ai += i*twr + r*twi;
        rotc(twr, twi, c1, s1);
    }
    Ar[tid] = ar; Ai[tid] = ai;
    __syncthreads();
    int m = tid, mk1 = m & 15;
    float a2 = 6.283185307179586f * (float)m / 256.f;
    float c2v, s2v; __sincosf(a2, &s2v, &c2v);
    float t2r = 1.f, t2i = 0.f, racc = 0.f;
    #pragma unroll
    for (int q = 0; q < 16; ++q) {
        float r = Ar[(q<<4) + mk1], i = Ai[(q<<4) + mk1];
        racc += r*t2r - i*t2i;
        rotc(t2r, t2i, c2v, s2v);
    }
    size_t o = ((size_t)((br*4 + b)*16 + c) << 16) + (y<<8) + m;
    A[o] = f2b(b2f(A[o]) + racc * 0.0625f);
}

// ---------------- pack combined ffc conv weights ---------------------------------
__global__ __launch_bounds__(256) void pack_ffcw_k(const float* __restrict__ l2l, const float* __restrict__ l2g,
                                                   const float* __restrict__ g2l, float* __restrict__ wout){
    int idx = blockIdx.x*256 + threadIdx.x;
    if (idx >= 6*2304) return;
    int t = idx % 9; int ic = (idx/9) % 16; int oc = (idx/144) % 16; int wi = idx/2304;
    float v;
    if (oc < 8) v = (ic < 8) ? l2g[((wi*8 + oc)*8 + ic)*9 + t] : 0.f;
    else {
        int o = oc - 8;
        v = (ic < 8) ? l2l[((wi*8 + o)*8 + ic)*9 + t] : g2l[((wi*8 + o)*8 + (ic-8))*9 + t];
    }
    wout[idx] = v;
}

// ---------------- fuse 1x1 (48->16) ---------------------------------------------
__global__ __launch_bounds__(256) void fuse1x1_k(const bf16* __restrict__ fc, const float* __restrict__ wl,
                                                 bf16* __restrict__ feat_all){
    int tid = threadIdx.x, bx = blockIdx.x;
    int pt = bx & 255, b = bx >> 8;
    int p = (pt << 8) + tid;
    float acc[16];
    #pragma unroll
    for (int oc = 0; oc < 16; ++oc) acc[oc] = 0.f;
    for (int ic = 0; ic < 48; ++ic) {
        float v = b2f(fc[((size_t)(b*48 + ic) << 16) + p]);
        #pragma unroll
        for (int oc = 0; oc < 16; ++oc) acc[oc] = fmaf(wl[oc*48 + ic], v, acc[oc]);
    }
    #pragma unroll
    for (int oc = 0; oc < 16; ++oc)
        feat_all[((size_t)(b*16 + oc) << 16) + p] = f2b(acc[oc]);
}

// ---------------- MLP weight repack ---------------------------------------------
__global__ __launch_bounds__(256) void repack_k(const float* __restrict__ mw_in,
                                                const float* __restrict__ mw_h,
                                                const float* __restrict__ mw_out,
                                                short* __restrict__ wp){
    int idx = blockIdx.x*256 + threadIdx.x;
    const int S0 = 40960;
    const int SH = 65536;
    const int TOT = S0 + 3*SH + 4096;
    if (idx >= TOT) return;
    float val;
    if (idx < S0) {
        int j = idx & 7, l = (idx>>3) & 63, nt = (idx>>9) & 15, kt = idx >> 13;
        int k = kt*32 + (l>>4)*8 + j;
        int n = nt*16 + (l&15);
        val = (k < 148) ? mw_in[k*256 + n] : 0.f;
    } else if (idx < S0 + 3*SH) {
        int i2 = idx - S0;
        int L = i2 >> 16, r = i2 & 65535;
        int j = r & 7, l = (r>>3) & 63, nt = (r>>9) & 15, kt = r >> 13;
        int k = kt*32 + (l>>4)*8 + j;
        int n = nt*16 + (l&15);
        val = mw_h[L*65536 + k*256 + n];
    } else {
        int i3 = idx - S0 - 3*SH;
        int j = i3 & 7, l = (i3>>3) & 63, kt = i3 >> 9;
        int k = kt*32 + (l>>4)*8 + j;
        int oc = l & 15;
        val = mw_out[k*16 + oc];
    }
    wp[idx] = f2bs(val);
}

// ---------------- LIIF MLP via MFMA (center), 2x2 wave split ---------------------
// wave w: m-half mh=w&1 (4 m-tiles), n-half nh=w>>1 (8 n-tiles of 16)
__global__ __launch_bounds__(256) void mlp_mfma_k(const short* __restrict__ feat,
        const short* __restrict__ wp,
        const float* __restrict__ b_in, const float* __restrict__ b_h,
        const float* __restrict__ b_out,
        float* __restrict__ fo){
    extern __shared__ short act_s[];
    int tid = threadIdx.x, bx = blockIdx.x;
    long P0 = (long)bx * 128;
    for (int idx = tid; idx < 128*160; idx += 256) {
        int pp = idx / 160, j = idx - pp*160;
        long P = P0 + pp;
        int bb = (int)(P >> 16), pim = (int)(P & 65535);
        int s0 = pim >> 8, s1 = pim & 255;
        short v = 0;
        if (j < 144) {
            int iy = j/48, ix = (j>>4)%3, c2 = j&15;
            int yy = s0 + iy - 1, xx = s1 + ix - 1;
            if (yy >= 0 && yy < 256 && xx >= 0 && xx < 256)
                v = feat[(((long)(bb*16 + c2)) << 16) + (yy<<8) + xx];
        } else if (j == 146 || j == 147) v = 0x4000;
        act_s[pp*264 + j] = v;
    }
    __syncthreads();

    int l = tid & 63, w = tid >> 6;
    int m_l = l & 15, q = l >> 4;
    int mh = w & 1, nh = w >> 1;
    int mtb = mh*4, ntb = nh*8;
    const short* wph  = wp + 40960;
    const short* wpo  = wp + 40960 + 3*65536;

    float4v acc[4][8];
    // ---- layer 0 ----
    #pragma unroll
    for (int mt = 0; mt < 4; ++mt)
        #pragma unroll
        for (int nt = 0; nt < 8; ++nt) acc[mt][nt] = (float4v){0.f,0.f,0.f,0.f};
    for (int kt = 0; kt < 5; ++kt) {
        const short* bp = wp + ((size_t)(kt*16 + ntb)*64 + l)*8;
        short8 bfr[8];
        #pragma unroll
        for (int nt = 0; nt < 8; ++nt) bfr[nt] = *(const short8*)(bp + (size_t)nt*64*8);
        #pragma unroll
        for (int mt = 0; mt < 4; ++mt) {
            short8 a = *(const short8*)&act_s[((mtb+mt)*16 + m_l)*264 + kt*32 + q*8];
            #pragma unroll
            for (int nt = 0; nt < 8; ++nt)
                acc[mt][nt] = __builtin_amdgcn_mfma_f32_16x16x32_bf16(a, bfr[nt], acc[mt][nt], 0, 0, 0);
        }
    }
    __syncthreads();
    #pragma unroll
    for (int nt = 0; nt < 8; ++nt) {
        int n = (ntb + nt)*16 + m_l;
        float bias = b_in[n];
        #pragma unroll
        for (int mt = 0; mt < 4; ++mt)
            #pragma unroll
            for (int r = 0; r < 4; ++r) {
                float vv = fmaxf(acc[mt][nt][r] + bias, 0.f);
                act_s[((mtb+mt)*16 + q*4 + r)*264 + n] = f2bs(vv);
            }
    }
    __syncthreads();
    // ---- hidden layers ----
    for (int L = 0; L < 3; ++L) {
        #pragma unroll
        for (int mt = 0; mt < 4; ++mt)
            #pragma unroll
            for (int nt = 0; nt < 8; ++nt) acc[mt][nt] = (float4v){0.f,0.f,0.f,0.f};
        const short* wl = wph + (size_t)L * 65536;
        for (int kt = 0; kt < 8; ++kt) {
            const short* bp = wl + ((size_t)(kt*16 + ntb)*64 + l)*8;
            short8 bfr[8];
            #pragma unroll
            for (int nt = 0; nt < 8; ++nt) bfr[nt] = *(const short8*)(bp + (size_t)nt*64*8);
            #pragma unroll
            for (int mt = 0; mt < 4; ++mt) {
                short8 a = *(const short8*)&act_s[((mtb+mt)*16 + m_l)*264 + kt*32 + q*8];
                #pragma unroll
                for (int nt = 0; nt < 8; ++nt)
                    acc[mt][nt] = __builtin_amdgcn_mfma_f32_16x16x32_bf16(a, bfr[nt], acc[mt][nt], 0, 0, 0);
            }
        }
        __syncthreads();
        #pragma unroll
        for (int nt = 0; nt < 8; ++nt) {
            int n = (ntb + nt)*16 + m_l;
            float bias = b_h[L*256 + n];
            #pragma unroll
            for (int mt = 0; mt < 4; ++mt)
                #pragma unroll
                for (int r = 0; r < 4; ++r) {
                    float vv = fmaxf(acc[mt][nt][r] + bias, 0.f);
                    act_s[((mtb+mt)*16 + q*4 + r)*264 + n] = f2bs(vv);
                }
        }
        __syncthreads();
    }
    // ---- output layer: waves with nh==0 handle their m-half ----
    if (nh == 0) {
        float4v o[4];
        #pragma unroll
        for (int mt = 0; mt < 4; ++mt) o[mt] = (float4v){0.f,0.f,0.f,0.f};
        for (int kt = 0; kt < 8; ++kt) {
            short8 bf = *(const short8*)(wpo + ((size_t)kt*64 + l)*8);
            #pragma unroll
            for (int mt = 0; mt < 4; ++mt) {
                short8 a = *(const short8*)&act_s[((mtb+mt)*16 + m_l)*264 + kt*32 + q*8];
                o[mt] = __builtin_amdgcn_mfma_f32_16x16x32_bf16(a, bf, o[mt], 0, 0, 0);
            }
        }
        float bias = b_out[m_l];
        #pragma unroll
        for (int mt = 0; mt < 4; ++mt) {
            #pragma unroll
            for (int r = 0; r < 4; ++r) {
                long P = P0 + (mtb+mt)*16 + q*4 + r;
                int bb = (int)(P >> 16), pim = (int)(P & 65535);
                int s0 = pim >> 8, s1 = pim & 255;
                float w0 = (s0 == 255 || s1 == 255) ? 0.25f : 1.0f;
                fo[(((long)(bb*16 + m_l)) << 16) + pim] = w0 * (o[mt][r] + bias);
            }
        }
    }
}

// ---------------- LIIF MLP edge corners via MFMA (old structure, 48 blocks) ------
__global__ __launch_bounds__(256) void mlp_edge_mfma_k(const short* __restrict__ feat,
        const short* __restrict__ wp,
        const float* __restrict__ b_in, const float* __restrict__ b_h,
        const float* __restrict__ b_out,
        float* __restrict__ fo){
    extern __shared__ short act_s[];
    int tid = threadIdx.x, bx = blockIdx.x;
    int E0 = bx * 128;
    for (int idx = tid; idx < 128*160; idx += 256) {
        int pp = idx / 160, j = idx - pp*160;
        int e = E0 + pp; if (e >= 6132) e = 0;
        int bb = e / 1533; int rem = e - bb*1533;
        int cn = rem / 511; int eidx = rem - cn*511;
        int s0 = (eidx < 256) ? 255 : eidx - 256;
        int s1 = (eidx < 256) ? eidx : 255;
        int vx = (cn == 0) ? -1 : 1;
        int vy = (cn == 1) ? -1 : 1;
        int i0 = (vx > 0) ? min(s0+1, 255) : s0;
        int i1 = (vy > 0) ? min(s1+1, 255) : s1;
        short v = 0;
        if (j < 144) {
            int iy = j/48, ix = (j>>4)%3, c2 = j&15;
            int yy = i0 + iy - 1, xx = i1 + ix - 1;
            if (yy >= 0 && yy < 256 && xx >= 0 && xx < 256)
                v = feat[(((long)(bb*16 + c2)) << 16) + (yy<<8) + xx];
        } else if (j == 144) v = f2bs(2.f*(float)(s0 - i0));
        else if (j == 145) v = f2bs(2.f*(float)(s1 - i1));
        else if (j >= 146) v = 0x4000;
        act_s[pp*264 + j] = v;
    }
    __syncthreads();

    int l = tid & 63, w = tid >> 6;
    int m_l = l & 15, q = l >> 4;
    int row0 = w * 32;
    const short* wph  = wp + 40960;
    const short* wpo  = wp + 40960 + 3*65536;

    float4v acc[2][16];
    #pragma unroll
    for (int mt = 0; mt < 2; ++mt)
        #pragma unroll
        for (int nt = 0; nt < 16; ++nt) acc[mt][nt] = (float4v){0.f,0.f,0.f,0.f};
    for (int kt = 0; kt < 5; ++kt) {
        short8 a0 = *(const short8*)&act_s[(row0 + m_l)*264 + kt*32 + q*8];
        short8 a1 = *(const short8*)&act_s[(row0 + 16 + m_l)*264 + kt*32 + q*8];
        const short* bp = wp + ((size_t)(kt*16)*64 + l)*8;
        #pragma unroll
        for (int nt = 0; nt < 16; ++nt) {
            short8 bf = *(const short8*)(bp + (size_t)nt*64*8);
            acc[0][nt] = __builtin_amdgcn_mfma_f32_16x16x32_bf16(a0, bf, acc[0][nt], 0, 0, 0);
            acc[1][nt] = __builtin_amdgcn_mfma_f32_16x16x32_bf16(a1, bf, acc[1][nt], 0, 0, 0);
        }
    }
    #pragma unroll
    for (int nt = 0; nt < 16; ++nt) {
        float bias = b_in[nt*16 + m_l];
        #pragma unroll
        for (int mt = 0; mt < 2; ++mt)
            #pragma unroll
            for (int r = 0; r < 4; ++r) {
                float vv = fmaxf(acc[mt][nt][r] + bias, 0.f);
                act_s[(row0 + mt*16 + q*4 + r)*264 + nt*16 + m_l] = f2bs(vv);
            }
    }
    for (int L = 0; L < 3; ++L) {
        #pragma unroll
        for (int mt = 0; mt < 2; ++mt)
            #pragma unroll
            for (int nt = 0; nt < 16; ++nt) acc[mt][nt] = (float4v){0.f,0.f,0.f,0.f};
        const short* wl = wph + (size_t)L * 65536;
        for (int kt = 0; kt < 8; ++kt) {
            short8 a0 = *(const short8*)&act_s[(row0 + m_l)*264 + kt*32 + q*8];
            short8 a1 = *(const short8*)&act_s[(row0 + 16 + m_l)*264 + kt*32 + q*8];
            const short* bp = wl + ((size_t)(kt*16)*64 + l)*8;
            #pragma unroll
            for (int nt = 0; nt < 16; ++nt) {
                short8 bf = *(const short8*)(bp + (size_t)nt*64*8);
                acc[0][nt] = __builtin_amdgcn_mfma_f32_16x16x32_bf16(a0, bf, acc[0][nt], 0, 0, 0);
                acc[1][nt] = __builtin_amdgcn_mfma_f32_16x16x32_bf16(a1, bf, acc[1][nt], 0, 0, 0);
            }
        }
        #pragma unroll
        for (int nt = 0; nt < 16; ++nt) {
            float bias = b_h[L*256 + nt*16 + m_l];
            #pragma unroll
            for (int mt = 0; mt < 2; ++mt)
                #pragma unroll
                for (int r = 0; r < 4; ++r) {
                    float vv = fmaxf(acc[mt][nt][r] + bias, 0.f);
                    act_s[(row0 + mt*16 + q*4 + r)*264 + nt*16 + m_l] = f2bs(vv);
                }
        }
    }
    float4v o0 = (float4v){0.f,0.f,0.f,0.f}, o1 = (float4v){0.f,0.f,0.f,0.f};
    for (int kt = 0; kt < 8; ++kt) {
        short8 a0 = *(const short8*)&act_s[(row0 + m_l)*264 + kt*32 + q*8];
        short8 a1 = *(const short8*)&act_s[(row0 + 16 + m_l)*264 + kt*32 + q*8];
        short8 bf = *(const short8*)(wpo + ((size_t)kt*64 + l)*8);
        o0 = __builtin_amdgcn_mfma_f32_16x16x32_bf16(a0, bf, o0, 0, 0, 0);
        o1 = __builtin_amdgcn_mfma_f32_16x16x32_bf16(a1, bf, o1, 0, 0, 0);
    }
    float bias = b_out[m_l];
    #pragma unroll
    for (int mt = 0; mt < 2; ++mt) {
        float4v* op = mt ? &o1 : &o0;
        #pragma unroll
        for (int r = 0; r < 4; ++r) {
            int e = E0 + row0 + mt*16 + q*4 + r;
            float scale = (e < 6132) ? 0.25f : 0.f;
            if (e >= 6132) e = 0;
            int bb = e / 1533; int rem = e - bb*1533;
            int cn = rem / 511; int eidx = rem - cn*511;
            int s0 = (eidx < 256) ? 255 : eidx - 256;
            int s1 = (eidx < 256) ? eidx : 255;
            atomicAdd(&fo[(((long)(bb*16 + m_l)) << 16) + (s0<<8) + s1],
                      scale * ((*op)[r] + bias));
        }
    }
}

// ---------------- final conv (16->4) + lrms_up -----------------------------------
__global__ __launch_bounds__(256) void final_k(const float* __restrict__ fo, const float* __restrict__ w,
                                               const float* __restrict__ lrms_up, float* __restrict__ out){
    int tid = threadIdx.x, bx = blockIdx.x;
    int y = bx & 255, oc = (bx >> 8) & 3, b = bx >> 10;
    int x = tid;
    const float* wg = w + (size_t)oc * 144;
    float acc = 0.f;
    for (int ic = 0; ic < 16; ++ic) {
        const float* base = fo + (((size_t)(b*16 + ic)) << 16);
        #pragma unroll
        for (int ky = 0; ky < 3; ++ky) {
            int yy = y + ky - 1; if (yy < 0 || yy > 255) continue;
            const float* rowp = base + (yy<<8);
            float v0 = (x > 0)   ? rowp[x-1] : 0.f;
            float v1 = rowp[x];
            float v2 = (x < 255) ? rowp[x+1] : 0.f;
            const float* wr = wg + ic*9 + ky*3;
            acc = fmaf(wr[0], v0, fmaf(wr[1], v1, fmaf(wr[2], v2, acc)));
        }
    }
    size_t oidx = (((size_t)(b*4 + oc)) << 16) + (y<<8) + x;
    out[oidx] = acc + lrms_up[oidx];
}

// ================================================================================
extern "C" void kernel_launch(void* const* d_in, const int* in_sizes, int n_in,
                              void* d_out, int out_size, void* d_ws, size_t ws_size,
                              hipStream_t stream) {
    const float* lrms     = (const float*)d_in[0];
    const float* pan      = (const float*)d_in[1];
    const float* w_convps = (const float*)d_in[2];
    const float* hor_w1   = (const float*)d_in[3];
    const float* hor_w2   = (const float*)d_in[4];
    const float* ffc_l2l  = (const float*)d_in[5];
    const float* ffc_l2g  = (const float*)d_in[6];
    const float* ffc_g2l  = (const float*)d_in[7];
    const float* ffc_spec = (const float*)d_in[8];
    const float* ref_in   = (const float*)d_in[9];
    const float* ref_b1   = (const float*)d_in[10];
    const float* ref_b2   = (const float*)d_in[11];
    const float* ref_ca1  = (const float*)d_in[12];
    const float* ref_ca2  = (const float*)d_in[13];
    const float* ref_out  = (const float*)d_in[14];
    const float* w_fuse   = (const float*)d_in[15];
    const float* w_liif   = (const float*)d_in[16];
    const float* w_hp     = (const float*)d_in[17];
    const float* mw_in    = (const float*)d_in[18];
    const float* mb_in    = (const float*)d_in[19];
    const float* mw_h     = (const float*)d_in[20];
    const float* mb_h     = (const float*)d_in[21];
    const float* mw_out   = (const float*)d_in[22];
    const float* mb_out   = (const float*)d_in[23];
    float* out = (float*)d_out;

    const size_t PLANE = 65536;
    char* base = (char*)d_ws;
    size_t off = 0;
    auto alloc = [&](size_t bytes){ void* p = base + off; off += (bytes + 255) & ~(size_t)255; return p; };
    float* lrms_up  = (float*)alloc(16*PLANE*4);
    bf16*  feat2    = (bf16*) alloc(24*PLANE*2);
    bf16*  bA       = (bf16*) alloc(192*PLANE*2);
    bf16*  bB       = (bf16*) alloc(192*PLANE*2);
    bf16*  bC       = (bf16*) alloc(192*PLANE*2);
    bf16*  bF       = (bf16*) alloc(192*PLANE*2);
    bf16*  fusedCat = (bf16*) alloc(192*PLANE*2);
    bf16*  feat_all = (bf16*) alloc(64*PLANE*2);
    float* fo       = (float*)alloc(64*PLANE*4);
    const size_t FFTB = (size_t)3*4*8*256*129;
    bf16* re0 = (bf16*)alloc(FFTB*2); bf16* im0 = (bf16*)alloc(FFTB*2);
    bf16* re1 = (bf16*)alloc(FFTB*2); bf16* im1 = (bf16*)alloc(FFTB*2);
    short* wpack = (short*)alloc(241664*2);
    float* ffcw  = (float*)alloc(13824*4);
    short* wconv = (short*)alloc(45*2560*2);
    float* means = (float*)alloc(192*4);
    float* cav   = (float*)alloc(192*4);
    if (off > ws_size) return;

    hipMemsetAsync(means, 0, 192*4, stream);
    repack_k<<<dim3(944), dim3(256), 0, stream>>>(mw_in, mw_h, mw_out, wpack);
    pack_ffcw_k<<<dim3(54), dim3(256), 0, stream>>>(ffc_l2l, ffc_l2g, ffc_g2l, ffcw);
    pack_convw_k<<<dim3(450), dim3(256), 0, stream>>>(hor_w2, ref_in, ref_b1, ref_b2, ffcw, wconv);
    conv_ps_k<<<dim3(4096), dim3(256), 0, stream>>>(lrms, w_convps, lrms_up);

    GK3 g3;
    {
        const int kss[3] = {5, 27, 41};
        const double sgs[3] = {1.5, 2.0, 2.8};
        for (int br = 0; br < 3; ++br) {
            g3.ks[br] = kss[br];
            double tmp[41]; double s = 0.0; double c = (kss[br]-1)/2.0;
            for (int i = 0; i < kss[br]; ++i) { double d = i - c; tmp[i] = exp(-(d*d)/(2.0*sgs[br]*sgs[br])); s += tmp[i]; }
            for (int i = 0; i < 41; ++i) g3.k[br][i] = (i < kss[br]) ? (float)(tmp[i]/s) : 0.f;
        }
    }
    gauss_hp_k<<<dim3(6144), dim3(256), 0, stream>>>(pan, lrms_up, feat2, g3);

    // hornet
    convA_k<<<dim3(3072), dim3(256), 0, stream>>>(feat2, 2, 2, hor_w1, 720, 45, bA, ACT_GELU);
    convM_k<<<dim3(768), dim3(256), 0, stream>>>(bA, wconv + 0*3*2560, bB, ACT_NONE, nullptr);

    for (int step = 0; step < 3; ++step) {
        bf16* Xin = (step == 0) ? bB : bA;
        bf16* Yb  = (step == 0) ? bA : bB;
        bf16* Db  = (step == 0) ? bB : bA;
        convM_k<<<dim3(768), dim3(256), 0, stream>>>(Xin, wconv + (1+step)*3*2560, Yb, ACT_NONE, nullptr);
        convM_k<<<dim3(768), dim3(256), 0, stream>>>(Yb,  wconv + (4+step)*3*2560, bC, ACT_RELU, nullptr);
        convM_k<<<dim3(768), dim3(256), 0, stream>>>(bC,  wconv + (7+step)*3*2560, Db, ACT_NONE, means);
        ca_k<<<dim3(1), dim3(192), 0, stream>>>(means, ref_ca1, ref_ca2, step, cav);
        convOut_k<<<dim3(3072), dim3(256), 0, stream>>>(Yb, Db, cav, ref_out + step*2304, w_fuse, step, bF, fusedCat);
        if (step < 2) {
            convM_k<<<dim3(768), dim3(256), 0, stream>>>(bF, wconv + (10+step)*3*2560, bA, ACT_NONE, nullptr);
            rfft_w_k<<<dim3(24576), dim3(256), 0, stream>>>(bF, re0, im0);
            fftspec_h_k<<<dim3(1548), dim3(256), 0, stream>>>(re0, im0, ffc_spec, step, re1, im1);
            irfft_w_k<<<dim3(24576), dim3(256), 0, stream>>>(re1, im1, bA);
        }
    }

    fuse1x1_k<<<dim3(1024), dim3(256), 0, stream>>>(fusedCat, w_liif, feat_all);
    mlp_mfma_k<<<dim3(2048), dim3(256), 128*264*2, stream>>>((const short*)feat_all, wpack, mb_in, mb_h, mb_out, fo);
    mlp_edge_mfma_k<<<dim3(48), dim3(256), 128*264*2, stream>>>((const short*)feat_all, wpack, mb_in, mb_h, mb_out, fo);
    final_k<<<dim3(4096), dim3(256), 0, stream>>>(fo, w_hp, lrms_up, out);
}

// Round 8
// 1558.813 us; speedup vs baseline: 8.5714x; 1.1839x over previous
//
#include <hip/hip_runtime.h>
#include <hip/hip_bf16.h>
#include <math.h>

typedef __hip_bfloat16 bf16;
typedef __attribute__((ext_vector_type(8))) short short8;
typedef __attribute__((ext_vector_type(4))) short short4v;
typedef __attribute__((ext_vector_type(4))) float float4v;

#define ACT_NONE 0
#define ACT_RELU 1
#define ACT_GELU 2

__device__ __forceinline__ float b2f(bf16 v){ return __bfloat162float(v); }
__device__ __forceinline__ bf16  f2b(float f){ return __float2bfloat16(f); }
__device__ __forceinline__ short f2bs(float f){ bf16 h = __float2bfloat16(f); return *reinterpret_cast<short*>(&h); }
__device__ __forceinline__ float bs2f(short s){ return __uint_as_float(((unsigned)(unsigned short)s) << 16); }
__device__ __forceinline__ void rotc(float& tr, float& ti, float cr, float ci){
    float t = tr*cr - ti*ci; ti = tr*ci + ti*cr; tr = t;
}

struct GK3 { float k[3][41]; int ks[3]; };

// ---------------- pixel-shuffle conv ------------------------------------------
__global__ __launch_bounds__(256) void conv_ps_k(const float* __restrict__ lrms,
                                                 const float* __restrict__ w,
                                                 float* __restrict__ up){
    int tid = threadIdx.x, bx = blockIdx.x;
    int y = bx & 255, c = (bx >> 8) & 3, b = bx >> 10;
    int x = tid;
    int h = y >> 2, r1 = y & 3, ww = x >> 2, r2 = x & 3;
    int oc = c*16 + r1*4 + r2;
    float acc = 0.f;
    for (int ic = 0; ic < 4; ++ic) {
        const float* base = lrms + ((b*4 + ic) << 12);
        const float* wb = w + (oc*4 + ic)*9;
        #pragma unroll
        for (int ky = 0; ky < 3; ++ky) {
            int hh = h + ky - 1; if (hh < 0 || hh > 63) continue;
            #pragma unroll
            for (int kx = 0; kx < 3; ++kx) {
                int cc = ww + kx - 1; if (cc < 0 || cc > 63) continue;
                acc += base[(hh<<6) + cc] * wb[ky*3 + kx];
            }
        }
    }
    up[(((size_t)(b*4 + c)) << 16) + (y<<8) + x] = acc;
}

// ---------------- fused gaussian highpass -------------------------------------
__global__ __launch_bounds__(256) void gauss_hp_k(const float* __restrict__ pan,
                                                  const float* __restrict__ lrms_up,
                                                  bf16* __restrict__ feat2, GK3 g){
    int tid = threadIdx.x, bx = blockIdx.x;
    int y = bx & 255, b = (bx >> 8) & 3, src = (bx >> 10) & 1, br = bx >> 11;
    int ks = g.ks[br], p = ks >> 1;
    const float* gk = g.k[br];
    const float* s = src ? (lrms_up + (size_t)b*4*65536) : (pan + (size_t)b*65536);
    __shared__ float vext[296];
    for (int i = tid; i < 296; i += 256) {
        int xe = i - 20; int xr = xe < 0 ? -xe : (xe > 255 ? 510 - xe : xe);
        float acc = 0.f;
        for (int t = 0; t < ks; ++t) {
            int yy = y - p + t; yy = yy < 0 ? -yy : (yy > 255 ? 510 - yy : yy);
            acc += gk[t] * s[(yy<<8) + xr];
        }
        vext[i] = acc;
    }
    __syncthreads();
    int x = tid;
    float acc = 0.f;
    for (int t = 0; t < ks; ++t) acc += gk[t] * vext[x - p + t + 20];
    float o = s[(y<<8) + x];
    feat2[(((size_t)((br*4 + b)*2 + src)) << 16) + (y<<8) + x] = f2b(o - acc);
}

// ---------------- scalar 3x3 conv (hornet conv1, Cin=2) -------------------------
__global__ __launch_bounds__(256) void convA_k(const bf16* __restrict__ in, int inCper, int Cin,
                                               const float* __restrict__ wbase, int wbrstride, int wocstride,
                                               bf16* __restrict__ out, int act){
    int tid = threadIdx.x, bx = blockIdx.x;
    int y = bx & 255, b = (bx >> 8) & 3, br = bx >> 10;
    const float* w = wbase + (size_t)br * wbrstride;
    int x = tid;
    float acc[16];
    #pragma unroll
    for (int oc = 0; oc < 16; ++oc) acc[oc] = 0.f;
    for (int ic = 0; ic < Cin; ++ic) {
        const bf16* base = in + ((size_t)((br*4 + b)*inCper + ic) << 16);
        const float* wic = w + ic*9;
        #pragma unroll
        for (int ky = 0; ky < 3; ++ky) {
            int yy = y + ky - 1; if (yy < 0 || yy > 255) continue;
            const bf16* rowp = base + (yy<<8);
            float v0 = (x > 0)   ? b2f(rowp[x-1]) : 0.f;
            float v1 = b2f(rowp[x]);
            float v2 = (x < 255) ? b2f(rowp[x+1]) : 0.f;
            const float* wr = wic + ky*3;
            #pragma unroll
            for (int oc = 0; oc < 16; ++oc) {
                const float* wo = wr + oc*wocstride;
                acc[oc] = fmaf(wo[0], v0, fmaf(wo[1], v1, fmaf(wo[2], v2, acc[oc])));
            }
        }
    }
    #pragma unroll
    for (int oc = 0; oc < 16; ++oc) {
        float a = acc[oc];
        if (act == ACT_RELU) a = fmaxf(a, 0.f);
        else if (act == ACT_GELU) {
            float u = 0.7978845608028654f * (a + 0.044715f*a*a*a);
            a = 0.5f * a * (1.f + tanhf(u));
        }
        out[((size_t)((br*4 + b)*16 + oc) << 16) + (y<<8) + x] = f2b(a);
    }
}

// ---------------- pack conv weights for MFMA: 45 sets = 15 groups x 3 br ---------
__global__ __launch_bounds__(256) void pack_convw_k(const float* __restrict__ hor_w2,
        const float* __restrict__ ref_in, const float* __restrict__ ref_b1,
        const float* __restrict__ ref_b2, const float* __restrict__ ffcw,
        const float* __restrict__ ref_out,
        short* __restrict__ wp){
    int idx = blockIdx.x*256 + threadIdx.x;
    if (idx >= 45*2560) return;
    int set = idx / 2560, r = idx % 2560;
    int j = r & 7, l = (r>>3) & 63, kt = r >> 9;
    int k = kt*32 + ((l>>4)&3)*8 + j;
    int n = l & 15;
    int g = set / 3, br = set % 3;
    float v = 0.f;
    if (k < 144) {
        int tap = k >> 4, ic = k & 15;
        int widx = (n*16 + ic)*9 + tap;
        const float* src;
        if (g == 0)       src = hor_w2 + br*2304;
        else if (g <= 3)  src = ref_in + (3*br + (g-1))*2304;
        else if (g <= 6)  src = ref_b1 + (3*br + (g-4))*2304;
        else if (g <= 9)  src = ref_b2 + (3*br + (g-7))*2304;
        else if (g <= 11) src = ffcw   + (2*br + (g-10))*2304;
        else              src = ref_out + (3*br + (g-12))*2304;
        v = src[widx];
    }
    wp[idx] = f2bs(v);
}

// ---------------- MFMA 3x3 conv, 4 output rows per block ------------------------
__global__ __launch_bounds__(256) void convM_k(const bf16* __restrict__ in,
        const short* __restrict__ wgroup,
        bf16* __restrict__ out, int act, float* __restrict__ means){
    __shared__ short sIn[6*258*20];
    __shared__ float sm[4][16];
    int tid = threadIdx.x, bx = blockIdx.x;
    int y0 = (bx & 63) << 2, b = (bx >> 6) & 3, br = bx >> 8;
    size_t pbase = (size_t)((br*4 + b)*16) << 16;
    if (tid < 192) {
        int r = tid >> 5, side = (tid >> 4) & 1, ic = tid & 15;
        sIn[(r*258 + (side ? 257 : 0))*20 + ic] = 0;
    }
    {
        int g = tid >> 5, tl = tid & 31, x0 = tl << 3, ic0 = g*2;
        for (int r = 0; r < 6; ++r) {
            int yy = y0 - 1 + r;
            short8 lo = {0,0,0,0,0,0,0,0}, hi = {0,0,0,0,0,0,0,0};
            if (yy >= 0 && yy <= 255) {
                lo = *(const short8*)&in[pbase + ((size_t)ic0<<16) + (yy<<8) + x0];
                hi = *(const short8*)&in[pbase + ((size_t)(ic0+1)<<16) + (yy<<8) + x0];
            }
            #pragma unroll
            for (int t = 0; t < 8; ++t) {
                int v = (int)(unsigned short)lo[t] | ((int)(unsigned short)hi[t] << 16);
                *(int*)&sIn[(r*258 + x0 + t + 1)*20 + ic0] = v;
            }
        }
    }
    __syncthreads();
    int l = tid & 63, w = tid >> 6, m_l = l & 15, q = l >> 4;
    const short* wp = wgroup + br*2560;
    short8 bfr[5];
    #pragma unroll
    for (int kt = 0; kt < 5; ++kt)
        bfr[kt] = *(const short8*)(wp + (kt*64 + l)*8);
    float4v acc[16];
    #pragma unroll
    for (int j = 0; j < 16; ++j) acc[j] = (float4v){0.f,0.f,0.f,0.f};
    #pragma unroll
    for (int kt = 0; kt < 5; ++kt) {
        int k0 = kt*32 + q*8;
        bool pad = (k0 >= 144);
        int tap = pad ? 0 : (k0 >> 4);
        int icb = k0 & 15;
        int ky = tap/3, kx = tap - ky*3;
        int rbase = (w + ky)*258 + kx;
        #pragma unroll
        for (int j = 0; j < 16; ++j) {
            int x = j*16 + m_l;
            const short* ap = &sIn[(rbase + x)*20 + icb];
            short4v alo = *(const short4v*)ap;
            short4v ahi = *(const short4v*)(ap + 4);
            short8 a;
            #pragma unroll
            for (int t = 0; t < 4; ++t) { a[t] = pad ? (short)0 : alo[t]; a[t+4] = pad ? (short)0 : ahi[t]; }
            acc[j] = __builtin_amdgcn_mfma_f32_16x16x32_bf16(a, bfr[kt], acc[j], 0, 0, 0);
        }
    }
    if (means) {
        float s = 0.f;
        #pragma unroll
        for (int j = 0; j < 16; ++j)
            #pragma unroll
            for (int r = 0; r < 4; ++r) s += acc[j][r];
        s += __shfl_xor(s, 16, 64);
        s += __shfl_xor(s, 32, 64);
        if (l < 16) sm[w][l] = s;
        __syncthreads();
        if (tid < 16) atomicAdd(&means[br*64 + b*16 + tid],
                                sm[0][tid] + sm[1][tid] + sm[2][tid] + sm[3][tid]);
    }
    int yrow = y0 + w;
    #pragma unroll
    for (int j = 0; j < 16; ++j) {
        #pragma unroll
        for (int r = 0; r < 4; ++r) {
            float a = acc[j][r];
            if (act == ACT_RELU) a = fmaxf(a, 0.f);
            else if (act == ACT_GELU) {
                float u = 0.7978845608028654f * (a + 0.044715f*a*a*a);
                a = 0.5f * a * (1.f + tanhf(u));
            }
            int x = j*16 + q*4 + r;
            out[pbase + ((size_t)m_l << 16) + (yrow<<8) + x] = f2b(a);
        }
    }
}

// ---------------- MFMA refine-out conv: in = Y + ca*BDY, + fuse 1x1 epilogue ----
__global__ __launch_bounds__(256) void convOutM_k(const bf16* __restrict__ Y, const bf16* __restrict__ BDY,
        const float* __restrict__ cav, const short* __restrict__ wgroup,
        const float* __restrict__ wfuse, int step,
        bf16* __restrict__ F, bf16* __restrict__ fusedCat){
    __shared__ short sIn[6*258*20];
    int tid = threadIdx.x, bx = blockIdx.x;
    int y0 = (bx & 63) << 2, b = (bx >> 6) & 3, br = bx >> 8;
    size_t pbase = (size_t)((br*4 + b)*16) << 16;
    if (tid < 192) {
        int r = tid >> 5, side = (tid >> 4) & 1, ic = tid & 15;
        sIn[(r*258 + (side ? 257 : 0))*20 + ic] = 0;
    }
    {
        int g = tid >> 5, tl = tid & 31, x0 = tl << 3, ic0 = g*2;
        float c0 = cav[br*64 + b*16 + ic0];
        float c1 = cav[br*64 + b*16 + ic0 + 1];
        for (int r = 0; r < 6; ++r) {
            int yy = y0 - 1 + r;
            short8 ylo = {0,0,0,0,0,0,0,0}, yhi = ylo, dlo = ylo, dhi = ylo;
            if (yy >= 0 && yy <= 255) {
                size_t o0 = pbase + ((size_t)ic0<<16) + (yy<<8) + x0;
                size_t o1 = pbase + ((size_t)(ic0+1)<<16) + (yy<<8) + x0;
                ylo = *(const short8*)&Y[o0];   yhi = *(const short8*)&Y[o1];
                dlo = *(const short8*)&BDY[o0]; dhi = *(const short8*)&BDY[o1];
            }
            #pragma unroll
            for (int t = 0; t < 8; ++t) {
                short s0 = f2bs(fmaf(bs2f(dlo[t]), c0, bs2f(ylo[t])));
                short s1 = f2bs(fmaf(bs2f(dhi[t]), c1, bs2f(yhi[t])));
                int v = (int)(unsigned short)s0 | ((int)(unsigned short)s1 << 16);
                *(int*)&sIn[(r*258 + x0 + t + 1)*20 + ic0] = v;
            }
        }
    }
    __syncthreads();
    int l = tid & 63, w = tid >> 6, m_l = l & 15, q = l >> 4;
    const short* wp = wgroup + br*2560;
    short8 bfr[5];
    #pragma unroll
    for (int kt = 0; kt < 5; ++kt)
        bfr[kt] = *(const short8*)(wp + (kt*64 + l)*8);
    float4v acc[16];
    #pragma unroll
    for (int j = 0; j < 16; ++j) acc[j] = (float4v){0.f,0.f,0.f,0.f};
    #pragma unroll
    for (int kt = 0; kt < 5; ++kt) {
        int k0 = kt*32 + q*8;
        bool pad = (k0 >= 144);
        int tap = pad ? 0 : (k0 >> 4);
        int icb = k0 & 15;
        int ky = tap/3, kx = tap - ky*3;
        int rbase = (w + ky)*258 + kx;
        #pragma unroll
        for (int j = 0; j < 16; ++j) {
            int x = j*16 + m_l;
            const short* ap = &sIn[(rbase + x)*20 + icb];
            short4v alo = *(const short4v*)ap;
            short4v ahi = *(const short4v*)(ap + 4);
            short8 a;
            #pragma unroll
            for (int t = 0; t < 4; ++t) { a[t] = pad ? (short)0 : alo[t]; a[t+4] = pad ? (short)0 : ahi[t]; }
            acc[j] = __builtin_amdgcn_mfma_f32_16x16x32_bf16(a, bfr[kt], acc[j], 0, 0, 0);
        }
    }
    int yrow = y0 + w;
    // write F
    #pragma unroll
    for (int j = 0; j < 16; ++j)
        #pragma unroll
        for (int r = 0; r < 4; ++r)
            F[pbase + ((size_t)m_l << 16) + (yrow<<8) + (j*16 + q*4 + r)] = f2b(acc[j][r]);
    // fuse 1x1 via second MFMA: D2[pix][oc2] = F[pix][oc] * wf[oc][oc2]
    __syncthreads();            // everyone done reading sIn; reuse as sF
    short* sF = sIn + w*4096;   // per-wave 256px x 16oc
    #pragma unroll
    for (int j = 0; j < 16; ++j)
        #pragma unroll
        for (int r = 0; r < 4; ++r)
            sF[(j*16 + q*4 + r)*16 + m_l] = f2bs(acc[j][r]);
    const float* wf = wfuse + br*768 + step*16;   // wf[oc2*48 + oc]
    short8 b2;
    #pragma unroll
    for (int jj = 0; jj < 8; ++jj) {
        int k = q*8 + jj;
        b2[jj] = (k < 16) ? f2bs(wf[m_l*48 + k]) : (short)0;
    }
    #pragma unroll
    for (int mt = 0; mt < 16; ++mt) {
        short8 a2 = {0,0,0,0,0,0,0,0};
        if (q < 2) a2 = *(const short8*)&sF[(mt*16 + m_l)*16 + q*8];
        float4v d2 = (float4v){0.f,0.f,0.f,0.f};
        d2 = __builtin_amdgcn_mfma_f32_16x16x32_bf16(a2, b2, d2, 0, 0, 0);
        #pragma unroll
        for (int r = 0; r < 4; ++r) {
            size_t fidx = ((size_t)(b*48 + br*16 + m_l) << 16) + (yrow<<8) + (mt*16 + q*4 + r);
            if (step == 0) fusedCat[fidx] = f2b(d2[r]);
            else           fusedCat[fidx] = f2b(b2f(fusedCat[fidx]) + d2[r]);
        }
    }
}

// ---------------- channel attention; rezeros means -------------------------------
__global__ void ca_k(float* __restrict__ means, const float* __restrict__ ca1,
                     const float* __restrict__ ca2, int step, float* __restrict__ cav){
    int t = threadIdx.x;  // 192
    int br = t >> 6, rem = t & 63, b = rem >> 4, oc = rem & 15;
    int ri = 3*br + step;
    const float* w1 = ca1 + ri*64; const float* w2 = ca2 + ri*64;
    float hid[4];
    #pragma unroll
    for (int c2 = 0; c2 < 4; ++c2) {
        float a = 0.f;
        for (int c = 0; c < 16; ++c) a += w1[c2*16 + c] * (means[br*64 + b*16 + c] * (1.f/65536.f));
        hid[c2] = fmaxf(a, 0.f);
    }
    float v = 0.f;
    #pragma unroll
    for (int c2 = 0; c2 < 4; ++c2) v += w2[oc*4 + c2] * hid[c2];
    cav[t] = 1.f / (1.f + expf(-v));
    __syncthreads();
    means[t] = 0.f;
}

// ---------------- radix-16 rfft along W (bf16 IO) --------------------------------
__global__ __launch_bounds__(256) void rfft_w_k(const bf16* __restrict__ F,
                                                bf16* __restrict__ ore, bf16* __restrict__ oim){
    int tid = threadIdx.x, bx = blockIdx.x;
    int y = bx & 255, c = (bx >> 8) & 7, b = (bx >> 11) & 3, br = bx >> 13;
    __shared__ float row[256], Ar[256], Ai[256];
    row[tid] = b2f(F[((size_t)((br*4 + b)*16 + 8 + c) << 16) + (y<<8) + tid]);
    __syncthreads();
    int n1 = tid >> 4, k1 = tid & 15;
    float a1 = -6.283185307179586f * (float)k1 / 16.f;
    float c1, s1; __sincosf(a1, &s1, &c1);
    float twr = 1.f, twi = 0.f, ar = 0.f, ai = 0.f;
    #pragma unroll
    for (int n2 = 0; n2 < 16; ++n2) {
        float xr = row[n1 + (n2<<4)];
        ar = fmaf(xr, twr, ar); ai = fmaf(xr, twi, ai);
        rotc(twr, twi, c1, s1);
    }
    Ar[tid] = ar; Ai[tid] = ai;
    __syncthreads();
    int k = tid, kk1 = k & 15;
    float a2 = -6.283185307179586f * (float)k / 256.f;
    float c2v, s2v; __sincosf(a2, &s2v, &c2v);
    float t2r = 1.f, t2i = 0.f, re = 0.f, im = 0.f;
    #pragma unroll
    for (int m = 0; m < 16; ++m) {
        float r = Ar[(m<<4) + kk1], i = Ai[(m<<4) + kk1];
        re += r*t2r - i*t2i; im += i*t2r + r*t2i;
        rotc(t2r, t2i, c2v, s2v);
    }
    if (k < 129) {
        size_t o = ((size_t)(((br*4 + b)*8 + c)*256 + y))*129 + k;
        ore[o] = f2b(re * 0.0625f); oim[o] = f2b(im * 0.0625f);
    }
}

// ---------------- FUSED: fft_h fwd (8ch) -> spec 1x1+relu -> fft_h inv (8ch) -----
__global__ __launch_bounds__(256) void fftspec_h_k(const bf16* __restrict__ re0, const bf16* __restrict__ im0,
                                                   const float* __restrict__ wspec, int step,
                                                   bf16* __restrict__ re1, bf16* __restrict__ im1){
    __shared__ float Fr[8][256], Fi[8][256], Sr[8][256], Si[8][256], Ar[256], Ai[256];
    int tid = threadIdx.x, bx = blockIdx.x;
    int k = bx % 129; int r2 = bx / 129; int b = r2 & 3, br = r2 >> 2;
    size_t cb = ((size_t)((br*4 + b)*8))*33024 + k;
    int n1 = tid >> 4, k1 = tid & 15;
    float a1 = -6.283185307179586f * (float)k1 / 16.f;
    float c1, s1; __sincosf(a1, &s1, &c1);
    float a2 = -6.283185307179586f * (float)tid / 256.f;
    float c2v, s2v; __sincosf(a2, &s2v, &c2v);
    #pragma unroll
    for (int c = 0; c < 8; ++c) {
        size_t base = cb + (size_t)c*33024 + (size_t)tid*129;
        Fr[c][tid] = b2f(re0[base]);
        Fi[c][tid] = b2f(im0[base]);
    }
    __syncthreads();
    for (int c = 0; c < 8; ++c) {
        float twr = 1.f, twi = 0.f, ar = 0.f, ai = 0.f;
        #pragma unroll
        for (int n2 = 0; n2 < 16; ++n2) {
            float r = Fr[c][n1 + (n2<<4)], i = Fi[c][n1 + (n2<<4)];
            ar += r*twr - i*twi; ai += i*twr + r*twi;
            rotc(twr, twi, c1, s1);
        }
        Ar[tid] = ar; Ai[tid] = ai;
        __syncthreads();
        float t2r = 1.f, t2i = 0.f, rr = 0.f, ii = 0.f;
        #pragma unroll
        for (int m = 0; m < 16; ++m) {
            float r = Ar[(m<<4) + k1], i = Ai[(m<<4) + k1];
            rr += r*t2r - i*t2i; ii += i*t2r + r*t2i;
            rotc(t2r, t2i, c2v, s2v);
        }
        Sr[c][tid] = rr * 0.0625f; Si[c][tid] = ii * 0.0625f;
        __syncthreads();
    }
    {
        const float* wl = wspec + (2*br + step)*256;
        float outv[16];
        #pragma unroll
        for (int oc = 0; oc < 16; ++oc) {
            float acc = 0.f;
            #pragma unroll
            for (int ic = 0; ic < 8; ++ic)
                acc += Sr[ic][tid] * wl[oc*16 + ic] + Si[ic][tid] * wl[oc*16 + 8 + ic];
            outv[oc] = fmaxf(acc, 0.f);
        }
        __syncthreads();
        #pragma unroll
        for (int oc = 0; oc < 8; ++oc) { Fr[oc][tid] = outv[oc]; Fi[oc][tid] = outv[oc+8]; }
        __syncthreads();
    }
    for (int c = 0; c < 8; ++c) {
        float twr = 1.f, twi = 0.f, ar = 0.f, ai = 0.f;
        #pragma unroll
        for (int n2 = 0; n2 < 16; ++n2) {
            float r = Fr[c][n1 + (n2<<4)], i = Fi[c][n1 + (n2<<4)];
            ar += r*twr + i*twi;
            ai += i*twr - r*twi;
            rotc(twr, twi, c1, s1);
        }
        Ar[tid] = ar; Ai[tid] = ai;
        __syncthreads();
        float t2r = 1.f, t2i = 0.f, rr = 0.f, ii = 0.f;
        #pragma unroll
        for (int m = 0; m < 16; ++m) {
            float r = Ar[(m<<4) + k1], i = Ai[(m<<4) + k1];
            rr += r*t2r + i*t2i;
            ii += i*t2r - r*t2i;
            rotc(t2r, t2i, c2v, s2v);
        }
        size_t base = cb + (size_t)c*33024 + (size_t)tid*129;
        re1[base] = f2b(rr * 0.0625f);
        im1[base] = f2b(ii * 0.0625f);
        __syncthreads();
    }
}

// ---------------- c2r irfft along W, += into A ch0..7 ----------------------------
__global__ __launch_bounds__(256) void irfft_w_k(const bf16* __restrict__ re1, const bf16* __restrict__ im1,
                                                 bf16* __restrict__ A){
    int tid = threadIdx.x, bx = blockIdx.x;
    int y = bx & 255, c = (bx >> 8) & 7, b = (bx >> 11) & 3, br = bx >> 13;
    __shared__ float cr[256], ci[256], Ar[256], Ai[256];
    size_t base = ((size_t)(((br*4 + b)*8 + c)*256 + y))*129;
    if (tid < 129) {
        cr[tid] = b2f(re1[base + tid]);
        ci[tid] = (tid == 0 || tid == 128) ? 0.f : b2f(im1[base + tid]);
    }
    __syncthreads();
    if (tid >= 129) { cr[tid] = cr[256 - tid]; ci[tid] = -ci[256 - tid]; }
    __syncthreads();
    int n1 = tid >> 4, k1 = tid & 15;
    float a1 = 6.283185307179586f * (float)k1 / 16.f;
    float c1, s1; __sincosf(a1, &s1, &c1);
    float twr = 1.f, twi = 0.f, ar = 0.f, ai = 0.f;
    #pragma unroll
    for (int n2 = 0; n2 < 16; ++n2) {
        float r = cr[n1 + (n2<<4)], i = ci[n1 + (n2<<4)];
        ar += r*twr - i*twi; ai += i*twr + r*twi;
        rotc(twr, twi, c1, s1);
    }
    Ar[tid] = ar; Ai[tid] = ai;
    __syncthreads();
    int m = tid, mk1 = m & 15;
    float a2 = 6.283185307179586f * (float)m / 256.f;
    float c2v, s2v; __sincosf(a2, &s2v, &c2v);
    float t2r = 1.f, t2i = 0.f, racc = 0.f;
    #pragma unroll
    for (int q = 0; q < 16; ++q) {
        float r = Ar[(q<<4) + mk1], i = Ai[(q<<4) + mk1];
        racc += r*t2r - i*t2i;
        rotc(t2r, t2i, c2v, s2v);
    }
    size_t o = ((size_t)((br*4 + b)*16 + c) << 16) + (y<<8) + m;
    A[o] = f2b(b2f(A[o]) + racc * 0.0625f);
}

// ---------------- pack combined ffc conv weights ---------------------------------
__global__ __launch_bounds__(256) void pack_ffcw_k(const float* __restrict__ l2l, const float* __restrict__ l2g,
                                                   const float* __restrict__ g2l, float* __restrict__ wout){
    int idx = blockIdx.x*256 + threadIdx.x;
    if (idx >= 6*2304) return;
    int t = idx % 9; int ic = (idx/9) % 16; int oc = (idx/144) % 16; int wi = idx/2304;
    float v;
    if (oc < 8) v = (ic < 8) ? l2g[((wi*8 + oc)*8 + ic)*9 + t] : 0.f;
    else {
        int o = oc - 8;
        v = (ic < 8) ? l2l[((wi*8 + o)*8 + ic)*9 + t] : g2l[((wi*8 + o)*8 + (ic-8))*9 + t];
    }
    wout[idx] = v;
}

// ---------------- fuse 1x1 (48->16) ---------------------------------------------
__global__ __launch_bounds__(256) void fuse1x1_k(const bf16* __restrict__ fc, const float* __restrict__ wl,
                                                 bf16* __restrict__ feat_all){
    int tid = threadIdx.x, bx = blockIdx.x;
    int pt = bx & 255, b = bx >> 8;
    int p = (pt << 8) + tid;
    float acc[16];
    #pragma unroll
    for (int oc = 0; oc < 16; ++oc) acc[oc] = 0.f;
    for (int ic = 0; ic < 48; ++ic) {
        float v = b2f(fc[((size_t)(b*48 + ic) << 16) + p]);
        #pragma unroll
        for (int oc = 0; oc < 16; ++oc) acc[oc] = fmaf(wl[oc*48 + ic], v, acc[oc]);
    }
    #pragma unroll
    for (int oc = 0; oc < 16; ++oc)
        feat_all[((size_t)(b*16 + oc) << 16) + p] = f2b(acc[oc]);
}

// ---------------- MLP weight repack ---------------------------------------------
__global__ __launch_bounds__(256) void repack_k(const float* __restrict__ mw_in,
                                                const float* __restrict__ mw_h,
                                                const float* __restrict__ mw_out,
                                                short* __restrict__ wp){
    int idx = blockIdx.x*256 + threadIdx.x;
    const int S0 = 40960;
    const int SH = 65536;
    const int TOT = S0 + 3*SH + 4096;
    if (idx >= TOT) return;
    float val;
    if (idx < S0) {
        int j = idx & 7, l = (idx>>3) & 63, nt = (idx>>9) & 15, kt = idx >> 13;
        int k = kt*32 + (l>>4)*8 + j;
        int n = nt*16 + (l&15);
        val = (k < 148) ? mw_in[k*256 + n] : 0.f;
    } else if (idx < S0 + 3*SH) {
        int i2 = idx - S0;
        int L = i2 >> 16, r = i2 & 65535;
        int j = r & 7, l = (r>>3) & 63, nt = (r>>9) & 15, kt = r >> 13;
        int k = kt*32 + (l>>4)*8 + j;
        int n = nt*16 + (l&15);
        val = mw_h[L*65536 + k*256 + n];
    } else {
        int i3 = idx - S0 - 3*SH;
        int j = i3 & 7, l = (i3>>3) & 63, kt = i3 >> 9;
        int k = kt*32 + (l>>4)*8 + j;
        int oc = l & 15;
        val = mw_out[k*16 + oc];
    }
    wp[idx] = f2bs(val);
}

// ---------------- LIIF MLP via MFMA (center), 512 thr = 8 waves ------------------
// wave w: mh = w>>2 (2 m-halves of 4 mt), nq = w&3 (4 n-quarters of 4 nt)
__global__ __launch_bounds__(512) void mlp_mfma_k(const short* __restrict__ feat,
        const short* __restrict__ wp,
        const float* __restrict__ b_in, const float* __restrict__ b_h,
        const float* __restrict__ b_out,
        float* __restrict__ fo){
    extern __shared__ short act_s[];
    int tid = threadIdx.x, bx = blockIdx.x;
    long P0 = (long)bx * 128;
    for (int idx = tid; idx < 128*160; idx += 512) {
        int pp = idx / 160, j = idx - pp*160;
        long P = P0 + pp;
        int bb = (int)(P >> 16), pim = (int)(P & 65535);
        int s0 = pim >> 8, s1 = pim & 255;
        short v = 0;
        if (j < 144) {
            int iy = j/48, ix = (j>>4)%3, c2 = j&15;
            int yy = s0 + iy - 1, xx = s1 + ix - 1;
            if (yy >= 0 && yy < 256 && xx >= 0 && xx < 256)
                v = feat[(((long)(bb*16 + c2)) << 16) + (yy<<8) + xx];
        } else if (j == 146 || j == 147) v = 0x4000;
        act_s[pp*264 + j] = v;
    }
    __syncthreads();

    int l = tid & 63, w = tid >> 6;
    int m_l = l & 15, q = l >> 4;
    int mh = w >> 2, nq = w & 3;
    int mtb = mh*4, ntb = nq*4;
    const short* wph  = wp + 40960;
    const short* wpo  = wp + 40960 + 3*65536;

    float4v acc[4][4];
    // ---- layer 0 (K=160, 5 kt) ----
    #pragma unroll
    for (int mt = 0; mt < 4; ++mt)
        #pragma unroll
        for (int nt = 0; nt < 4; ++nt) acc[mt][nt] = (float4v){0.f,0.f,0.f,0.f};
    for (int kt = 0; kt < 5; ++kt) {
        const short* bp = wp + ((size_t)(kt*16 + ntb)*64 + l)*8;
        short8 bfr[4];
        #pragma unroll
        for (int nt = 0; nt < 4; ++nt) bfr[nt] = *(const short8*)(bp + (size_t)nt*64*8);
        #pragma unroll
        for (int mt = 0; mt < 4; ++mt) {
            short8 a = *(const short8*)&act_s[((mtb+mt)*16 + m_l)*264 + kt*32 + q*8];
            #pragma unroll
            for (int nt = 0; nt < 4; ++nt)
                acc[mt][nt] = __builtin_amdgcn_mfma_f32_16x16x32_bf16(a, bfr[nt], acc[mt][nt], 0, 0, 0);
        }
    }
    __syncthreads();
    #pragma unroll
    for (int nt = 0; nt < 4; ++nt) {
        int n = (ntb + nt)*16 + m_l;
        float bias = b_in[n];
        #pragma unroll
        for (int mt = 0; mt < 4; ++mt)
            #pragma unroll
            for (int r = 0; r < 4; ++r) {
                float vv = fmaxf(acc[mt][nt][r] + bias, 0.f);
                act_s[((mtb+mt)*16 + q*4 + r)*264 + n] = f2bs(vv);
            }
    }
    __syncthreads();
    // ---- hidden layers (K=256, 8 kt) ----
    for (int L = 0; L < 3; ++L) {
        #pragma unroll
        for (int mt = 0; mt < 4; ++mt)
            #pragma unroll
            for (int nt = 0; nt < 4; ++nt) acc[mt][nt] = (float4v){0.f,0.f,0.f,0.f};
        const short* wl = wph + (size_t)L * 65536;
        for (int kt = 0; kt < 8; ++kt) {
            const short* bp = wl + ((size_t)(kt*16 + ntb)*64 + l)*8;
            short8 bfr[4];
            #pragma unroll
            for (int nt = 0; nt < 4; ++nt) bfr[nt] = *(const short8*)(bp + (size_t)nt*64*8);
            #pragma unroll
            for (int mt = 0; mt < 4; ++mt) {
                short8 a = *(const short8*)&act_s[((mtb+mt)*16 + m_l)*264 + kt*32 + q*8];
                #pragma unroll
                for (int nt = 0; nt < 4; ++nt)
                    acc[mt][nt] = __builtin_amdgcn_mfma_f32_16x16x32_bf16(a, bfr[nt], acc[mt][nt], 0, 0, 0);
            }
        }
        __syncthreads();
        #pragma unroll
        for (int nt = 0; nt < 4; ++nt) {
            int n = (ntb + nt)*16 + m_l;
            float bias = b_h[L*256 + n];
            #pragma unroll
            for (int mt = 0; mt < 4; ++mt)
                #pragma unroll
                for (int r = 0; r < 4; ++r) {
                    float vv = fmaxf(acc[mt][nt][r] + bias, 0.f);
                    act_s[((mtb+mt)*16 + q*4 + r)*264 + n] = f2bs(vv);
                }
        }
        __syncthreads();
    }
    // ---- output layer (N=16): waves with nq==0 handle their m-half ----
    if (nq == 0) {
        float4v o[4];
        #pragma unroll
        for (int mt = 0; mt < 4; ++mt) o[mt] = (float4v){0.f,0.f,0.f,0.f};
        for (int kt = 0; kt < 8; ++kt) {
            short8 bf = *(const short8*)(wpo + ((size_t)kt*64 + l)*8);
            #pragma unroll
            for (int mt = 0; mt < 4; ++mt) {
                short8 a = *(const short8*)&act_s[((mtb+mt)*16 + m_l)*264 + kt*32 + q*8];
                o[mt] = __builtin_amdgcn_mfma_f32_16x16x32_bf16(a, bf, o[mt], 0, 0, 0);
            }
        }
        float bias = b_out[m_l];
        #pragma unroll
        for (int mt = 0; mt < 4; ++mt) {
            #pragma unroll
            for (int r = 0; r < 4; ++r) {
                long P = P0 + (mtb+mt)*16 + q*4 + r;
                int bb = (int)(P >> 16), pim = (int)(P & 65535);
                int s0 = pim >> 8, s1 = pim & 255;
                float w0 = (s0 == 255 || s1 == 255) ? 0.25f : 1.0f;
                fo[(((long)(bb*16 + m_l)) << 16) + pim] = w0 * (o[mt][r] + bias);
            }
        }
    }
}

// ---------------- LIIF MLP edge corners via MFMA (48 blocks) ---------------------
__global__ __launch_bounds__(256) void mlp_edge_mfma_k(const short* __restrict__ feat,
        const short* __restrict__ wp,
        const float* __restrict__ b_in, const float* __restrict__ b_h,
        const float* __restrict__ b_out,
        float* __restrict__ fo){
    extern __shared__ short act_s[];
    int tid = threadIdx.x, bx = blockIdx.x;
    int E0 = bx * 128;
    for (int idx = tid; idx < 128*160; idx += 256) {
        int pp = idx / 160, j = idx - pp*160;
        int e = E0 + pp; if (e >= 6132) e = 0;
        int bb = e / 1533; int rem = e - bb*1533;
        int cn = rem / 511; int eidx = rem - cn*511;
        int s0 = (eidx < 256) ? 255 : eidx - 256;
        int s1 = (eidx < 256) ? eidx : 255;
        int vx = (cn == 0) ? -1 : 1;
        int vy = (cn == 1) ? -1 : 1;
        int i0 = (vx > 0) ? min(s0+1, 255) : s0;
        int i1 = (vy > 0) ? min(s1+1, 255) : s1;
        short v = 0;
        if (j < 144) {
            int iy = j/48, ix = (j>>4)%3, c2 = j&15;
            int yy = i0 + iy - 1, xx = i1 + ix - 1;
            if (yy >= 0 && yy < 256 && xx >= 0 && xx < 256)
                v = feat[(((long)(bb*16 + c2)) << 16) + (yy<<8) + xx];
        } else if (j == 144) v = f2bs(2.f*(float)(s0 - i0));
        else if (j == 145) v = f2bs(2.f*(float)(s1 - i1));
        else if (j >= 146) v = 0x4000;
        act_s[pp*264 + j] = v;
    }
    __syncthreads();

    int l = tid & 63, w = tid >> 6;
    int m_l = l & 15, q = l >> 4;
    int row0 = w * 32;
    const short* wph  = wp + 40960;
    const short* wpo  = wp + 40960 + 3*65536;

    float4v acc[2][16];
    #pragma unroll
    for (int mt = 0; mt < 2; ++mt)
        #pragma unroll
        for (int nt = 0; nt < 16; ++nt) acc[mt][nt] = (float4v){0.f,0.f,0.f,0.f};
    for (int kt = 0; kt < 5; ++kt) {
        short8 a0 = *(const short8*)&act_s[(row0 + m_l)*264 + kt*32 + q*8];
        short8 a1 = *(const short8*)&act_s[(row0 + 16 + m_l)*264 + kt*32 + q*8];
        const short* bp = wp + ((size_t)(kt*16)*64 + l)*8;
        #pragma unroll
        for (int nt = 0; nt < 16; ++nt) {
            short8 bf = *(const short8*)(bp + (size_t)nt*64*8);
            acc[0][nt] = __builtin_amdgcn_mfma_f32_16x16x32_bf16(a0, bf, acc[0][nt], 0, 0, 0);
            acc[1][nt] = __builtin_amdgcn_mfma_f32_16x16x32_bf16(a1, bf, acc[1][nt], 0, 0, 0);
        }
    }
    #pragma unroll
    for (int nt = 0; nt < 16; ++nt) {
        float bias = b_in[nt*16 + m_l];
        #pragma unroll
        for (int mt = 0; mt < 2; ++mt)
            #pragma unroll
            for (int r = 0; r < 4; ++r) {
                float vv = fmaxf(acc[mt][nt][r] + bias, 0.f);
                act_s[(row0 + mt*16 + q*4 + r)*264 + nt*16 + m_l] = f2bs(vv);
            }
    }
    for (int L = 0; L < 3; ++L) {
        #pragma unroll
        for (int mt = 0; mt < 2; ++mt)
            #pragma unroll
            for (int nt = 0; nt < 16; ++nt) acc[mt][nt] = (float4v){0.f,0.f,0.f,0.f};
        const short* wl = wph + (size_t)L * 65536;
        for (int kt = 0; kt < 8; ++kt) {
            short8 a0 = *(const short8*)&act_s[(row0 + m_l)*264 + kt*32 + q*8];
            short8 a1 = *(const short8*)&act_s[(row0 + 16 + m_l)*264 + kt*32 + q*8];
            const short* bp = wl + ((size_t)(kt*16)*64 + l)*8;
            #pragma unroll
            for (int nt = 0; nt < 16; ++nt) {
                short8 bf = *(const short8*)(bp + (size_t)nt*64*8);
                acc[0][nt] = __builtin_amdgcn_mfma_f32_16x16x32_bf16(a0, bf, acc[0][nt], 0, 0, 0);
                acc[1][nt] = __builtin_amdgcn_mfma_f32_16x16x32_bf16(a1, bf, acc[1][nt], 0, 0, 0);
            }
        }
        #pragma unroll
        for (int nt = 0; nt < 16; ++nt) {
            float bias = b_h[L*256 + nt*16 + m_l];
            #pragma unroll
            for (int mt = 0; mt < 2; ++mt)
                #pragma unroll
                for (int r = 0; r < 4; ++r) {
                    float vv = fmaxf(acc[mt][nt][r] + bias, 0.f);
                    act_s[(row0 + mt*16 + q*4 + r)*264 + nt*16 + m_l] = f2bs(vv);
                }
        }
    }
    float4v o0 = (float4v){0.f,0.f,0.f,0.f}, o1 = (float4v){0.f,0.f,0.f,0.f};
    for (int kt = 0; kt < 8; ++kt) {
        short8 a0 = *(const short8*)&act_s[(row0 + m_l)*264 + kt*32 + q*8];
        short8 a1 = *(const short8*)&act_s[(row0 + 16 + m_l)*264 + kt*32 + q*8];
        short8 bf = *(const short8*)(wpo + ((size_t)kt*64 + l)*8);
        o0 = __builtin_amdgcn_mfma_f32_16x16x32_bf16(a0, bf, o0, 0, 0, 0);
        o1 = __builtin_amdgcn_mfma_f32_16x16x32_bf16(a1, bf, o1, 0, 0, 0);
    }
    float bias = b_out[m_l];
    #pragma unroll
    for (int mt = 0; mt < 2; ++mt) {
        float4v* op = mt ? &o1 : &o0;
        #pragma unroll
        for (int r = 0; r < 4; ++r) {
            int e = E0 + row0 + mt*16 + q*4 + r;
            float scale = (e < 6132) ? 0.25f : 0.f;
            if (e >= 6132) e = 0;
            int bb = e / 1533; int rem = e - bb*1533;
            int cn = rem / 511; int eidx = rem - cn*511;
            int s0 = (eidx < 256) ? 255 : eidx - 256;
            int s1 = (eidx < 256) ? eidx : 255;
            atomicAdd(&fo[(((long)(bb*16 + m_l)) << 16) + (s0<<8) + s1],
                      scale * ((*op)[r] + bias));
        }
    }
}

// ---------------- final conv (16->4) + lrms_up -----------------------------------
__global__ __launch_bounds__(256) void final_k(const float* __restrict__ fo, const float* __restrict__ w,
                                               const float* __restrict__ lrms_up, float* __restrict__ out){
    int tid = threadIdx.x, bx = blockIdx.x;
    int y = bx & 255, oc = (bx >> 8) & 3, b = bx >> 10;
    int x = tid;
    const float* wg = w + (size_t)oc * 144;
    float acc = 0.f;
    for (int ic = 0; ic < 16; ++ic) {
        const float* base = fo + (((size_t)(b*16 + ic)) << 16);
        #pragma unroll
        for (int ky = 0; ky < 3; ++ky) {
            int yy = y + ky - 1; if (yy < 0 || yy > 255) continue;
            const float* rowp = base + (yy<<8);
            float v0 = (x > 0)   ? rowp[x-1] : 0.f;
            float v1 = rowp[x];
            float v2 = (x < 255) ? rowp[x+1] : 0.f;
            const float* wr = wg + ic*9 + ky*3;
            acc = fmaf(wr[0], v0, fmaf(wr[1], v1, fmaf(wr[2], v2, acc)));
        }
    }
    size_t oidx = (((size_t)(b*4 + oc)) << 16) + (y<<8) + x;
    out[oidx] = acc + lrms_up[oidx];
}

// ================================================================================
extern "C" void kernel_launch(void* const* d_in, const int* in_sizes, int n_in,
                              void* d_out, int out_size, void* d_ws, size_t ws_size,
                              hipStream_t stream) {
    const float* lrms     = (const float*)d_in[0];
    const float* pan      = (const float*)d_in[1];
    const float* w_convps = (const float*)d_in[2];
    const float* hor_w1   = (const float*)d_in[3];
    const float* hor_w2   = (const float*)d_in[4];
    const float* ffc_l2l  = (const float*)d_in[5];
    const float* ffc_l2g  = (const float*)d_in[6];
    const float* ffc_g2l  = (const float*)d_in[7];
    const float* ffc_spec = (const float*)d_in[8];
    const float* ref_in   = (const float*)d_in[9];
    const float* ref_b1   = (const float*)d_in[10];
    const float* ref_b2   = (const float*)d_in[11];
    const float* ref_ca1  = (const float*)d_in[12];
    const float* ref_ca2  = (const float*)d_in[13];
    const float* ref_out  = (const float*)d_in[14];
    const float* w_fuse   = (const float*)d_in[15];
    const float* w_liif   = (const float*)d_in[16];
    const float* w_hp     = (const float*)d_in[17];
    const float* mw_in    = (const float*)d_in[18];
    const float* mb_in    = (const float*)d_in[19];
    const float* mw_h     = (const float*)d_in[20];
    const float* mb_h     = (const float*)d_in[21];
    const float* mw_out   = (const float*)d_in[22];
    const float* mb_out   = (const float*)d_in[23];
    float* out = (float*)d_out;

    const size_t PLANE = 65536;
    char* base = (char*)d_ws;
    size_t off = 0;
    auto alloc = [&](size_t bytes){ void* p = base + off; off += (bytes + 255) & ~(size_t)255; return p; };
    float* lrms_up  = (float*)alloc(16*PLANE*4);
    bf16*  feat2    = (bf16*) alloc(24*PLANE*2);
    bf16*  bA       = (bf16*) alloc(192*PLANE*2);
    bf16*  bB       = (bf16*) alloc(192*PLANE*2);
    bf16*  bC       = (bf16*) alloc(192*PLANE*2);
    bf16*  bF       = (bf16*) alloc(192*PLANE*2);
    bf16*  fusedCat = (bf16*) alloc(192*PLANE*2);
    bf16*  feat_all = (bf16*) alloc(64*PLANE*2);
    float* fo       = (float*)alloc(64*PLANE*4);
    const size_t FFTB = (size_t)3*4*8*256*129;
    bf16* re0 = (bf16*)alloc(FFTB*2); bf16* im0 = (bf16*)alloc(FFTB*2);
    bf16* re1 = (bf16*)alloc(FFTB*2); bf16* im1 = (bf16*)alloc(FFTB*2);
    short* wpack = (short*)alloc(241664*2);
    float* ffcw  = (float*)alloc(13824*4);
    short* wconv = (short*)alloc(45*2560*2);
    float* means = (float*)alloc(192*4);
    float* cav   = (float*)alloc(192*4);
    if (off > ws_size) return;

    hipMemsetAsync(means, 0, 192*4, stream);
    repack_k<<<dim3(944), dim3(256), 0, stream>>>(mw_in, mw_h, mw_out, wpack);
    pack_ffcw_k<<<dim3(54), dim3(256), 0, stream>>>(ffc_l2l, ffc_l2g, ffc_g2l, ffcw);
    pack_convw_k<<<dim3(450), dim3(256), 0, stream>>>(hor_w2, ref_in, ref_b1, ref_b2, ffcw, ref_out, wconv);
    conv_ps_k<<<dim3(4096), dim3(256), 0, stream>>>(lrms, w_convps, lrms_up);

    GK3 g3;
    {
        const int kss[3] = {5, 27, 41};
        const double sgs[3] = {1.5, 2.0, 2.8};
        for (int br = 0; br < 3; ++br) {
            g3.ks[br] = kss[br];
            double tmp[41]; double s = 0.0; double c = (kss[br]-1)/2.0;
            for (int i = 0; i < kss[br]; ++i) { double d = i - c; tmp[i] = exp(-(d*d)/(2.0*sgs[br]*sgs[br])); s += tmp[i]; }
            for (int i = 0; i < 41; ++i) g3.k[br][i] = (i < kss[br]) ? (float)(tmp[i]/s) : 0.f;
        }
    }
    gauss_hp_k<<<dim3(6144), dim3(256), 0, stream>>>(pan, lrms_up, feat2, g3);

    // hornet
    convA_k<<<dim3(3072), dim3(256), 0, stream>>>(feat2, 2, 2, hor_w1, 720, 45, bA, ACT_GELU);
    convM_k<<<dim3(768), dim3(256), 0, stream>>>(bA, wconv + 0*3*2560, bB, ACT_NONE, nullptr);

    for (int step = 0; step < 3; ++step) {
        bf16* Xin = (step == 0) ? bB : bA;
        bf16* Yb  = (step == 0) ? bA : bB;
        bf16* Db  = (step == 0) ? bB : bA;
        convM_k<<<dim3(768), dim3(256), 0, stream>>>(Xin, wconv + (1+step)*3*2560, Yb, ACT_NONE, nullptr);
        convM_k<<<dim3(768), dim3(256), 0, stream>>>(Yb,  wconv + (4+step)*3*2560, bC, ACT_RELU, nullptr);
        convM_k<<<dim3(768), dim3(256), 0, stream>>>(bC,  wconv + (7+step)*3*2560, Db, ACT_NONE, means);
        ca_k<<<dim3(1), dim3(192), 0, stream>>>(means, ref_ca1, ref_ca2, step, cav);
        convOutM_k<<<dim3(768), dim3(256), 0, stream>>>(Yb, Db, cav, wconv + (12+step)*3*2560, w_fuse, step, bF, fusedCat);
        if (step < 2) {
            convM_k<<<dim3(768), dim3(256), 0, stream>>>(bF, wconv + (10+step)*3*2560, bA, ACT_NONE, nullptr);
            rfft_w_k<<<dim3(24576), dim3(256), 0, stream>>>(bF, re0, im0);
            fftspec_h_k<<<dim3(1548), dim3(256), 0, stream>>>(re0, im0, ffc_spec, step, re1, im1);
            irfft_w_k<<<dim3(24576), dim3(256), 0, stream>>>(re1, im1, bA);
        }
    }

    fuse1x1_k<<<dim3(1024), dim3(256), 0, stream>>>(fusedCat, w_liif, feat_all);
    mlp_mfma_k<<<dim3(2048), dim3(512), 128*264*2, stream>>>((const short*)feat_all, wpack, mb_in, mb_h, mb_out, fo);
    mlp_edge_mfma_k<<<dim3(48), dim3(256), 128*264*2, stream>>>((const short*)feat_all, wpack, mb_in, mb_h, mb_out, fo);
    final_k<<<dim3(4096), dim3(256), 0, stream>>>(fo, w_hp, lrms_up, out);
}

// Round 9
// 1206.327 us; speedup vs baseline: 11.0760x; 1.2922x over previous
//
#include <hip/hip_runtime.h>
#include <hip/hip_bf16.h>
#include <math.h>

typedef __hip_bfloat16 bf16;
typedef __attribute__((ext_vector_type(8))) short short8;
typedef __attribute__((ext_vector_type(4))) short short4v;
typedef __attribute__((ext_vector_type(4))) float float4v;

#define ACT_NONE 0
#define ACT_RELU 1
#define ACT_GELU 2

__device__ __forceinline__ float b2f(bf16 v){ return __bfloat162float(v); }
__device__ __forceinline__ bf16  f2b(float f){ return __float2bfloat16(f); }
__device__ __forceinline__ short f2bs(float f){ bf16 h = __float2bfloat16(f); return *reinterpret_cast<short*>(&h); }
__device__ __forceinline__ float bs2f(short s){ return __uint_as_float(((unsigned)(unsigned short)s) << 16); }
__device__ __forceinline__ void rotc(float& tr, float& ti, float cr, float ci){
    float t = tr*cr - ti*ci; ti = tr*ci + ti*cr; tr = t;
}
// swizzled LDS index for mlp activations: row stride 256 shorts, 16B-chunk XOR
__device__ __forceinline__ int swz(int row, int col){ return row*256 + (col ^ ((row & 7) << 3)); }

struct GK3 { float k[3][41]; int ks[3]; };

// ---------------- pixel-shuffle conv ------------------------------------------
__global__ __launch_bounds__(256) void conv_ps_k(const float* __restrict__ lrms,
                                                 const float* __restrict__ w,
                                                 float* __restrict__ up){
    int tid = threadIdx.x, bx = blockIdx.x;
    int y = bx & 255, c = (bx >> 8) & 3, b = bx >> 10;
    int x = tid;
    int h = y >> 2, r1 = y & 3, ww = x >> 2, r2 = x & 3;
    int oc = c*16 + r1*4 + r2;
    float acc = 0.f;
    for (int ic = 0; ic < 4; ++ic) {
        const float* base = lrms + ((b*4 + ic) << 12);
        const float* wb = w + (oc*4 + ic)*9;
        #pragma unroll
        for (int ky = 0; ky < 3; ++ky) {
            int hh = h + ky - 1; if (hh < 0 || hh > 63) continue;
            #pragma unroll
            for (int kx = 0; kx < 3; ++kx) {
                int cc = ww + kx - 1; if (cc < 0 || cc > 63) continue;
                acc += base[(hh<<6) + cc] * wb[ky*3 + kx];
            }
        }
    }
    up[(((size_t)(b*4 + c)) << 16) + (y<<8) + x] = acc;
}

// ---------------- fused gaussian highpass -------------------------------------
__global__ __launch_bounds__(256) void gauss_hp_k(const float* __restrict__ pan,
                                                  const float* __restrict__ lrms_up,
                                                  bf16* __restrict__ feat2, GK3 g){
    int tid = threadIdx.x, bx = blockIdx.x;
    int y = bx & 255, b = (bx >> 8) & 3, src = (bx >> 10) & 1, br = bx >> 11;
    int ks = g.ks[br], p = ks >> 1;
    const float* gk = g.k[br];
    const float* s = src ? (lrms_up + (size_t)b*4*65536) : (pan + (size_t)b*65536);
    __shared__ float vext[296];
    for (int i = tid; i < 296; i += 256) {
        int xe = i - 20; int xr = xe < 0 ? -xe : (xe > 255 ? 510 - xe : xe);
        float acc = 0.f;
        for (int t = 0; t < ks; ++t) {
            int yy = y - p + t; yy = yy < 0 ? -yy : (yy > 255 ? 510 - yy : yy);
            acc += gk[t] * s[(yy<<8) + xr];
        }
        vext[i] = acc;
    }
    __syncthreads();
    int x = tid;
    float acc = 0.f;
    for (int t = 0; t < ks; ++t) acc += gk[t] * vext[x - p + t + 20];
    float o = s[(y<<8) + x];
    feat2[(((size_t)((br*4 + b)*2 + src)) << 16) + (y<<8) + x] = f2b(o - acc);
}

// ---------------- scalar 3x3 conv (hornet conv1, Cin=2) -------------------------
__global__ __launch_bounds__(256) void convA_k(const bf16* __restrict__ in, int inCper, int Cin,
                                               const float* __restrict__ wbase, int wbrstride, int wocstride,
                                               bf16* __restrict__ out, int act){
    int tid = threadIdx.x, bx = blockIdx.x;
    int y = bx & 255, b = (bx >> 8) & 3, br = bx >> 10;
    const float* w = wbase + (size_t)br * wbrstride;
    int x = tid;
    float acc[16];
    #pragma unroll
    for (int oc = 0; oc < 16; ++oc) acc[oc] = 0.f;
    for (int ic = 0; ic < Cin; ++ic) {
        const bf16* base = in + ((size_t)((br*4 + b)*inCper + ic) << 16);
        const float* wic = w + ic*9;
        #pragma unroll
        for (int ky = 0; ky < 3; ++ky) {
            int yy = y + ky - 1; if (yy < 0 || yy > 255) continue;
            const bf16* rowp = base + (yy<<8);
            float v0 = (x > 0)   ? b2f(rowp[x-1]) : 0.f;
            float v1 = b2f(rowp[x]);
            float v2 = (x < 255) ? b2f(rowp[x+1]) : 0.f;
            const float* wr = wic + ky*3;
            #pragma unroll
            for (int oc = 0; oc < 16; ++oc) {
                const float* wo = wr + oc*wocstride;
                acc[oc] = fmaf(wo[0], v0, fmaf(wo[1], v1, fmaf(wo[2], v2, acc[oc])));
            }
        }
    }
    #pragma unroll
    for (int oc = 0; oc < 16; ++oc) {
        float a = acc[oc];
        if (act == ACT_RELU) a = fmaxf(a, 0.f);
        else if (act == ACT_GELU) {
            float u = 0.7978845608028654f * (a + 0.044715f*a*a*a);
            a = 0.5f * a * (1.f + tanhf(u));
        }
        out[((size_t)((br*4 + b)*16 + oc) << 16) + (y<<8) + x] = f2b(a);
    }
}

// ---------------- pack conv weights for MFMA: 45 sets = 15 groups x 3 br ---------
__global__ __launch_bounds__(256) void pack_convw_k(const float* __restrict__ hor_w2,
        const float* __restrict__ ref_in, const float* __restrict__ ref_b1,
        const float* __restrict__ ref_b2, const float* __restrict__ ffcw,
        const float* __restrict__ ref_out,
        short* __restrict__ wp){
    int idx = blockIdx.x*256 + threadIdx.x;
    if (idx >= 45*2560) return;
    int set = idx / 2560, r = idx % 2560;
    int j = r & 7, l = (r>>3) & 63, kt = r >> 9;
    int k = kt*32 + ((l>>4)&3)*8 + j;
    int n = l & 15;
    int g = set / 3, br = set % 3;
    float v = 0.f;
    if (k < 144) {
        int tap = k >> 4, ic = k & 15;
        int widx = (n*16 + ic)*9 + tap;
        const float* src;
        if (g == 0)       src = hor_w2 + br*2304;
        else if (g <= 3)  src = ref_in + (3*br + (g-1))*2304;
        else if (g <= 6)  src = ref_b1 + (3*br + (g-4))*2304;
        else if (g <= 9)  src = ref_b2 + (3*br + (g-7))*2304;
        else if (g <= 11) src = ffcw   + (2*br + (g-10))*2304;
        else              src = ref_out + (3*br + (g-12))*2304;
        v = src[widx];
    }
    wp[idx] = f2bs(v);
}

// ---------------- MFMA 3x3 conv, 4 output rows per block ------------------------
__global__ __launch_bounds__(256) void convM_k(const bf16* __restrict__ in,
        const short* __restrict__ wgroup,
        bf16* __restrict__ out, int act, float* __restrict__ means){
    __shared__ short sIn[6*258*20];
    __shared__ float sm[4][16];
    int tid = threadIdx.x, bx = blockIdx.x;
    int y0 = (bx & 63) << 2, b = (bx >> 6) & 3, br = bx >> 8;
    size_t pbase = (size_t)((br*4 + b)*16) << 16;
    if (tid < 192) {
        int r = tid >> 5, side = (tid >> 4) & 1, ic = tid & 15;
        sIn[(r*258 + (side ? 257 : 0))*20 + ic] = 0;
    }
    {
        int g = tid >> 5, tl = tid & 31, x0 = tl << 3, ic0 = g*2;
        for (int r = 0; r < 6; ++r) {
            int yy = y0 - 1 + r;
            short8 lo = {0,0,0,0,0,0,0,0}, hi = {0,0,0,0,0,0,0,0};
            if (yy >= 0 && yy <= 255) {
                lo = *(const short8*)&in[pbase + ((size_t)ic0<<16) + (yy<<8) + x0];
                hi = *(const short8*)&in[pbase + ((size_t)(ic0+1)<<16) + (yy<<8) + x0];
            }
            #pragma unroll
            for (int t = 0; t < 8; ++t) {
                int v = (int)(unsigned short)lo[t] | ((int)(unsigned short)hi[t] << 16);
                *(int*)&sIn[(r*258 + x0 + t + 1)*20 + ic0] = v;
            }
        }
    }
    __syncthreads();
    int l = tid & 63, w = tid >> 6, m_l = l & 15, q = l >> 4;
    const short* wp = wgroup + br*2560;
    short8 bfr[5];
    #pragma unroll
    for (int kt = 0; kt < 5; ++kt)
        bfr[kt] = *(const short8*)(wp + (kt*64 + l)*8);
    float4v acc[16];
    #pragma unroll
    for (int j = 0; j < 16; ++j) acc[j] = (float4v){0.f,0.f,0.f,0.f};
    #pragma unroll
    for (int kt = 0; kt < 5; ++kt) {
        int k0 = kt*32 + q*8;
        bool pad = (k0 >= 144);
        int tap = pad ? 0 : (k0 >> 4);
        int icb = k0 & 15;
        int ky = tap/3, kx = tap - ky*3;
        int rbase = (w + ky)*258 + kx;
        #pragma unroll
        for (int j = 0; j < 16; ++j) {
            int x = j*16 + m_l;
            const short* ap = &sIn[(rbase + x)*20 + icb];
            short4v alo = *(const short4v*)ap;
            short4v ahi = *(const short4v*)(ap + 4);
            short8 a;
            #pragma unroll
            for (int t = 0; t < 4; ++t) { a[t] = pad ? (short)0 : alo[t]; a[t+4] = pad ? (short)0 : ahi[t]; }
            acc[j] = __builtin_amdgcn_mfma_f32_16x16x32_bf16(a, bfr[kt], acc[j], 0, 0, 0);
        }
    }
    if (means) {
        float s = 0.f;
        #pragma unroll
        for (int j = 0; j < 16; ++j)
            #pragma unroll
            for (int r = 0; r < 4; ++r) s += acc[j][r];
        s += __shfl_xor(s, 16, 64);
        s += __shfl_xor(s, 32, 64);
        if (l < 16) sm[w][l] = s;
        __syncthreads();
        if (tid < 16) atomicAdd(&means[br*64 + b*16 + tid],
                                sm[0][tid] + sm[1][tid] + sm[2][tid] + sm[3][tid]);
    }
    int yrow = y0 + w;
    #pragma unroll
    for (int j = 0; j < 16; ++j) {
        short4v pk;
        #pragma unroll
        for (int r = 0; r < 4; ++r) {
            float a = acc[j][r];
            if (act == ACT_RELU) a = fmaxf(a, 0.f);
            else if (act == ACT_GELU) {
                float u = 0.7978845608028654f * (a + 0.044715f*a*a*a);
                a = 0.5f * a * (1.f + tanhf(u));
            }
            pk[r] = f2bs(a);
        }
        *(short4v*)&out[pbase + ((size_t)m_l << 16) + (yrow<<8) + j*16 + q*4] = pk;
    }
}

// ---------------- MFMA refine-out conv: in = Y + ca*BDY, + fuse 1x1 epilogue ----
__global__ __launch_bounds__(256) void convOutM_k(const bf16* __restrict__ Y, const bf16* __restrict__ BDY,
        const float* __restrict__ cav, const short* __restrict__ wgroup,
        const float* __restrict__ wfuse, int step,
        bf16* __restrict__ F, bf16* __restrict__ fusedCat){
    __shared__ short sIn[6*258*20];
    int tid = threadIdx.x, bx = blockIdx.x;
    int y0 = (bx & 63) << 2, b = (bx >> 6) & 3, br = bx >> 8;
    size_t pbase = (size_t)((br*4 + b)*16) << 16;
    if (tid < 192) {
        int r = tid >> 5, side = (tid >> 4) & 1, ic = tid & 15;
        sIn[(r*258 + (side ? 257 : 0))*20 + ic] = 0;
    }
    {
        int g = tid >> 5, tl = tid & 31, x0 = tl << 3, ic0 = g*2;
        float c0 = cav[br*64 + b*16 + ic0];
        float c1 = cav[br*64 + b*16 + ic0 + 1];
        for (int r = 0; r < 6; ++r) {
            int yy = y0 - 1 + r;
            short8 ylo = {0,0,0,0,0,0,0,0}, yhi = ylo, dlo = ylo, dhi = ylo;
            if (yy >= 0 && yy <= 255) {
                size_t o0 = pbase + ((size_t)ic0<<16) + (yy<<8) + x0;
                size_t o1 = pbase + ((size_t)(ic0+1)<<16) + (yy<<8) + x0;
                ylo = *(const short8*)&Y[o0];   yhi = *(const short8*)&Y[o1];
                dlo = *(const short8*)&BDY[o0]; dhi = *(const short8*)&BDY[o1];
            }
            #pragma unroll
            for (int t = 0; t < 8; ++t) {
                short s0 = f2bs(fmaf(bs2f(dlo[t]), c0, bs2f(ylo[t])));
                short s1 = f2bs(fmaf(bs2f(dhi[t]), c1, bs2f(yhi[t])));
                int v = (int)(unsigned short)s0 | ((int)(unsigned short)s1 << 16);
                *(int*)&sIn[(r*258 + x0 + t + 1)*20 + ic0] = v;
            }
        }
    }
    __syncthreads();
    int l = tid & 63, w = tid >> 6, m_l = l & 15, q = l >> 4;
    const short* wp = wgroup + br*2560;
    short8 bfr[5];
    #pragma unroll
    for (int kt = 0; kt < 5; ++kt)
        bfr[kt] = *(const short8*)(wp + (kt*64 + l)*8);
    float4v acc[16];
    #pragma unroll
    for (int j = 0; j < 16; ++j) acc[j] = (float4v){0.f,0.f,0.f,0.f};
    #pragma unroll
    for (int kt = 0; kt < 5; ++kt) {
        int k0 = kt*32 + q*8;
        bool pad = (k0 >= 144);
        int tap = pad ? 0 : (k0 >> 4);
        int icb = k0 & 15;
        int ky = tap/3, kx = tap - ky*3;
        int rbase = (w + ky)*258 + kx;
        #pragma unroll
        for (int j = 0; j < 16; ++j) {
            int x = j*16 + m_l;
            const short* ap = &sIn[(rbase + x)*20 + icb];
            short4v alo = *(const short4v*)ap;
            short4v ahi = *(const short4v*)(ap + 4);
            short8 a;
            #pragma unroll
            for (int t = 0; t < 4; ++t) { a[t] = pad ? (short)0 : alo[t]; a[t+4] = pad ? (short)0 : ahi[t]; }
            acc[j] = __builtin_amdgcn_mfma_f32_16x16x32_bf16(a, bfr[kt], acc[j], 0, 0, 0);
        }
    }
    int yrow = y0 + w;
    #pragma unroll
    for (int j = 0; j < 16; ++j) {
        short4v pk;
        #pragma unroll
        for (int r = 0; r < 4; ++r) pk[r] = f2bs(acc[j][r]);
        *(short4v*)&F[pbase + ((size_t)m_l << 16) + (yrow<<8) + j*16 + q*4] = pk;
    }
    __syncthreads();            // everyone done reading sIn; reuse as sF
    short* sF = sIn + w*4096;   // per-wave 256px x 16oc
    #pragma unroll
    for (int j = 0; j < 16; ++j)
        #pragma unroll
        for (int r = 0; r < 4; ++r)
            sF[(j*16 + q*4 + r)*16 + m_l] = f2bs(acc[j][r]);
    const float* wf = wfuse + br*768 + step*16;   // wf[oc2*48 + oc]
    short8 b2;
    #pragma unroll
    for (int jj = 0; jj < 8; ++jj) {
        int k = q*8 + jj;
        b2[jj] = (k < 16) ? f2bs(wf[m_l*48 + k]) : (short)0;
    }
    #pragma unroll
    for (int mt = 0; mt < 16; ++mt) {
        short8 a2 = {0,0,0,0,0,0,0,0};
        if (q < 2) a2 = *(const short8*)&sF[(mt*16 + m_l)*16 + q*8];
        float4v d2 = (float4v){0.f,0.f,0.f,0.f};
        d2 = __builtin_amdgcn_mfma_f32_16x16x32_bf16(a2, b2, d2, 0, 0, 0);
        size_t fidx = ((size_t)(b*48 + br*16 + m_l) << 16) + (yrow<<8) + mt*16 + q*4;
        short4v pk;
        if (step == 0) {
            #pragma unroll
            for (int r = 0; r < 4; ++r) pk[r] = f2bs(d2[r]);
        } else {
            short4v old = *(const short4v*)&fusedCat[fidx];
            #pragma unroll
            for (int r = 0; r < 4; ++r) pk[r] = f2bs(bs2f(old[r]) + d2[r]);
        }
        *(short4v*)&fusedCat[fidx] = pk;
    }
}

// ---------------- channel attention; rezeros means -------------------------------
__global__ void ca_k(float* __restrict__ means, const float* __restrict__ ca1,
                     const float* __restrict__ ca2, int step, float* __restrict__ cav){
    int t = threadIdx.x;  // 192
    int br = t >> 6, rem = t & 63, b = rem >> 4, oc = rem & 15;
    int ri = 3*br + step;
    const float* w1 = ca1 + ri*64; const float* w2 = ca2 + ri*64;
    float hid[4];
    #pragma unroll
    for (int c2 = 0; c2 < 4; ++c2) {
        float a = 0.f;
        for (int c = 0; c < 16; ++c) a += w1[c2*16 + c] * (means[br*64 + b*16 + c] * (1.f/65536.f));
        hid[c2] = fmaxf(a, 0.f);
    }
    float v = 0.f;
    #pragma unroll
    for (int c2 = 0; c2 < 4; ++c2) v += w2[oc*4 + c2] * hid[c2];
    cav[t] = 1.f / (1.f + expf(-v));
    __syncthreads();
    means[t] = 0.f;
}

// ---------------- radix-16 rfft along W, output TRANSPOSED [k][y] ----------------
// block: 16 rows of one (br,b,c). out index: ((bc8+c)*129 + k)*256 + y
__global__ __launch_bounds__(256) void rfft_wT_k(const bf16* __restrict__ F,
                                                 bf16* __restrict__ ore, bf16* __restrict__ oim){
    __shared__ float rows[16][256];
    __shared__ float Ar[256], Ai[256];
    __shared__ float Tr[129][17], Ti[129][17];
    int tid = threadIdx.x, bx = blockIdx.x;
    int t = bx & 15, c = (bx >> 4) & 7, b = (bx >> 7) & 3, br = bx >> 9;
    int y0 = t << 4;
    size_t plane = (size_t)((br*4 + b)*16 + 8 + c) << 16;
    #pragma unroll
    for (int r = 0; r < 16; ++r)
        rows[r][tid] = b2f(F[plane + ((size_t)(y0 + r) << 8) + tid]);
    __syncthreads();
    int n1 = tid >> 4, k1 = tid & 15;
    float a1 = -6.283185307179586f * (float)k1 / 16.f;
    float c1, s1; __sincosf(a1, &s1, &c1);
    float a2 = -6.283185307179586f * (float)tid / 256.f;
    float c2v, s2v; __sincosf(a2, &s2v, &c2v);
    for (int r = 0; r < 16; ++r) {
        float twr = 1.f, twi = 0.f, ar = 0.f, ai = 0.f;
        #pragma unroll
        for (int n2 = 0; n2 < 16; ++n2) {
            float xr = rows[r][n1 + (n2<<4)];
            ar = fmaf(xr, twr, ar); ai = fmaf(xr, twi, ai);
            rotc(twr, twi, c1, s1);
        }
        Ar[tid] = ar; Ai[tid] = ai;
        __syncthreads();
        float t2r = 1.f, t2i = 0.f, re = 0.f, im = 0.f;
        #pragma unroll
        for (int m = 0; m < 16; ++m) {
            float rr = Ar[(m<<4) + k1], ii = Ai[(m<<4) + k1];
            re += rr*t2r - ii*t2i; im += ii*t2r + rr*t2i;
            rotc(t2r, t2i, c2v, s2v);
        }
        if (tid < 129) { Tr[tid][r] = re * 0.0625f; Ti[tid][r] = im * 0.0625f; }
        __syncthreads();
    }
    size_t obase = ((size_t)(((br*4 + b)*8 + c)*129)) * 256 + y0;
    for (int idx = tid; idx < 129*16; idx += 256) {
        int k = idx >> 4, ty = idx & 15;
        ore[obase + (size_t)k*256 + ty] = f2b(Tr[k][ty]);
        oim[obase + (size_t)k*256 + ty] = f2b(Ti[k][ty]);
    }
}

// ---------------- FUSED: fft_h fwd -> spec -> fft_h inv, on [k][y] layout --------
__global__ __launch_bounds__(256) void fftspec_hT_k(const bf16* __restrict__ re0, const bf16* __restrict__ im0,
                                                    const float* __restrict__ wspec, int step,
                                                    bf16* __restrict__ re1, bf16* __restrict__ im1){
    __shared__ float Fr[8][256], Fi[8][256], Sr[8][256], Si[8][256], Ar[256], Ai[256];
    int tid = threadIdx.x, bx = blockIdx.x;
    int k = bx % 129; int r2 = bx / 129; int b = r2 & 3, br = r2 >> 2;
    size_t cb = (size_t)((br*4 + b)*8) * 33024 + (size_t)k * 256;   // + c*33024 + y
    int n1 = tid >> 4, k1 = tid & 15;
    float a1 = -6.283185307179586f * (float)k1 / 16.f;
    float c1, s1; __sincosf(a1, &s1, &c1);
    float a2 = -6.283185307179586f * (float)tid / 256.f;
    float c2v, s2v; __sincosf(a2, &s2v, &c2v);
    #pragma unroll
    for (int c = 0; c < 8; ++c) {
        size_t base = cb + (size_t)c*33024 + tid;
        Fr[c][tid] = b2f(re0[base]);
        Fi[c][tid] = b2f(im0[base]);
    }
    __syncthreads();
    for (int c = 0; c < 8; ++c) {
        float twr = 1.f, twi = 0.f, ar = 0.f, ai = 0.f;
        #pragma unroll
        for (int n2 = 0; n2 < 16; ++n2) {
            float r = Fr[c][n1 + (n2<<4)], i = Fi[c][n1 + (n2<<4)];
            ar += r*twr - i*twi; ai += i*twr + r*twi;
            rotc(twr, twi, c1, s1);
        }
        Ar[tid] = ar; Ai[tid] = ai;
        __syncthreads();
        float t2r = 1.f, t2i = 0.f, rr = 0.f, ii = 0.f;
        #pragma unroll
        for (int m = 0; m < 16; ++m) {
            float r = Ar[(m<<4) + k1], i = Ai[(m<<4) + k1];
            rr += r*t2r - i*t2i; ii += i*t2r + r*t2i;
            rotc(t2r, t2i, c2v, s2v);
        }
        Sr[c][tid] = rr * 0.0625f; Si[c][tid] = ii * 0.0625f;
        __syncthreads();
    }
    {
        const float* wl = wspec + (2*br + step)*256;
        float outv[16];
        #pragma unroll
        for (int oc = 0; oc < 16; ++oc) {
            float acc = 0.f;
            #pragma unroll
            for (int ic = 0; ic < 8; ++ic)
                acc += Sr[ic][tid] * wl[oc*16 + ic] + Si[ic][tid] * wl[oc*16 + 8 + ic];
            outv[oc] = fmaxf(acc, 0.f);
        }
        __syncthreads();
        #pragma unroll
        for (int oc = 0; oc < 8; ++oc) { Fr[oc][tid] = outv[oc]; Fi[oc][tid] = outv[oc+8]; }
        __syncthreads();
    }
    for (int c = 0; c < 8; ++c) {
        float twr = 1.f, twi = 0.f, ar = 0.f, ai = 0.f;
        #pragma unroll
        for (int n2 = 0; n2 < 16; ++n2) {
            float r = Fr[c][n1 + (n2<<4)], i = Fi[c][n1 + (n2<<4)];
            ar += r*twr + i*twi;
            ai += i*twr - r*twi;
            rotc(twr, twi, c1, s1);
        }
        Ar[tid] = ar; Ai[tid] = ai;
        __syncthreads();
        float t2r = 1.f, t2i = 0.f, rr = 0.f, ii = 0.f;
        #pragma unroll
        for (int m = 0; m < 16; ++m) {
            float r = Ar[(m<<4) + k1], i = Ai[(m<<4) + k1];
            rr += r*t2r + i*t2i;
            ii += i*t2r - r*t2i;
            rotc(t2r, t2i, c2v, s2v);
        }
        size_t base = cb + (size_t)c*33024 + tid;
        re1[base] = f2b(rr * 0.0625f);
        im1[base] = f2b(ii * 0.0625f);
        __syncthreads();
    }
}

// ---------------- c2r irfft along W from [k][y] layout, += into A ch0..7 ---------
__global__ __launch_bounds__(256) void irfft_wT_k(const bf16* __restrict__ re1, const bf16* __restrict__ im1,
                                                  bf16* __restrict__ A){
    __shared__ float Cr[129][17], Ci[129][17];
    __shared__ float er[256], ei[256];
    __shared__ float Ar[256], Ai[256];
    int tid = threadIdx.x, bx = blockIdx.x;
    int t = bx & 15, c = (bx >> 4) & 7, b = (bx >> 7) & 3, br = bx >> 9;
    int y0 = t << 4;
    size_t ibase = ((size_t)(((br*4 + b)*8 + c)*129)) * 256 + y0;
    for (int idx = tid; idx < 129*16; idx += 256) {
        int k = idx >> 4, ty = idx & 15;
        Cr[k][ty] = b2f(re1[ibase + (size_t)k*256 + ty]);
        Ci[k][ty] = (k == 0 || k == 128) ? 0.f : b2f(im1[ibase + (size_t)k*256 + ty]);
    }
    __syncthreads();
    int n1 = tid >> 4, k1 = tid & 15;
    float a1 = 6.283185307179586f * (float)k1 / 16.f;
    float c1, s1; __sincosf(a1, &s1, &c1);
    float a2 = 6.283185307179586f * (float)tid / 256.f;
    float c2v, s2v; __sincosf(a2, &s2v, &c2v);
    size_t plane = (size_t)((br*4 + b)*16 + c) << 16;
    for (int ty = 0; ty < 16; ++ty) {
        if (tid < 129) { er[tid] = Cr[tid][ty]; ei[tid] = Ci[tid][ty]; }
        else           { er[tid] = Cr[256 - tid][ty]; ei[tid] = -Ci[256 - tid][ty]; }
        __syncthreads();
        float twr = 1.f, twi = 0.f, ar = 0.f, ai = 0.f;
        #pragma unroll
        for (int n2 = 0; n2 < 16; ++n2) {
            float r = er[n1 + (n2<<4)], i = ei[n1 + (n2<<4)];
            ar += r*twr - i*twi; ai += i*twr + r*twi;
            rotc(twr, twi, c1, s1);
        }
        Ar[tid] = ar; Ai[tid] = ai;
        __syncthreads();
        float t2r = 1.f, t2i = 0.f, racc = 0.f;
        #pragma unroll
        for (int m = 0; m < 16; ++m) {
            float r = Ar[(m<<4) + k1], i = Ai[(m<<4) + k1];
            racc += r*t2r - i*t2i;
            rotc(t2r, t2i, c2v, s2v);
        }
        size_t o = plane + ((size_t)(y0 + ty) << 8) + tid;
        A[o] = f2b(b2f(A[o]) + racc * 0.0625f);
        __syncthreads();
    }
}

// ---------------- pack combined ffc conv weights ---------------------------------
__global__ __launch_bounds__(256) void pack_ffcw_k(const float* __restrict__ l2l, const float* __restrict__ l2g,
                                                   const float* __restrict__ g2l, float* __restrict__ wout){
    int idx = blockIdx.x*256 + threadIdx.x;
    if (idx >= 6*2304) return;
    int t = idx % 9; int ic = (idx/9) % 16; int oc = (idx/144) % 16; int wi = idx/2304;
    float v;
    if (oc < 8) v = (ic < 8) ? l2g[((wi*8 + oc)*8 + ic)*9 + t] : 0.f;
    else {
        int o = oc - 8;
        v = (ic < 8) ? l2l[((wi*8 + o)*8 + ic)*9 + t] : g2l[((wi*8 + o)*8 + (ic-8))*9 + t];
    }
    wout[idx] = v;
}

// ---------------- fuse 1x1 (48->16) ---------------------------------------------
__global__ __launch_bounds__(256) void fuse1x1_k(const bf16* __restrict__ fc, const float* __restrict__ wl,
                                                 bf16* __restrict__ feat_all){
    int tid = threadIdx.x, bx = blockIdx.x;
    int pt = bx & 255, b = bx >> 8;
    int p = (pt << 8) + tid;
    float acc[16];
    #pragma unroll
    for (int oc = 0; oc < 16; ++oc) acc[oc] = 0.f;
    for (int ic = 0; ic < 48; ++ic) {
        float v = b2f(fc[((size_t)(b*48 + ic) << 16) + p]);
        #pragma unroll
        for (int oc = 0; oc < 16; ++oc) acc[oc] = fmaf(wl[oc*48 + ic], v, acc[oc]);
    }
    #pragma unroll
    for (int oc = 0; oc < 16; ++oc)
        feat_all[((size_t)(b*16 + oc) << 16) + p] = f2b(acc[oc]);
}

// ---------------- MLP weight repack ---------------------------------------------
__global__ __launch_bounds__(256) void repack_k(const float* __restrict__ mw_in,
                                                const float* __restrict__ mw_h,
                                                const float* __restrict__ mw_out,
                                                short* __restrict__ wp){
    int idx = blockIdx.x*256 + threadIdx.x;
    const int S0 = 40960;
    const int SH = 65536;
    const int TOT = S0 + 3*SH + 4096;
    if (idx >= TOT) return;
    float val;
    if (idx < S0) {
        int j = idx & 7, l = (idx>>3) & 63, nt = (idx>>9) & 15, kt = idx >> 13;
        int k = kt*32 + (l>>4)*8 + j;
        int n = nt*16 + (l&15);
        val = (k < 148) ? mw_in[k*256 + n] : 0.f;
    } else if (idx < S0 + 3*SH) {
        int i2 = idx - S0;
        int L = i2 >> 16, r = i2 & 65535;
        int j = r & 7, l = (r>>3) & 63, nt = (r>>9) & 15, kt = r >> 13;
        int k = kt*32 + (l>>4)*8 + j;
        int n = nt*16 + (l&15);
        val = mw_h[L*65536 + k*256 + n];
    } else {
        int i3 = idx - S0 - 3*SH;
        int j = i3 & 7, l = (i3>>3) & 63, kt = i3 >> 9;
        int k = kt*32 + (l>>4)*8 + j;
        int oc = l & 15;
        val = mw_out[k*16 + oc];
    }
    wp[idx] = f2bs(val);
}

// ---------------- LIIF MLP via MFMA (center), 512 thr, 64KB swizzled LDS ---------
__global__ __launch_bounds__(512) void mlp_mfma_k(const short* __restrict__ feat,
        const short* __restrict__ wp,
        const float* __restrict__ b_in, const float* __restrict__ b_h,
        const float* __restrict__ b_out,
        float* __restrict__ fo){
    extern __shared__ short act_s[];   // 128 rows x 256 shorts, XOR-swizzled = 65536 B
    int tid = threadIdx.x, bx = blockIdx.x;
    long P0 = (long)bx * 128;
    for (int idx = tid; idx < 128*160; idx += 512) {
        int pp = idx / 160, j = idx - pp*160;
        long P = P0 + pp;
        int bb = (int)(P >> 16), pim = (int)(P & 65535);
        int s0 = pim >> 8, s1 = pim & 255;
        short v = 0;
        if (j < 144) {
            int iy = j/48, ix = (j>>4)%3, c2 = j&15;
            int yy = s0 + iy - 1, xx = s1 + ix - 1;
            if (yy >= 0 && yy < 256 && xx >= 0 && xx < 256)
                v = feat[(((long)(bb*16 + c2)) << 16) + (yy<<8) + xx];
        } else if (j == 146 || j == 147) v = 0x4000;
        act_s[swz(pp, j)] = v;
    }
    __syncthreads();

    int l = tid & 63, w = tid >> 6;
    int m_l = l & 15, q = l >> 4;
    int mh = w >> 2, nq = w & 3;
    int mtb = mh*4, ntb = nq*4;
    const short* wph  = wp + 40960;
    const short* wpo  = wp + 40960 + 3*65536;

    float4v acc[4][4];
    // ---- layer 0 (K=160, 5 kt) ----
    #pragma unroll
    for (int mt = 0; mt < 4; ++mt)
        #pragma unroll
        for (int nt = 0; nt < 4; ++nt) acc[mt][nt] = (float4v){0.f,0.f,0.f,0.f};
    for (int kt = 0; kt < 5; ++kt) {
        const short* bp = wp + ((size_t)(kt*16 + ntb)*64 + l)*8;
        short8 bfr[4];
        #pragma unroll
        for (int nt = 0; nt < 4; ++nt) bfr[nt] = *(const short8*)(bp + (size_t)nt*64*8);
        #pragma unroll
        for (int mt = 0; mt < 4; ++mt) {
            short8 a = *(const short8*)&act_s[swz((mtb+mt)*16 + m_l, kt*32 + q*8)];
            #pragma unroll
            for (int nt = 0; nt < 4; ++nt)
                acc[mt][nt] = __builtin_amdgcn_mfma_f32_16x16x32_bf16(a, bfr[nt], acc[mt][nt], 0, 0, 0);
        }
    }
    __syncthreads();
    #pragma unroll
    for (int nt = 0; nt < 4; ++nt) {
        int n = (ntb + nt)*16 + m_l;
        float bias = b_in[n];
        #pragma unroll
        for (int mt = 0; mt < 4; ++mt)
            #pragma unroll
            for (int r = 0; r < 4; ++r) {
                float vv = fmaxf(acc[mt][nt][r] + bias, 0.f);
                act_s[swz((mtb+mt)*16 + q*4 + r, n)] = f2bs(vv);
            }
    }
    __syncthreads();
    // ---- hidden layers (K=256, 8 kt) ----
    for (int L = 0; L < 3; ++L) {
        #pragma unroll
        for (int mt = 0; mt < 4; ++mt)
            #pragma unroll
            for (int nt = 0; nt < 4; ++nt) acc[mt][nt] = (float4v){0.f,0.f,0.f,0.f};
        const short* wl = wph + (size_t)L * 65536;
        for (int kt = 0; kt < 8; ++kt) {
            const short* bp = wl + ((size_t)(kt*16 + ntb)*64 + l)*8;
            short8 bfr[4];
            #pragma unroll
            for (int nt = 0; nt < 4; ++nt) bfr[nt] = *(const short8*)(bp + (size_t)nt*64*8);
            #pragma unroll
            for (int mt = 0; mt < 4; ++mt) {
                short8 a = *(const short8*)&act_s[swz((mtb+mt)*16 + m_l, kt*32 + q*8)];
                #pragma unroll
                for (int nt = 0; nt < 4; ++nt)
                    acc[mt][nt] = __builtin_amdgcn_mfma_f32_16x16x32_bf16(a, bfr[nt], acc[mt][nt], 0, 0, 0);
            }
        }
        __syncthreads();
        #pragma unroll
        for (int nt = 0; nt < 4; ++nt) {
            int n = (ntb + nt)*16 + m_l;
            float bias = b_h[L*256 + n];
            #pragma unroll
            for (int mt = 0; mt < 4; ++mt)
                #pragma unroll
                for (int r = 0; r < 4; ++r) {
                    float vv = fmaxf(acc[mt][nt][r] + bias, 0.f);
                    act_s[swz((mtb+mt)*16 + q*4 + r, n)] = f2bs(vv);
                }
        }
        __syncthreads();
    }
    // ---- output layer (N=16): waves with nq==0 handle their m-half ----
    if (nq == 0) {
        float4v o[4];
        #pragma unroll
        for (int mt = 0; mt < 4; ++mt) o[mt] = (float4v){0.f,0.f,0.f,0.f};
        for (int kt = 0; kt < 8; ++kt) {
            short8 bf = *(const short8*)(wpo + ((size_t)kt*64 + l)*8);
            #pragma unroll
            for (int mt = 0; mt < 4; ++mt) {
                short8 a = *(const short8*)&act_s[swz((mtb+mt)*16 + m_l, kt*32 + q*8)];
                o[mt] = __builtin_amdgcn_mfma_f32_16x16x32_bf16(a, bf, o[mt], 0, 0, 0);
            }
        }
        float bias = b_out[m_l];
        #pragma unroll
        for (int mt = 0; mt < 4; ++mt) {
            #pragma unroll
            for (int r = 0; r < 4; ++r) {
                long P = P0 + (mtb+mt)*16 + q*4 + r;
                int bb = (int)(P >> 16), pim = (int)(P & 65535);
                int s0 = pim >> 8, s1 = pim & 255;
                float w0 = (s0 == 255 || s1 == 255) ? 0.25f : 1.0f;
                fo[(((long)(bb*16 + m_l)) << 16) + pim] = w0 * (o[mt][r] + bias);
            }
        }
    }
}

// ---------------- LIIF MLP edge corners via MFMA (48 blocks) ---------------------
__global__ __launch_bounds__(256) void mlp_edge_mfma_k(const short* __restrict__ feat,
        const short* __restrict__ wp,
        const float* __restrict__ b_in, const float* __restrict__ b_h,
        const float* __restrict__ b_out,
        float* __restrict__ fo){
    extern __shared__ short act_s[];
    int tid = threadIdx.x, bx = blockIdx.x;
    int E0 = bx * 128;
    for (int idx = tid; idx < 128*160; idx += 256) {
        int pp = idx / 160, j = idx - pp*160;
        int e = E0 + pp; if (e >= 6132) e = 0;
        int bb = e / 1533; int rem = e - bb*1533;
        int cn = rem / 511; int eidx = rem - cn*511;
        int s0 = (eidx < 256) ? 255 : eidx - 256;
        int s1 = (eidx < 256) ? eidx : 255;
        int vx = (cn == 0) ? -1 : 1;
        int vy = (cn == 1) ? -1 : 1;
        int i0 = (vx > 0) ? min(s0+1, 255) : s0;
        int i1 = (vy > 0) ? min(s1+1, 255) : s1;
        short v = 0;
        if (j < 144) {
            int iy = j/48, ix = (j>>4)%3, c2 = j&15;
            int yy = i0 + iy - 1, xx = i1 + ix - 1;
            if (yy >= 0 && yy < 256 && xx >= 0 && xx < 256)
                v = feat[(((long)(bb*16 + c2)) << 16) + (yy<<8) + xx];
        } else if (j == 144) v = f2bs(2.f*(float)(s0 - i0));
        else if (j == 145) v = f2bs(2.f*(float)(s1 - i1));
        else if (j >= 146) v = 0x4000;
        act_s[pp*264 + j] = v;
    }
    __syncthreads();

    int l = tid & 63, w = tid >> 6;
    int m_l = l & 15, q = l >> 4;
    int row0 = w * 32;
    const short* wph  = wp + 40960;
    const short* wpo  = wp + 40960 + 3*65536;

    float4v acc[2][16];
    #pragma unroll
    for (int mt = 0; mt < 2; ++mt)
        #pragma unroll
        for (int nt = 0; nt < 16; ++nt) acc[mt][nt] = (float4v){0.f,0.f,0.f,0.f};
    for (int kt = 0; kt < 5; ++kt) {
        short8 a0 = *(const short8*)&act_s[(row0 + m_l)*264 + kt*32 + q*8];
        short8 a1 = *(const short8*)&act_s[(row0 + 16 + m_l)*264 + kt*32 + q*8];
        const short* bp = wp + ((size_t)(kt*16)*64 + l)*8;
        #pragma unroll
        for (int nt = 0; nt < 16; ++nt) {
            short8 bf = *(const short8*)(bp + (size_t)nt*64*8);
            acc[0][nt] = __builtin_amdgcn_mfma_f32_16x16x32_bf16(a0, bf, acc[0][nt], 0, 0, 0);
            acc[1][nt] = __builtin_amdgcn_mfma_f32_16x16x32_bf16(a1, bf, acc[1][nt], 0, 0, 0);
        }
    }
    #pragma unroll
    for (int nt = 0; nt < 16; ++nt) {
        float bias = b_in[nt*16 + m_l];
        #pragma unroll
        for (int mt = 0; mt < 2; ++mt)
            #pragma unroll
            for (int r = 0; r < 4; ++r) {
                float vv = fmaxf(acc[mt][nt][r] + bias, 0.f);
                act_s[(row0 + mt*16 + q*4 + r)*264 + nt*16 + m_l] = f2bs(vv);
            }
    }
    for (int L = 0; L < 3; ++L) {
        #pragma unroll
        for (int mt = 0; mt < 2; ++mt)
            #pragma unroll
            for (int nt = 0; nt < 16; ++nt) acc[mt][nt] = (float4v){0.f,0.f,0.f,0.f};
        const short* wl = wph + (size_t)L * 65536;
        for (int kt = 0; kt < 8; ++kt) {
            short8 a0 = *(const short8*)&act_s[(row0 + m_l)*264 + kt*32 + q*8];
            short8 a1 = *(const short8*)&act_s[(row0 + 16 + m_l)*264 + kt*32 + q*8];
            const short* bp = wl + ((size_t)(kt*16)*64 + l)*8;
            #pragma unroll
            for (int nt = 0; nt < 16; ++nt) {
                short8 bf = *(const short8*)(bp + (size_t)nt*64*8);
                acc[0][nt] = __builtin_amdgcn_mfma_f32_16x16x32_bf16(a0, bf, acc[0][nt], 0, 0, 0);
                acc[1][nt] = __builtin_amdgcn_mfma_f32_16x16x32_bf16(a1, bf, acc[1][nt], 0, 0, 0);
            }
        }
        #pragma unroll
        for (int nt = 0; nt < 16; ++nt) {
            float bias = b_h[L*256 + nt*16 + m_l];
            #pragma unroll
            for (int mt = 0; mt < 2; ++mt)
                #pragma unroll
                for (int r = 0; r < 4; ++r) {
                    float vv = fmaxf(acc[mt][nt][r] + bias, 0.f);
                    act_s[(row0 + mt*16 + q*4 + r)*264 + nt*16 + m_l] = f2bs(vv);
                }
        }
    }
    float4v o0 = (float4v){0.f,0.f,0.f,0.f}, o1 = (float4v){0.f,0.f,0.f,0.f};
    for (int kt = 0; kt < 8; ++kt) {
        short8 a0 = *(const short8*)&act_s[(row0 + m_l)*264 + kt*32 + q*8];
        short8 a1 = *(const short8*)&act_s[(row0 + 16 + m_l)*264 + kt*32 + q*8];
        short8 bf = *(const short8*)(wpo + ((size_t)kt*64 + l)*8);
        o0 = __builtin_amdgcn_mfma_f32_16x16x32_bf16(a0, bf, o0, 0, 0, 0);
        o1 = __builtin_amdgcn_mfma_f32_16x16x32_bf16(a1, bf, o1, 0, 0, 0);
    }
    float bias = b_out[m_l];
    #pragma unroll
    for (int mt = 0; mt < 2; ++mt) {
        float4v* op = mt ? &o1 : &o0;
        #pragma unroll
        for (int r = 0; r < 4; ++r) {
            int e = E0 + row0 + mt*16 + q*4 + r;
            float scale = (e < 6132) ? 0.25f : 0.f;
            if (e >= 6132) e = 0;
            int bb = e / 1533; int rem = e - bb*1533;
            int cn = rem / 511; int eidx = rem - cn*511;
            int s0 = (eidx < 256) ? 255 : eidx - 256;
            int s1 = (eidx < 256) ? eidx : 255;
            atomicAdd(&fo[(((long)(bb*16 + m_l)) << 16) + (s0<<8) + s1],
                      scale * ((*op)[r] + bias));
        }
    }
}

// ---------------- final conv (16->4) + lrms_up -----------------------------------
__global__ __launch_bounds__(256) void final_k(const float* __restrict__ fo, const float* __restrict__ w,
                                               const float* __restrict__ lrms_up, float* __restrict__ out){
    int tid = threadIdx.x, bx = blockIdx.x;
    int y = bx & 255, oc = (bx >> 8) & 3, b = bx >> 10;
    int x = tid;
    const float* wg = w + (size_t)oc * 144;
    float acc = 0.f;
    for (int ic = 0; ic < 16; ++ic) {
        const float* base = fo + (((size_t)(b*16 + ic)) << 16);
        #pragma unroll
        for (int ky = 0; ky < 3; ++ky) {
            int yy = y + ky - 1; if (yy < 0 || yy > 255) continue;
            const float* rowp = base + (yy<<8);
            float v0 = (x > 0)   ? rowp[x-1] : 0.f;
            float v1 = rowp[x];
            float v2 = (x < 255) ? rowp[x+1] : 0.f;
            const float* wr = wg + ic*9 + ky*3;
            acc = fmaf(wr[0], v0, fmaf(wr[1], v1, fmaf(wr[2], v2, acc)));
        }
    }
    size_t oidx = (((size_t)(b*4 + oc)) << 16) + (y<<8) + x;
    out[oidx] = acc + lrms_up[oidx];
}

// ================================================================================
extern "C" void kernel_launch(void* const* d_in, const int* in_sizes, int n_in,
                              void* d_out, int out_size, void* d_ws, size_t ws_size,
                              hipStream_t stream) {
    const float* lrms     = (const float*)d_in[0];
    const float* pan      = (const float*)d_in[1];
    const float* w_convps = (const float*)d_in[2];
    const float* hor_w1   = (const float*)d_in[3];
    const float* hor_w2   = (const float*)d_in[4];
    const float* ffc_l2l  = (const float*)d_in[5];
    const float* ffc_l2g  = (const float*)d_in[6];
    const float* ffc_g2l  = (const float*)d_in[7];
    const float* ffc_spec = (const float*)d_in[8];
    const float* ref_in   = (const float*)d_in[9];
    const float* ref_b1   = (const float*)d_in[10];
    const float* ref_b2   = (const float*)d_in[11];
    const float* ref_ca1  = (const float*)d_in[12];
    const float* ref_ca2  = (const float*)d_in[13];
    const float* ref_out  = (const float*)d_in[14];
    const float* w_fuse   = (const float*)d_in[15];
    const float* w_liif   = (const float*)d_in[16];
    const float* w_hp     = (const float*)d_in[17];
    const float* mw_in    = (const float*)d_in[18];
    const float* mb_in    = (const float*)d_in[19];
    const float* mw_h     = (const float*)d_in[20];
    const float* mb_h     = (const float*)d_in[21];
    const float* mw_out   = (const float*)d_in[22];
    const float* mb_out   = (const float*)d_in[23];
    float* out = (float*)d_out;

    const size_t PLANE = 65536;
    char* base = (char*)d_ws;
    size_t off = 0;
    auto alloc = [&](size_t bytes){ void* p = base + off; off += (bytes + 255) & ~(size_t)255; return p; };
    float* lrms_up  = (float*)alloc(16*PLANE*4);
    bf16*  feat2    = (bf16*) alloc(24*PLANE*2);
    bf16*  bA       = (bf16*) alloc(192*PLANE*2);
    bf16*  bB       = (bf16*) alloc(192*PLANE*2);
    bf16*  bC       = (bf16*) alloc(192*PLANE*2);
    bf16*  bF       = (bf16*) alloc(192*PLANE*2);
    bf16*  fusedCat = (bf16*) alloc(192*PLANE*2);
    bf16*  feat_all = (bf16*) alloc(64*PLANE*2);
    float* fo       = (float*)alloc(64*PLANE*4);
    const size_t FFTB = (size_t)3*4*8*256*129;
    bf16* re0 = (bf16*)alloc(FFTB*2); bf16* im0 = (bf16*)alloc(FFTB*2);
    bf16* re1 = (bf16*)alloc(FFTB*2); bf16* im1 = (bf16*)alloc(FFTB*2);
    short* wpack = (short*)alloc(241664*2);
    float* ffcw  = (float*)alloc(13824*4);
    short* wconv = (short*)alloc(45*2560*2);
    float* means = (float*)alloc(192*4);
    float* cav   = (float*)alloc(192*4);
    if (off > ws_size) return;

    hipMemsetAsync(means, 0, 192*4, stream);
    repack_k<<<dim3(944), dim3(256), 0, stream>>>(mw_in, mw_h, mw_out, wpack);
    pack_ffcw_k<<<dim3(54), dim3(256), 0, stream>>>(ffc_l2l, ffc_l2g, ffc_g2l, ffcw);
    pack_convw_k<<<dim3(450), dim3(256), 0, stream>>>(hor_w2, ref_in, ref_b1, ref_b2, ffcw, ref_out, wconv);
    conv_ps_k<<<dim3(4096), dim3(256), 0, stream>>>(lrms, w_convps, lrms_up);

    GK3 g3;
    {
        const int kss[3] = {5, 27, 41};
        const double sgs[3] = {1.5, 2.0, 2.8};
        for (int br = 0; br < 3; ++br) {
            g3.ks[br] = kss[br];
            double tmp[41]; double s = 0.0; double c = (kss[br]-1)/2.0;
            for (int i = 0; i < kss[br]; ++i) { double d = i - c; tmp[i] = exp(-(d*d)/(2.0*sgs[br]*sgs[br])); s += tmp[i]; }
            for (int i = 0; i < 41; ++i) g3.k[br][i] = (i < kss[br]) ? (float)(tmp[i]/s) : 0.f;
        }
    }
    gauss_hp_k<<<dim3(6144), dim3(256), 0, stream>>>(pan, lrms_up, feat2, g3);

    // hornet
    convA_k<<<dim3(3072), dim3(256), 0, stream>>>(feat2, 2, 2, hor_w1, 720, 45, bA, ACT_GELU);
    convM_k<<<dim3(768), dim3(256), 0, stream>>>(bA, wconv + 0*3*2560, bB, ACT_NONE, nullptr);

    for (int step = 0; step < 3; ++step) {
        bf16* Xin = (step == 0) ? bB : bA;
        bf16* Yb  = (step == 0) ? bA : bB;
        bf16* Db  = (step == 0) ? bB : bA;
        convM_k<<<dim3(768), dim3(256), 0, stream>>>(Xin, wconv + (1+step)*3*2560, Yb, ACT_NONE, nullptr);
        convM_k<<<dim3(768), dim3(256), 0, stream>>>(Yb,  wconv + (4+step)*3*2560, bC, ACT_RELU, nullptr);
        convM_k<<<dim3(768), dim3(256), 0, stream>>>(bC,  wconv + (7+step)*3*2560, Db, ACT_NONE, means);
        ca_k<<<dim3(1), dim3(192), 0, stream>>>(means, ref_ca1, ref_ca2, step, cav);
        convOutM_k<<<dim3(768), dim3(256), 0, stream>>>(Yb, Db, cav, wconv + (12+step)*3*2560, w_fuse, step, bF, fusedCat);
        if (step < 2) {
            convM_k<<<dim3(768), dim3(256), 0, stream>>>(bF, wconv + (10+step)*3*2560, bA, ACT_NONE, nullptr);
            rfft_wT_k<<<dim3(1536), dim3(256), 0, stream>>>(bF, re0, im0);
            fftspec_hT_k<<<dim3(1548), dim3(256), 0, stream>>>(re0, im0, ffc_spec, step, re1, im1);
            irfft_wT_k<<<dim3(1536), dim3(256), 0, stream>>>(re1, im1, bA);
        }
    }

    fuse1x1_k<<<dim3(1024), dim3(256), 0, stream>>>(fusedCat, w_liif, feat_all);
    mlp_mfma_k<<<dim3(2048), dim3(512), 65536, stream>>>((const short*)feat_all, wpack, mb_in, mb_h, mb_out, fo);
    mlp_edge_mfma_k<<<dim3(48), dim3(256), 128*264*2, stream>>>((const short*)feat_all, wpack, mb_in, mb_h, mb_out, fo);
    final_k<<<dim3(4096), dim3(256), 0, stream>>>(fo, w_hp, lrms_up, out);
}

// Round 10
// 1168.965 us; speedup vs baseline: 11.4300x; 1.0320x over previous
//
#include <hip/hip_runtime.h>
#include <hip/hip_bf16.h>
#include <math.h>

typedef __hip_bfloat16 bf16;
typedef __attribute__((ext_vector_type(8))) short short8;
typedef __attribute__((ext_vector_type(4))) short short4v;
typedef __attribute__((ext_vector_type(4))) float float4v;

#define ACT_NONE 0
#define ACT_RELU 1
#define ACT_GELU 2

__device__ __forceinline__ float b2f(bf16 v){ return __bfloat162float(v); }
__device__ __forceinline__ bf16  f2b(float f){ return __float2bfloat16(f); }
__device__ __forceinline__ short f2bs(float f){ bf16 h = __float2bfloat16(f); return *reinterpret_cast<short*>(&h); }
__device__ __forceinline__ float bs2f(short s){ return __uint_as_float(((unsigned)(unsigned short)s) << 16); }
__device__ __forceinline__ void rotc(float& tr, float& ti, float cr, float ci){
    float t = tr*cr - ti*ci; ti = tr*ci + ti*cr; tr = t;
}

struct GK3 { float k[3][41]; int ks[3]; };

// ---------------- pixel-shuffle conv ------------------------------------------
__global__ __launch_bounds__(256) void conv_ps_k(const float* __restrict__ lrms,
                                                 const float* __restrict__ w,
                                                 float* __restrict__ up){
    int tid = threadIdx.x, bx = blockIdx.x;
    int y = bx & 255, c = (bx >> 8) & 3, b = bx >> 10;
    int x = tid;
    int h = y >> 2, r1 = y & 3, ww = x >> 2, r2 = x & 3;
    int oc = c*16 + r1*4 + r2;
    float acc = 0.f;
    for (int ic = 0; ic < 4; ++ic) {
        const float* base = lrms + ((b*4 + ic) << 12);
        const float* wb = w + (oc*4 + ic)*9;
        #pragma unroll
        for (int ky = 0; ky < 3; ++ky) {
            int hh = h + ky - 1; if (hh < 0 || hh > 63) continue;
            #pragma unroll
            for (int kx = 0; kx < 3; ++kx) {
                int cc = ww + kx - 1; if (cc < 0 || cc > 63) continue;
                acc += base[(hh<<6) + cc] * wb[ky*3 + kx];
            }
        }
    }
    up[(((size_t)(b*4 + c)) << 16) + (y<<8) + x] = acc;
}

// ---------------- fused gaussian highpass -------------------------------------
__global__ __launch_bounds__(256) void gauss_hp_k(const float* __restrict__ pan,
                                                  const float* __restrict__ lrms_up,
                                                  bf16* __restrict__ feat2, GK3 g){
    int tid = threadIdx.x, bx = blockIdx.x;
    int y = bx & 255, b = (bx >> 8) & 3, src = (bx >> 10) & 1, br = bx >> 11;
    int ks = g.ks[br], p = ks >> 1;
    const float* gk = g.k[br];
    const float* s = src ? (lrms_up + (size_t)b*4*65536) : (pan + (size_t)b*65536);
    __shared__ float vext[296];
    for (int i = tid; i < 296; i += 256) {
        int xe = i - 20; int xr = xe < 0 ? -xe : (xe > 255 ? 510 - xe : xe);
        float acc = 0.f;
        for (int t = 0; t < ks; ++t) {
            int yy = y - p + t; yy = yy < 0 ? -yy : (yy > 255 ? 510 - yy : yy);
            acc += gk[t] * s[(yy<<8) + xr];
        }
        vext[i] = acc;
    }
    __syncthreads();
    int x = tid;
    float acc = 0.f;
    for (int t = 0; t < ks; ++t) acc += gk[t] * vext[x - p + t + 20];
    float o = s[(y<<8) + x];
    feat2[(((size_t)((br*4 + b)*2 + src)) << 16) + (y<<8) + x] = f2b(o - acc);
}

// ---------------- scalar 3x3 conv (hornet conv1, Cin=2) -------------------------
__global__ __launch_bounds__(256) void convA_k(const bf16* __restrict__ in, int inCper, int Cin,
                                               const float* __restrict__ wbase, int wbrstride, int wocstride,
                                               bf16* __restrict__ out, int act){
    int tid = threadIdx.x, bx = blockIdx.x;
    int y = bx & 255, b = (bx >> 8) & 3, br = bx >> 10;
    const float* w = wbase + (size_t)br * wbrstride;
    int x = tid;
    float acc[16];
    #pragma unroll
    for (int oc = 0; oc < 16; ++oc) acc[oc] = 0.f;
    for (int ic = 0; ic < Cin; ++ic) {
        const bf16* base = in + ((size_t)((br*4 + b)*inCper + ic) << 16);
        const float* wic = w + ic*9;
        #pragma unroll
        for (int ky = 0; ky < 3; ++ky) {
            int yy = y + ky - 1; if (yy < 0 || yy > 255) continue;
            const bf16* rowp = base + (yy<<8);
            float v0 = (x > 0)   ? b2f(rowp[x-1]) : 0.f;
            float v1 = b2f(rowp[x]);
            float v2 = (x < 255) ? b2f(rowp[x+1]) : 0.f;
            const float* wr = wic + ky*3;
            #pragma unroll
            for (int oc = 0; oc < 16; ++oc) {
                const float* wo = wr + oc*wocstride;
                acc[oc] = fmaf(wo[0], v0, fmaf(wo[1], v1, fmaf(wo[2], v2, acc[oc])));
            }
        }
    }
    #pragma unroll
    for (int oc = 0; oc < 16; ++oc) {
        float a = acc[oc];
        if (act == ACT_RELU) a = fmaxf(a, 0.f);
        else if (act == ACT_GELU) {
            float u = 0.7978845608028654f * (a + 0.044715f*a*a*a);
            a = 0.5f * a * (1.f + tanhf(u));
        }
        out[((size_t)((br*4 + b)*16 + oc) << 16) + (y<<8) + x] = f2b(a);
    }
}

// ---------------- merged pack: MLP weights + conv weights (ffcw inlined) ---------
__global__ __launch_bounds__(256) void pack_all_k(const float* __restrict__ mw_in,
        const float* __restrict__ mw_h, const float* __restrict__ mw_out,
        const float* __restrict__ hor_w2,
        const float* __restrict__ ref_in, const float* __restrict__ ref_b1,
        const float* __restrict__ ref_b2, const float* __restrict__ ref_out,
        const float* __restrict__ l2l, const float* __restrict__ l2g,
        const float* __restrict__ g2l,
        short* __restrict__ wp, short* __restrict__ wc){
    int idx = blockIdx.x*256 + threadIdx.x;
    const int S0 = 40960, SH = 65536;
    const int TOTM = S0 + 3*SH + 4096;        // 241664
    const int TOTC = 45*2560;                  // 115200
    if (idx < TOTM) {
        float val;
        if (idx < S0) {
            int j = idx & 7, l = (idx>>3) & 63, nt = (idx>>9) & 15, kt = idx >> 13;
            int k = kt*32 + (l>>4)*8 + j;
            int n = nt*16 + (l&15);
            val = (k < 148) ? mw_in[k*256 + n] : 0.f;
        } else if (idx < S0 + 3*SH) {
            int i2 = idx - S0;
            int L = i2 >> 16, r = i2 & 65535;
            int j = r & 7, l = (r>>3) & 63, nt = (r>>9) & 15, kt = r >> 13;
            int k = kt*32 + (l>>4)*8 + j;
            int n = nt*16 + (l&15);
            val = mw_h[L*65536 + k*256 + n];
        } else {
            int i3 = idx - S0 - 3*SH;
            int j = i3 & 7, l = (i3>>3) & 63, kt = i3 >> 9;
            int k = kt*32 + (l>>4)*8 + j;
            int oc = l & 15;
            val = mw_out[k*16 + oc];
        }
        wp[idx] = f2bs(val);
        return;
    }
    int idx2 = idx - TOTM;
    if (idx2 >= TOTC) return;
    int set = idx2 / 2560, r = idx2 % 2560;
    int j = r & 7, l = (r>>3) & 63, kt = r >> 9;
    int k = kt*32 + ((l>>4)&3)*8 + j;
    int n = l & 15;
    int g = set / 3, br = set % 3;
    float v = 0.f;
    if (k < 144) {
        int tap = k >> 4, ic = k & 15;
        if (g == 10 || g == 11) {
            int wi = 2*br + (g-10);
            if (n < 8) v = (ic < 8) ? l2g[((wi*8 + n)*8 + ic)*9 + tap] : 0.f;
            else {
                int o = n - 8;
                v = (ic < 8) ? l2l[((wi*8 + o)*8 + ic)*9 + tap]
                             : g2l[((wi*8 + o)*8 + (ic-8))*9 + tap];
            }
        } else {
            int widx = (n*16 + ic)*9 + tap;
            const float* src;
            if (g == 0)       src = hor_w2 + br*2304;
            else if (g <= 3)  src = ref_in + (3*br + (g-1))*2304;
            else if (g <= 6)  src = ref_b1 + (3*br + (g-4))*2304;
            else if (g <= 9)  src = ref_b2 + (3*br + (g-7))*2304;
            else              src = ref_out + (3*br + (g-12))*2304;
            v = src[widx];
        }
    }
    wc[idx2] = f2bs(v);
}

// ---------------- MFMA 3x3 conv, 4 output rows per block ------------------------
__global__ __launch_bounds__(256) void convM_k(const bf16* __restrict__ in,
        const short* __restrict__ wgroup,
        bf16* __restrict__ out, int act, float* __restrict__ means){
    __shared__ short sIn[6*258*20];
    __shared__ float sm[4][16];
    int tid = threadIdx.x, bx = blockIdx.x;
    int y0 = (bx & 63) << 2, b = (bx >> 6) & 3, br = bx >> 8;
    size_t pbase = (size_t)((br*4 + b)*16) << 16;
    if (tid < 192) {
        int r = tid >> 5, side = (tid >> 4) & 1, ic = tid & 15;
        sIn[(r*258 + (side ? 257 : 0))*20 + ic] = 0;
    }
    {
        int g = tid >> 5, tl = tid & 31, x0 = tl << 3, ic0 = g*2;
        for (int r = 0; r < 6; ++r) {
            int yy = y0 - 1 + r;
            short8 lo = {0,0,0,0,0,0,0,0}, hi = {0,0,0,0,0,0,0,0};
            if (yy >= 0 && yy <= 255) {
                lo = *(const short8*)&in[pbase + ((size_t)ic0<<16) + (yy<<8) + x0];
                hi = *(const short8*)&in[pbase + ((size_t)(ic0+1)<<16) + (yy<<8) + x0];
            }
            #pragma unroll
            for (int t = 0; t < 8; ++t) {
                int v = (int)(unsigned short)lo[t] | ((int)(unsigned short)hi[t] << 16);
                *(int*)&sIn[(r*258 + x0 + t + 1)*20 + ic0] = v;
            }
        }
    }
    __syncthreads();
    int l = tid & 63, w = tid >> 6, m_l = l & 15, q = l >> 4;
    const short* wp = wgroup + br*2560;
    short8 bfr[5];
    #pragma unroll
    for (int kt = 0; kt < 5; ++kt)
        bfr[kt] = *(const short8*)(wp + (kt*64 + l)*8);
    float4v acc[16];
    #pragma unroll
    for (int j = 0; j < 16; ++j) acc[j] = (float4v){0.f,0.f,0.f,0.f};
    #pragma unroll
    for (int kt = 0; kt < 5; ++kt) {
        int k0 = kt*32 + q*8;
        bool pad = (k0 >= 144);
        int tap = pad ? 0 : (k0 >> 4);
        int icb = k0 & 15;
        int ky = tap/3, kx = tap - ky*3;
        int rbase = (w + ky)*258 + kx;
        #pragma unroll
        for (int j = 0; j < 16; ++j) {
            int x = j*16 + m_l;
            const short* ap = &sIn[(rbase + x)*20 + icb];
            short4v alo = *(const short4v*)ap;
            short4v ahi = *(const short4v*)(ap + 4);
            short8 a;
            #pragma unroll
            for (int t = 0; t < 4; ++t) { a[t] = pad ? (short)0 : alo[t]; a[t+4] = pad ? (short)0 : ahi[t]; }
            acc[j] = __builtin_amdgcn_mfma_f32_16x16x32_bf16(a, bfr[kt], acc[j], 0, 0, 0);
        }
    }
    if (means) {
        float s = 0.f;
        #pragma unroll
        for (int j = 0; j < 16; ++j)
            #pragma unroll
            for (int r = 0; r < 4; ++r) s += acc[j][r];
        s += __shfl_xor(s, 16, 64);
        s += __shfl_xor(s, 32, 64);
        if (l < 16) sm[w][l] = s;
        __syncthreads();
        if (tid < 16) atomicAdd(&means[br*64 + b*16 + tid],
                                sm[0][tid] + sm[1][tid] + sm[2][tid] + sm[3][tid]);
    }
    int yrow = y0 + w;
    #pragma unroll
    for (int j = 0; j < 16; ++j) {
        short4v pk;
        #pragma unroll
        for (int r = 0; r < 4; ++r) {
            float a = acc[j][r];
            if (act == ACT_RELU) a = fmaxf(a, 0.f);
            else if (act == ACT_GELU) {
                float u = 0.7978845608028654f * (a + 0.044715f*a*a*a);
                a = 0.5f * a * (1.f + tanhf(u));
            }
            pk[r] = f2bs(a);
        }
        *(short4v*)&out[pbase + ((size_t)m_l << 16) + (yrow<<8) + j*16 + q*4] = pk;
    }
}

// ---------------- MFMA refine-out conv: ca computed inline, + fuse 1x1 ----------
__global__ __launch_bounds__(256) void convOutM_k(const bf16* __restrict__ Y, const bf16* __restrict__ BDY,
        const float* __restrict__ means, const float* __restrict__ ca1, const float* __restrict__ ca2,
        const short* __restrict__ wgroup,
        const float* __restrict__ wfuse, int step,
        bf16* __restrict__ F, bf16* __restrict__ fusedCat){
    __shared__ short sIn[6*258*20];
    __shared__ float sCav[16];
    int tid = threadIdx.x, bx = blockIdx.x;
    int y0 = (bx & 63) << 2, b = (bx >> 6) & 3, br = bx >> 8;
    size_t pbase = (size_t)((br*4 + b)*16) << 16;
    if (tid < 192) {
        int r = tid >> 5, side = (tid >> 4) & 1, ic = tid & 15;
        sIn[(r*258 + (side ? 257 : 0))*20 + ic] = 0;
    }
    if (tid < 16) {
        int ri = 3*br + step;
        const float* w1 = ca1 + ri*64; const float* w2 = ca2 + ri*64;
        float hid[4];
        #pragma unroll
        for (int c2 = 0; c2 < 4; ++c2) {
            float a = 0.f;
            for (int c = 0; c < 16; ++c) a += w1[c2*16 + c] * (means[br*64 + b*16 + c] * (1.f/65536.f));
            hid[c2] = fmaxf(a, 0.f);
        }
        float v = 0.f;
        #pragma unroll
        for (int c2 = 0; c2 < 4; ++c2) v += w2[tid*4 + c2] * hid[c2];
        sCav[tid] = 1.f / (1.f + expf(-v));
    }
    __syncthreads();
    {
        int g = tid >> 5, tl = tid & 31, x0 = tl << 3, ic0 = g*2;
        float c0 = sCav[ic0];
        float c1 = sCav[ic0 + 1];
        for (int r = 0; r < 6; ++r) {
            int yy = y0 - 1 + r;
            short8 ylo = {0,0,0,0,0,0,0,0}, yhi = ylo, dlo = ylo, dhi = ylo;
            if (yy >= 0 && yy <= 255) {
                size_t o0 = pbase + ((size_t)ic0<<16) + (yy<<8) + x0;
                size_t o1 = pbase + ((size_t)(ic0+1)<<16) + (yy<<8) + x0;
                ylo = *(const short8*)&Y[o0];   yhi = *(const short8*)&Y[o1];
                dlo = *(const short8*)&BDY[o0]; dhi = *(const short8*)&BDY[o1];
            }
            #pragma unroll
            for (int t = 0; t < 8; ++t) {
                short s0 = f2bs(fmaf(bs2f(dlo[t]), c0, bs2f(ylo[t])));
                short s1 = f2bs(fmaf(bs2f(dhi[t]), c1, bs2f(yhi[t])));
                int v = (int)(unsigned short)s0 | ((int)(unsigned short)s1 << 16);
                *(int*)&sIn[(r*258 + x0 + t + 1)*20 + ic0] = v;
            }
        }
    }
    __syncthreads();
    int l = tid & 63, w = tid >> 6, m_l = l & 15, q = l >> 4;
    const short* wp = wgroup + br*2560;
    short8 bfr[5];
    #pragma unroll
    for (int kt = 0; kt < 5; ++kt)
        bfr[kt] = *(const short8*)(wp + (kt*64 + l)*8);
    float4v acc[16];
    #pragma unroll
    for (int j = 0; j < 16; ++j) acc[j] = (float4v){0.f,0.f,0.f,0.f};
    #pragma unroll
    for (int kt = 0; kt < 5; ++kt) {
        int k0 = kt*32 + q*8;
        bool pad = (k0 >= 144);
        int tap = pad ? 0 : (k0 >> 4);
        int icb = k0 & 15;
        int ky = tap/3, kx = tap - ky*3;
        int rbase = (w + ky)*258 + kx;
        #pragma unroll
        for (int j = 0; j < 16; ++j) {
            int x = j*16 + m_l;
            const short* ap = &sIn[(rbase + x)*20 + icb];
            short4v alo = *(const short4v*)ap;
            short4v ahi = *(const short4v*)(ap + 4);
            short8 a;
            #pragma unroll
            for (int t = 0; t < 4; ++t) { a[t] = pad ? (short)0 : alo[t]; a[t+4] = pad ? (short)0 : ahi[t]; }
            acc[j] = __builtin_amdgcn_mfma_f32_16x16x32_bf16(a, bfr[kt], acc[j], 0, 0, 0);
        }
    }
    int yrow = y0 + w;
    #pragma unroll
    for (int j = 0; j < 16; ++j) {
        short4v pk;
        #pragma unroll
        for (int r = 0; r < 4; ++r) pk[r] = f2bs(acc[j][r]);
        *(short4v*)&F[pbase + ((size_t)m_l << 16) + (yrow<<8) + j*16 + q*4] = pk;
    }
    __syncthreads();            // everyone done reading sIn; reuse as sF
    short* sF = sIn + w*4096;   // per-wave 256px x 16oc
    #pragma unroll
    for (int j = 0; j < 16; ++j)
        #pragma unroll
        for (int r = 0; r < 4; ++r)
            sF[(j*16 + q*4 + r)*16 + m_l] = f2bs(acc[j][r]);
    const float* wf = wfuse + br*768 + step*16;   // wf[oc2*48 + oc]
    short8 b2;
    #pragma unroll
    for (int jj = 0; jj < 8; ++jj) {
        int k = q*8 + jj;
        b2[jj] = (k < 16) ? f2bs(wf[m_l*48 + k]) : (short)0;
    }
    #pragma unroll
    for (int mt = 0; mt < 16; ++mt) {
        short8 a2 = {0,0,0,0,0,0,0,0};
        if (q < 2) a2 = *(const short8*)&sF[(mt*16 + m_l)*16 + q*8];
        float4v d2 = (float4v){0.f,0.f,0.f,0.f};
        d2 = __builtin_amdgcn_mfma_f32_16x16x32_bf16(a2, b2, d2, 0, 0, 0);
        size_t fidx = ((size_t)(b*48 + br*16 + m_l) << 16) + (yrow<<8) + mt*16 + q*4;
        short4v pk;
        if (step == 0) {
            #pragma unroll
            for (int r = 0; r < 4; ++r) pk[r] = f2bs(d2[r]);
        } else {
            short4v old = *(const short4v*)&fusedCat[fidx];
            #pragma unroll
            for (int r = 0; r < 4; ++r) pk[r] = f2bs(bs2f(old[r]) + d2[r]);
        }
        *(short4v*)&fusedCat[fidx] = pk;
    }
}

// ---------------- radix-16 rfft along W, output TRANSPOSED [k][y] ----------------
__global__ __launch_bounds__(256) void rfft_wT_k(const bf16* __restrict__ F,
                                                 bf16* __restrict__ ore, bf16* __restrict__ oim){
    __shared__ float rows[16][256];
    __shared__ float Ar[256], Ai[256];
    __shared__ float Tr[129][17], Ti[129][17];
    int tid = threadIdx.x, bx = blockIdx.x;
    int t = bx & 15, c = (bx >> 4) & 7, b = (bx >> 7) & 3, br = bx >> 9;
    int y0 = t << 4;
    size_t plane = (size_t)((br*4 + b)*16 + 8 + c) << 16;
    #pragma unroll
    for (int r = 0; r < 16; ++r)
        rows[r][tid] = b2f(F[plane + ((size_t)(y0 + r) << 8) + tid]);
    __syncthreads();
    int n1 = tid >> 4, k1 = tid & 15;
    float a1 = -6.283185307179586f * (float)k1 / 16.f;
    float c1, s1; __sincosf(a1, &s1, &c1);
    float a2 = -6.283185307179586f * (float)tid / 256.f;
    float c2v, s2v; __sincosf(a2, &s2v, &c2v);
    for (int r = 0; r < 16; ++r) {
        float twr = 1.f, twi = 0.f, ar = 0.f, ai = 0.f;
        #pragma unroll
        for (int n2 = 0; n2 < 16; ++n2) {
            float xr = rows[r][n1 + (n2<<4)];
            ar = fmaf(xr, twr, ar); ai = fmaf(xr, twi, ai);
            rotc(twr, twi, c1, s1);
        }
        Ar[tid] = ar; Ai[tid] = ai;
        __syncthreads();
        float t2r = 1.f, t2i = 0.f, re = 0.f, im = 0.f;
        #pragma unroll
        for (int m = 0; m < 16; ++m) {
            float rr = Ar[(m<<4) + k1], ii = Ai[(m<<4) + k1];
            re += rr*t2r - ii*t2i; im += ii*t2r + rr*t2i;
            rotc(t2r, t2i, c2v, s2v);
        }
        if (tid < 129) { Tr[tid][r] = re * 0.0625f; Ti[tid][r] = im * 0.0625f; }
        __syncthreads();
    }
    size_t obase = ((size_t)(((br*4 + b)*8 + c)*129)) * 256 + y0;
    for (int idx = tid; idx < 129*16; idx += 256) {
        int k = idx >> 4, ty = idx & 15;
        ore[obase + (size_t)k*256 + ty] = f2b(Tr[k][ty]);
        oim[obase + (size_t)k*256 + ty] = f2b(Ti[k][ty]);
    }
}

// ---------------- FUSED: fft_h fwd -> spec -> fft_h inv, on [k][y] layout --------
__global__ __launch_bounds__(256) void fftspec_hT_k(const bf16* __restrict__ re0, const bf16* __restrict__ im0,
                                                    const float* __restrict__ wspec, int step,
                                                    bf16* __restrict__ re1, bf16* __restrict__ im1){
    __shared__ float Fr[8][256], Fi[8][256], Sr[8][256], Si[8][256], Ar[256], Ai[256];
    int tid = threadIdx.x, bx = blockIdx.x;
    int k = bx % 129; int r2 = bx / 129; int b = r2 & 3, br = r2 >> 2;
    size_t cb = (size_t)((br*4 + b)*8) * 33024 + (size_t)k * 256;
    int n1 = tid >> 4, k1 = tid & 15;
    float a1 = -6.283185307179586f * (float)k1 / 16.f;
    float c1, s1; __sincosf(a1, &s1, &c1);
    float a2 = -6.283185307179586f * (float)tid / 256.f;
    float c2v, s2v; __sincosf(a2, &s2v, &c2v);
    #pragma unroll
    for (int c = 0; c < 8; ++c) {
        size_t base = cb + (size_t)c*33024 + tid;
        Fr[c][tid] = b2f(re0[base]);
        Fi[c][tid] = b2f(im0[base]);
    }
    __syncthreads();
    for (int c = 0; c < 8; ++c) {
        float twr = 1.f, twi = 0.f, ar = 0.f, ai = 0.f;
        #pragma unroll
        for (int n2 = 0; n2 < 16; ++n2) {
            float r = Fr[c][n1 + (n2<<4)], i = Fi[c][n1 + (n2<<4)];
            ar += r*twr - i*twi; ai += i*twr + r*twi;
            rotc(twr, twi, c1, s1);
        }
        Ar[tid] = ar; Ai[tid] = ai;
        __syncthreads();
        float t2r = 1.f, t2i = 0.f, rr = 0.f, ii = 0.f;
        #pragma unroll
        for (int m = 0; m < 16; ++m) {
            float r = Ar[(m<<4) + k1], i = Ai[(m<<4) + k1];
            rr += r*t2r - i*t2i; ii += i*t2r + r*t2i;
            rotc(t2r, t2i, c2v, s2v);
        }
        Sr[c][tid] = rr * 0.0625f; Si[c][tid] = ii * 0.0625f;
        __syncthreads();
    }
    {
        const float* wl = wspec + (2*br + step)*256;
        float outv[16];
        #pragma unroll
        for (int oc = 0; oc < 16; ++oc) {
            float acc = 0.f;
            #pragma unroll
            for (int ic = 0; ic < 8; ++ic)
                acc += Sr[ic][tid] * wl[oc*16 + ic] + Si[ic][tid] * wl[oc*16 + 8 + ic];
            outv[oc] = fmaxf(acc, 0.f);
        }
        __syncthreads();
        #pragma unroll
        for (int oc = 0; oc < 8; ++oc) { Fr[oc][tid] = outv[oc]; Fi[oc][tid] = outv[oc+8]; }
        __syncthreads();
    }
    for (int c = 0; c < 8; ++c) {
        float twr = 1.f, twi = 0.f, ar = 0.f, ai = 0.f;
        #pragma unroll
        for (int n2 = 0; n2 < 16; ++n2) {
            float r = Fr[c][n1 + (n2<<4)], i = Fi[c][n1 + (n2<<4)];
            ar += r*twr + i*twi;
            ai += i*twr - r*twi;
            rotc(twr, twi, c1, s1);
        }
        Ar[tid] = ar; Ai[tid] = ai;
        __syncthreads();
        float t2r = 1.f, t2i = 0.f, rr = 0.f, ii = 0.f;
        #pragma unroll
        for (int m = 0; m < 16; ++m) {
            float r = Ar[(m<<4) + k1], i = Ai[(m<<4) + k1];
            rr += r*t2r + i*t2i;
            ii += i*t2r - r*t2i;
            rotc(t2r, t2i, c2v, s2v);
        }
        size_t base = cb + (size_t)c*33024 + tid;
        re1[base] = f2b(rr * 0.0625f);
        im1[base] = f2b(ii * 0.0625f);
        __syncthreads();
    }
}

// ---------------- c2r irfft along W from [k][y] layout, += into A ch0..7 ---------
__global__ __launch_bounds__(256) void irfft_wT_k(const bf16* __restrict__ re1, const bf16* __restrict__ im1,
                                                  bf16* __restrict__ A){
    __shared__ float Cr[129][17], Ci[129][17];
    __shared__ float er[256], ei[256];
    __shared__ float Ar[256], Ai[256];
    int tid = threadIdx.x, bx = blockIdx.x;
    int t = bx & 15, c = (bx >> 4) & 7, b = (bx >> 7) & 3, br = bx >> 9;
    int y0 = t << 4;
    size_t ibase = ((size_t)(((br*4 + b)*8 + c)*129)) * 256 + y0;
    for (int idx = tid; idx < 129*16; idx += 256) {
        int k = idx >> 4, ty = idx & 15;
        Cr[k][ty] = b2f(re1[ibase + (size_t)k*256 + ty]);
        Ci[k][ty] = (k == 0 || k == 128) ? 0.f : b2f(im1[ibase + (size_t)k*256 + ty]);
    }
    __syncthreads();
    int n1 = tid >> 4, k1 = tid & 15;
    float a1 = 6.283185307179586f * (float)k1 / 16.f;
    float c1, s1; __sincosf(a1, &s1, &c1);
    float a2 = 6.283185307179586f * (float)tid / 256.f;
    float c2v, s2v; __sincosf(a2, &s2v, &c2v);
    size_t plane = (size_t)((br*4 + b)*16 + c) << 16;
    for (int ty = 0; ty < 16; ++ty) {
        if (tid < 129) { er[tid] = Cr[tid][ty]; ei[tid] = Ci[tid][ty]; }
        else           { er[tid] = Cr[256 - tid][ty]; ei[tid] = -Ci[256 - tid][ty]; }
        __syncthreads();
        float twr = 1.f, twi = 0.f, ar = 0.f, ai = 0.f;
        #pragma unroll
        for (int n2 = 0; n2 < 16; ++n2) {
            float r = er[n1 + (n2<<4)], i = ei[n1 + (n2<<4)];
            ar += r*twr - i*twi; ai += i*twr + r*twi;
            rotc(twr, twi, c1, s1);
        }
        Ar[tid] = ar; Ai[tid] = ai;
        __syncthreads();
        float t2r = 1.f, t2i = 0.f, racc = 0.f;
        #pragma unroll
        for (int m = 0; m < 16; ++m) {
            float r = Ar[(m<<4) + k1], i = Ai[(m<<4) + k1];
            racc += r*t2r - i*t2i;
            rotc(t2r, t2i, c2v, s2v);
        }
        size_t o = plane + ((size_t)(y0 + ty) << 8) + tid;
        A[o] = f2b(b2f(A[o]) + racc * 0.0625f);
        __syncthreads();
    }
}

// ---------------- fuse 1x1 (48->16) ---------------------------------------------
__global__ __launch_bounds__(256) void fuse1x1_k(const bf16* __restrict__ fc, const float* __restrict__ wl,
                                                 bf16* __restrict__ feat_all){
    int tid = threadIdx.x, bx = blockIdx.x;
    int pt = bx & 255, b = bx >> 8;
    int p = (pt << 8) + tid;
    float acc[16];
    #pragma unroll
    for (int oc = 0; oc < 16; ++oc) acc[oc] = 0.f;
    for (int ic = 0; ic < 48; ++ic) {
        float v = b2f(fc[((size_t)(b*48 + ic) << 16) + p]);
        #pragma unroll
        for (int oc = 0; oc < 16; ++oc) acc[oc] = fmaf(wl[oc*48 + ic], v, acc[oc]);
    }
    #pragma unroll
    for (int oc = 0; oc < 16; ++oc)
        feat_all[((size_t)(b*16 + oc) << 16) + p] = f2b(acc[oc]);
}

// ---------------- LIIF MLP via MFMA (center), 256 thr, 64 px, 33.8KB LDS ---------
// wave w = n-quarter (4 nt of 16); all 4 m-tiles per wave.
__global__ __launch_bounds__(256) void mlp_mfma_k(const short* __restrict__ feat,
        const short* __restrict__ wp,
        const float* __restrict__ b_in, const float* __restrict__ b_h,
        const float* __restrict__ b_out,
        float* __restrict__ fo){
    extern __shared__ short act_s[];   // 64 rows x 264 shorts
    int tid = threadIdx.x, bx = blockIdx.x;
    long P0 = (long)bx * 64;
    for (int idx = tid; idx < 64*160; idx += 256) {
        int pp = idx / 160, j = idx - pp*160;
        long P = P0 + pp;
        int bb = (int)(P >> 16), pim = (int)(P & 65535);
        int s0 = pim >> 8, s1 = pim & 255;
        short v = 0;
        if (j < 144) {
            int iy = j/48, ix = (j>>4)%3, c2 = j&15;
            int yy = s0 + iy - 1, xx = s1 + ix - 1;
            if (yy >= 0 && yy < 256 && xx >= 0 && xx < 256)
                v = feat[(((long)(bb*16 + c2)) << 16) + (yy<<8) + xx];
        } else if (j == 146 || j == 147) v = 0x4000;
        act_s[pp*264 + j] = v;
    }
    __syncthreads();

    int l = tid & 63, w = tid >> 6;
    int m_l = l & 15, q = l >> 4;
    int ntb = w*4;
    const short* wph  = wp + 40960;
    const short* wpo  = wp + 40960 + 3*65536;

    float4v acc[4][4];
    // ---- layer 0 (K=160, 5 kt) ----
    #pragma unroll
    for (int mt = 0; mt < 4; ++mt)
        #pragma unroll
        for (int nt = 0; nt < 4; ++nt) acc[mt][nt] = (float4v){0.f,0.f,0.f,0.f};
    for (int kt = 0; kt < 5; ++kt) {
        const short* bp = wp + ((size_t)(kt*16 + ntb)*64 + l)*8;
        short8 bfr[4];
        #pragma unroll
        for (int nt = 0; nt < 4; ++nt) bfr[nt] = *(const short8*)(bp + (size_t)nt*64*8);
        #pragma unroll
        for (int mt = 0; mt < 4; ++mt) {
            short8 a = *(const short8*)&act_s[(mt*16 + m_l)*264 + kt*32 + q*8];
            #pragma unroll
            for (int nt = 0; nt < 4; ++nt)
                acc[mt][nt] = __builtin_amdgcn_mfma_f32_16x16x32_bf16(a, bfr[nt], acc[mt][nt], 0, 0, 0);
        }
    }
    __syncthreads();
    #pragma unroll
    for (int nt = 0; nt < 4; ++nt) {
        int n = (ntb + nt)*16 + m_l;
        float bias = b_in[n];
        #pragma unroll
        for (int mt = 0; mt < 4; ++mt)
            #pragma unroll
            for (int r = 0; r < 4; ++r) {
                float vv = fmaxf(acc[mt][nt][r] + bias, 0.f);
                act_s[(mt*16 + q*4 + r)*264 + n] = f2bs(vv);
            }
    }
    __syncthreads();
    // ---- hidden layers (K=256, 8 kt) ----
    for (int L = 0; L < 3; ++L) {
        #pragma unroll
        for (int mt = 0; mt < 4; ++mt)
            #pragma unroll
            for (int nt = 0; nt < 4; ++nt) acc[mt][nt] = (float4v){0.f,0.f,0.f,0.f};
        const short* wl = wph + (size_t)L * 65536;
        for (int kt = 0; kt < 8; ++kt) {
            const short* bp = wl + ((size_t)(kt*16 + ntb)*64 + l)*8;
            short8 bfr[4];
            #pragma unroll
            for (int nt = 0; nt < 4; ++nt) bfr[nt] = *(const short8*)(bp + (size_t)nt*64*8);
            #pragma unroll
            for (int mt = 0; mt < 4; ++mt) {
                short8 a = *(const short8*)&act_s[(mt*16 + m_l)*264 + kt*32 + q*8];
                #pragma unroll
                for (int nt = 0; nt < 4; ++nt)
                    acc[mt][nt] = __builtin_amdgcn_mfma_f32_16x16x32_bf16(a, bfr[nt], acc[mt][nt], 0, 0, 0);
            }
        }
        __syncthreads();
        #pragma unroll
        for (int nt = 0; nt < 4; ++nt) {
            int n = (ntb + nt)*16 + m_l;
            float bias = b_h[L*256 + n];
            #pragma unroll
            for (int mt = 0; mt < 4; ++mt)
                #pragma unroll
                for (int r = 0; r < 4; ++r) {
                    float vv = fmaxf(acc[mt][nt][r] + bias, 0.f);
                    act_s[(mt*16 + q*4 + r)*264 + n] = f2bs(vv);
                }
        }
        __syncthreads();
    }
    // ---- output layer (N=16): wave 0 only ----
    if (w == 0) {
        float4v o[4];
        #pragma unroll
        for (int mt = 0; mt < 4; ++mt) o[mt] = (float4v){0.f,0.f,0.f,0.f};
        for (int kt = 0; kt < 8; ++kt) {
            short8 bf = *(const short8*)(wpo + ((size_t)kt*64 + l)*8);
            #pragma unroll
            for (int mt = 0; mt < 4; ++mt) {
                short8 a = *(const short8*)&act_s[(mt*16 + m_l)*264 + kt*32 + q*8];
                o[mt] = __builtin_amdgcn_mfma_f32_16x16x32_bf16(a, bf, o[mt], 0, 0, 0);
            }
        }
        float bias = b_out[m_l];
        #pragma unroll
        for (int mt = 0; mt < 4; ++mt) {
            #pragma unroll
            for (int r = 0; r < 4; ++r) {
                long P = P0 + mt*16 + q*4 + r;
                int bb = (int)(P >> 16), pim = (int)(P & 65535);
                int s0 = pim >> 8, s1 = pim & 255;
                float w0 = (s0 == 255 || s1 == 255) ? 0.25f : 1.0f;
                fo[(((long)(bb*16 + m_l)) << 16) + pim] = w0 * (o[mt][r] + bias);
            }
        }
    }
}

// ---------------- LIIF MLP edge corners via MFMA (48 blocks) ---------------------
__global__ __launch_bounds__(256) void mlp_edge_mfma_k(const short* __restrict__ feat,
        const short* __restrict__ wp,
        const float* __restrict__ b_in, const float* __restrict__ b_h,
        const float* __restrict__ b_out,
        float* __restrict__ fo){
    extern __shared__ short act_s[];
    int tid = threadIdx.x, bx = blockIdx.x;
    int E0 = bx * 128;
    for (int idx = tid; idx < 128*160; idx += 256) {
        int pp = idx / 160, j = idx - pp*160;
        int e = E0 + pp; if (e >= 6132) e = 0;
        int bb = e / 1533; int rem = e - bb*1533;
        int cn = rem / 511; int eidx = rem - cn*511;
        int s0 = (eidx < 256) ? 255 : eidx - 256;
        int s1 = (eidx < 256) ? eidx : 255;
        int vx = (cn == 0) ? -1 : 1;
        int vy = (cn == 1) ? -1 : 1;
        int i0 = (vx > 0) ? min(s0+1, 255) : s0;
        int i1 = (vy > 0) ? min(s1+1, 255) : s1;
        short v = 0;
        if (j < 144) {
            int iy = j/48, ix = (j>>4)%3, c2 = j&15;
            int yy = i0 + iy - 1, xx = i1 + ix - 1;
            if (yy >= 0 && yy < 256 && xx >= 0 && xx < 256)
                v = feat[(((long)(bb*16 + c2)) << 16) + (yy<<8) + xx];
        } else if (j == 144) v = f2bs(2.f*(float)(s0 - i0));
        else if (j == 145) v = f2bs(2.f*(float)(s1 - i1));
        else if (j >= 146) v = 0x4000;
        act_s[pp*264 + j] = v;
    }
    __syncthreads();

    int l = tid & 63, w = tid >> 6;
    int m_l = l & 15, q = l >> 4;
    int row0 = w * 32;
    const short* wph  = wp + 40960;
    const short* wpo  = wp + 40960 + 3*65536;

    float4v acc[2][16];
    #pragma unroll
    for (int mt = 0; mt < 2; ++mt)
        #pragma unroll
        for (int nt = 0; nt < 16; ++nt) acc[mt][nt] = (float4v){0.f,0.f,0.f,0.f};
    for (int kt = 0; kt < 5; ++kt) {
        short8 a0 = *(const short8*)&act_s[(row0 + m_l)*264 + kt*32 + q*8];
        short8 a1 = *(const short8*)&act_s[(row0 + 16 + m_l)*264 + kt*32 + q*8];
        const short* bp = wp + ((size_t)(kt*16)*64 + l)*8;
        #pragma unroll
        for (int nt = 0; nt < 16; ++nt) {
            short8 bf = *(const short8*)(bp + (size_t)nt*64*8);
            acc[0][nt] = __builtin_amdgcn_mfma_f32_16x16x32_bf16(a0, bf, acc[0][nt], 0, 0, 0);
            acc[1][nt] = __builtin_amdgcn_mfma_f32_16x16x32_bf16(a1, bf, acc[1][nt], 0, 0, 0);
        }
    }
    #pragma unroll
    for (int nt = 0; nt < 16; ++nt) {
        float bias = b_in[nt*16 + m_l];
        #pragma unroll
        for (int mt = 0; mt < 2; ++mt)
            #pragma unroll
            for (int r = 0; r < 4; ++r) {
                float vv = fmaxf(acc[mt][nt][r] + bias, 0.f);
                act_s[(row0 + mt*16 + q*4 + r)*264 + nt*16 + m_l] = f2bs(vv);
            }
    }
    for (int L = 0; L < 3; ++L) {
        #pragma unroll
        for (int mt = 0; mt < 2; ++mt)
            #pragma unroll
            for (int nt = 0; nt < 16; ++nt) acc[mt][nt] = (float4v){0.f,0.f,0.f,0.f};
        const short* wl = wph + (size_t)L * 65536;
        for (int kt = 0; kt < 8; ++kt) {
            short8 a0 = *(const short8*)&act_s[(row0 + m_l)*264 + kt*32 + q*8];
            short8 a1 = *(const short8*)&act_s[(row0 + 16 + m_l)*264 + kt*32 + q*8];
            const short* bp = wl + ((size_t)(kt*16)*64 + l)*8;
            #pragma unroll
            for (int nt = 0; nt < 16; ++nt) {
                short8 bf = *(const short8*)(bp + (size_t)nt*64*8);
                acc[0][nt] = __builtin_amdgcn_mfma_f32_16x16x32_bf16(a0, bf, acc[0][nt], 0, 0, 0);
                acc[1][nt] = __builtin_amdgcn_mfma_f32_16x16x32_bf16(a1, bf, acc[1][nt], 0, 0, 0);
            }
        }
        #pragma unroll
        for (int nt = 0; nt < 16; ++nt) {
            float bias = b_h[L*256 + nt*16 + m_l];
            #pragma unroll
            for (int mt = 0; mt < 2; ++mt)
                #pragma unroll
                for (int r = 0; r < 4; ++r) {
                    float vv = fmaxf(acc[mt][nt][r] + bias, 0.f);
                    act_s[(row0 + mt*16 + q*4 + r)*264 + nt*16 + m_l] = f2bs(vv);
                }
        }
    }
    float4v o0 = (float4v){0.f,0.f,0.f,0.f}, o1 = (float4v){0.f,0.f,0.f,0.f};
    for (int kt = 0; kt < 8; ++kt) {
        short8 a0 = *(const short8*)&act_s[(row0 + m_l)*264 + kt*32 + q*8];
        short8 a1 = *(const short8*)&act_s[(row0 + 16 + m_l)*264 + kt*32 + q*8];
        short8 bf = *(const short8*)(wpo + ((size_t)kt*64 + l)*8);
        o0 = __builtin_amdgcn_mfma_f32_16x16x32_bf16(a0, bf, o0, 0, 0, 0);
        o1 = __builtin_amdgcn_mfma_f32_16x16x32_bf16(a1, bf, o1, 0, 0, 0);
    }
    float bias = b_out[m_l];
    #pragma unroll
    for (int mt = 0; mt < 2; ++mt) {
        float4v* op = mt ? &o1 : &o0;
        #pragma unroll
        for (int r = 0; r < 4; ++r) {
            int e = E0 + row0 + mt*16 + q*4 + r;
            float scale = (e < 6132) ? 0.25f : 0.f;
            if (e >= 6132) e = 0;
            int bb = e / 1533; int rem = e - bb*1533;
            int cn = rem / 511; int eidx = rem - cn*511;
            int s0 = (eidx < 256) ? 255 : eidx - 256;
            int s1 = (eidx < 256) ? eidx : 255;
            atomicAdd(&fo[(((long)(bb*16 + m_l)) << 16) + (s0<<8) + s1],
                      scale * ((*op)[r] + bias));
        }
    }
}

// ---------------- final conv (16->4) + lrms_up -----------------------------------
__global__ __launch_bounds__(256) void final_k(const float* __restrict__ fo, const float* __restrict__ w,
                                               const float* __restrict__ lrms_up, float* __restrict__ out){
    int tid = threadIdx.x, bx = blockIdx.x;
    int y = bx & 255, oc = (bx >> 8) & 3, b = bx >> 10;
    int x = tid;
    const float* wg = w + (size_t)oc * 144;
    float acc = 0.f;
    for (int ic = 0; ic < 16; ++ic) {
        const float* base = fo + (((size_t)(b*16 + ic)) << 16);
        #pragma unroll
        for (int ky = 0; ky < 3; ++ky) {
            int yy = y + ky - 1; if (yy < 0 || yy > 255) continue;
            const float* rowp = base + (yy<<8);
            float v0 = (x > 0)   ? rowp[x-1] : 0.f;
            float v1 = rowp[x];
            float v2 = (x < 255) ? rowp[x+1] : 0.f;
            const float* wr = wg + ic*9 + ky*3;
            acc = fmaf(wr[0], v0, fmaf(wr[1], v1, fmaf(wr[2], v2, acc)));
        }
    }
    size_t oidx = (((size_t)(b*4 + oc)) << 16) + (y<<8) + x;
    out[oidx] = acc + lrms_up[oidx];
}

// ================================================================================
extern "C" void kernel_launch(void* const* d_in, const int* in_sizes, int n_in,
                              void* d_out, int out_size, void* d_ws, size_t ws_size,
                              hipStream_t stream) {
    const float* lrms     = (const float*)d_in[0];
    const float* pan      = (const float*)d_in[1];
    const float* w_convps = (const float*)d_in[2];
    const float* hor_w1   = (const float*)d_in[3];
    const float* hor_w2   = (const float*)d_in[4];
    const float* ffc_l2l  = (const float*)d_in[5];
    const float* ffc_l2g  = (const float*)d_in[6];
    const float* ffc_g2l  = (const float*)d_in[7];
    const float* ffc_spec = (const float*)d_in[8];
    const float* ref_in   = (const float*)d_in[9];
    const float* ref_b1   = (const float*)d_in[10];
    const float* ref_b2   = (const float*)d_in[11];
    const float* ref_ca1  = (const float*)d_in[12];
    const float* ref_ca2  = (const float*)d_in[13];
    const float* ref_out  = (const float*)d_in[14];
    const float* w_fuse   = (const float*)d_in[15];
    const float* w_liif   = (const float*)d_in[16];
    const float* w_hp     = (const float*)d_in[17];
    const float* mw_in    = (const float*)d_in[18];
    const float* mb_in    = (const float*)d_in[19];
    const float* mw_h     = (const float*)d_in[20];
    const float* mb_h     = (const float*)d_in[21];
    const float* mw_out   = (const float*)d_in[22];
    const float* mb_out   = (const float*)d_in[23];
    float* out = (float*)d_out;

    const size_t PLANE = 65536;
    char* base = (char*)d_ws;
    size_t off = 0;
    auto alloc = [&](size_t bytes){ void* p = base + off; off += (bytes + 255) & ~(size_t)255; return p; };
    float* lrms_up  = (float*)alloc(16*PLANE*4);
    bf16*  feat2    = (bf16*) alloc(24*PLANE*2);
    bf16*  bA       = (bf16*) alloc(192*PLANE*2);
    bf16*  bB       = (bf16*) alloc(192*PLANE*2);
    bf16*  bC       = (bf16*) alloc(192*PLANE*2);
    bf16*  bF       = (bf16*) alloc(192*PLANE*2);
    bf16*  fusedCat = (bf16*) alloc(192*PLANE*2);
    bf16*  feat_all = (bf16*) alloc(64*PLANE*2);
    float* fo       = (float*)alloc(64*PLANE*4);
    const size_t FFTB = (size_t)3*4*8*256*129;
    bf16* re0 = (bf16*)alloc(FFTB*2); bf16* im0 = (bf16*)alloc(FFTB*2);
    bf16* re1 = (bf16*)alloc(FFTB*2); bf16* im1 = (bf16*)alloc(FFTB*2);
    short* wpack = (short*)alloc(241664*2);
    short* wconv = (short*)alloc(45*2560*2);
    float* means3 = (float*)alloc(3*192*4);
    if (off > ws_size) return;

    hipMemsetAsync(means3, 0, 3*192*4, stream);
    pack_all_k<<<dim3(1395), dim3(256), 0, stream>>>(mw_in, mw_h, mw_out, hor_w2,
        ref_in, ref_b1, ref_b2, ref_out, ffc_l2l, ffc_l2g, ffc_g2l, wpack, wconv);
    conv_ps_k<<<dim3(4096), dim3(256), 0, stream>>>(lrms, w_convps, lrms_up);

    GK3 g3;
    {
        const int kss[3] = {5, 27, 41};
        const double sgs[3] = {1.5, 2.0, 2.8};
        for (int br = 0; br < 3; ++br) {
            g3.ks[br] = kss[br];
            double tmp[41]; double s = 0.0; double c = (kss[br]-1)/2.0;
            for (int i = 0; i < kss[br]; ++i) { double d = i - c; tmp[i] = exp(-(d*d)/(2.0*sgs[br]*sgs[br])); s += tmp[i]; }
            for (int i = 0; i < 41; ++i) g3.k[br][i] = (i < kss[br]) ? (float)(tmp[i]/s) : 0.f;
        }
    }
    gauss_hp_k<<<dim3(6144), dim3(256), 0, stream>>>(pan, lrms_up, feat2, g3);

    // hornet
    convA_k<<<dim3(3072), dim3(256), 0, stream>>>(feat2, 2, 2, hor_w1, 720, 45, bA, ACT_GELU);
    convM_k<<<dim3(768), dim3(256), 0, stream>>>(bA, wconv + 0*3*2560, bB, ACT_NONE, nullptr);

    for (int step = 0; step < 3; ++step) {
        bf16* Xin = (step == 0) ? bB : bA;
        bf16* Yb  = (step == 0) ? bA : bB;
        bf16* Db  = (step == 0) ? bB : bA;
        convM_k<<<dim3(768), dim3(256), 0, stream>>>(Xin, wconv + (1+step)*3*2560, Yb, ACT_NONE, nullptr);
        convM_k<<<dim3(768), dim3(256), 0, stream>>>(Yb,  wconv + (4+step)*3*2560, bC, ACT_RELU, nullptr);
        convM_k<<<dim3(768), dim3(256), 0, stream>>>(bC,  wconv + (7+step)*3*2560, Db, ACT_NONE, means3 + step*192);
        convOutM_k<<<dim3(768), dim3(256), 0, stream>>>(Yb, Db, means3 + step*192, ref_ca1, ref_ca2,
                                                        wconv + (12+step)*3*2560, w_fuse, step, bF, fusedCat);
        if (step < 2) {
            convM_k<<<dim3(768), dim3(256), 0, stream>>>(bF, wconv + (10+step)*3*2560, bA, ACT_NONE, nullptr);
            rfft_wT_k<<<dim3(1536), dim3(256), 0, stream>>>(bF, re0, im0);
            fftspec_hT_k<<<dim3(1548), dim3(256), 0, stream>>>(re0, im0, ffc_spec, step, re1, im1);
            irfft_wT_k<<<dim3(1536), dim3(256), 0, stream>>>(re1, im1, bA);
        }
    }

    fuse1x1_k<<<dim3(1024), dim3(256), 0, stream>>>(fusedCat, w_liif, feat_all);
    mlp_mfma_k<<<dim3(4096), dim3(256), 64*264*2, stream>>>((const short*)feat_all, wpack, mb_in, mb_h, mb_out, fo);
    mlp_edge_mfma_k<<<dim3(48), dim3(256), 128*264*2, stream>>>((const short*)feat_all, wpack, mb_in, mb_h, mb_out, fo);
    final_k<<<dim3(4096), dim3(256), 0, stream>>>(fo, w_hp, lrms_up, out);
}